// Round 1
// baseline (1834.238 us; speedup 1.0000x reference)
//
#include <hip/hip_runtime.h>
#include <hip/hip_bf16.h>

#define NR_ 40000
#define NV_ 4000
#define ERR_ 400000
#define EVR_ 150000
#define ERV_ 150000
#define HH_ 128   // HEADS*H
#define NEG_ 0.2f
#define EPS_ 1e-5f

// ---------------- fold kernels (tiny precompute) ----------------

// folds[layer][rel][side][k][h] = sum_c W[rel][k][h*64+c] * a[rel][h][c]
__global__ void fold_kernel(const float* __restrict__ Wsrc1, const float* __restrict__ Wdst1,
                            const float* __restrict__ asrc1, const float* __restrict__ adst1,
                            const float* __restrict__ Wsrc2, const float* __restrict__ Wdst2,
                            const float* __restrict__ asrc2, const float* __restrict__ adst2,
                            float* __restrict__ folds /* [2][3][2][128][2] */) {
    int b = blockIdx.x;               // 0..11
    int layer = b / 6;
    int rel = (b % 6) / 2;
    int side = b & 1;
    int K = (layer == 0) ? 16 : 128;
    const float* W;
    const float* a;
    if (layer == 0) { W = side ? Wdst1 : Wsrc1; a = side ? adst1 : asrc1; }
    else            { W = side ? Wdst2 : Wsrc2; a = side ? adst2 : asrc2; }
    W += (size_t)rel * K * 128;
    a += rel * 128;
    float* out = folds + (size_t)(((layer * 3 + rel) * 2 + side)) * 256;
    int k = threadIdx.x;
    if (k < K) {
        for (int h = 0; h < 2; ++h) {
            float s = 0.f;
            for (int c = 0; c < 64; ++c) s += W[k * 128 + h * 64 + c] * a[h * 64 + c];
            out[k * 2 + h] = s;
        }
    }
}

// wp2[i][k][o] = sum_c Wp[i][k][c]*Wlin[(128+c)*2+o];  cterm[i][o] = blin[o] + sum_c bp[i][c]*Wlin[(128+c)*2+o]
__global__ void wp_fold_kernel(const float* __restrict__ Wp, const float* __restrict__ bp,
                               const float* __restrict__ Wlin, const float* __restrict__ blin,
                               float* __restrict__ wp2 /*[3][8][2]*/, float* __restrict__ cterm /*[3][2]*/) {
    int t = threadIdx.x;
    if (t < 48) {
        int i = t / 16, k = (t / 2) % 8, o = t & 1;
        float s = 0.f;
        for (int c = 0; c < 64; ++c) s += Wp[(i * 8 + k) * 64 + c] * Wlin[(128 + c) * 2 + o];
        wp2[t] = s;
    } else if (t < 54) {
        int i = (t - 48) / 2, o = (t - 48) & 1;
        float s = blin[o];
        for (int c = 0; c < 64; ++c) s += bp[i * 64 + c] * Wlin[(128 + c) * 2 + o];
        cterm[i * 2 + o] = s;
    }
}

// ---------------- projection: hs = x @ W  ([N,K] @ [K,128]) ----------------

template <int K, int ROWS>
__global__ void proj_kernel(const float* __restrict__ x, const float* __restrict__ W,
                            float* __restrict__ hs, int N) {
    __shared__ float sx[ROWS][K];
    int c = threadIdx.x;              // 0..127
    int row0 = blockIdx.x * ROWS;
    for (int i = threadIdx.x; i < ROWS * K; i += 128) {
        int r = i / K, k = i % K;
        int rr = row0 + r;
        sx[r][k] = (rr < N) ? x[(size_t)rr * K + k] : 0.f;
    }
    __syncthreads();
    float acc[ROWS];
#pragma unroll
    for (int r = 0; r < ROWS; ++r) acc[r] = 0.f;
    for (int k = 0; k < K; ++k) {
        float wk = W[k * 128 + c];
#pragma unroll
        for (int r = 0; r < ROWS; ++r) acc[r] += sx[r][k] * wk;
    }
#pragma unroll
    for (int r = 0; r < ROWS; ++r) {
        int rr = row0 + r;
        if (rr < N) hs[(size_t)rr * 128 + c] = acc[r];
    }
}

// ---------------- per-node attention scalars: out[n,h] = sum_k x[n,k]*fold[k,h] ----------------

template <int K>
__global__ void scores_kernel(const float* __restrict__ x, const float* __restrict__ fold,
                              float* __restrict__ out, int N) {
    int wave = (int)((blockIdx.x * (size_t)blockDim.x + threadIdx.x) >> 6);
    int lane = threadIdx.x & 63;
    if (wave >= N) return;
    float s0 = 0.f, s1 = 0.f;
    for (int k = lane; k < K; k += 64) {
        float v = x[(size_t)wave * K + k];
        s0 += v * fold[k * 2 + 0];
        s1 += v * fold[k * 2 + 1];
    }
    for (int off = 32; off; off >>= 1) {
        s0 += __shfl_down(s0, off);
        s1 += __shfl_down(s1, off);
    }
    if (lane == 0) { out[wave * 2 + 0] = s0; out[wave * 2 + 1] = s1; }
}

// ---------------- edge pass 1: ex = exp(lrelu(es[src]+ed[dst])), den[dst] += ex ----------------

__global__ void edge_pass1(const int* __restrict__ src, const int* __restrict__ dst,
                           const float* __restrict__ es, const float* __restrict__ ed,
                           float* __restrict__ ex, float* __restrict__ den, int E) {
    int e = blockIdx.x * blockDim.x + threadIdx.x;
    if (e >= E) return;
    int s = src[e], d = dst[e];
    float e0 = es[s * 2 + 0] + ed[d * 2 + 0];
    float e1 = es[s * 2 + 1] + ed[d * 2 + 1];
    e0 = (e0 >= 0.f) ? e0 : NEG_ * e0;
    e1 = (e1 >= 0.f) ? e1 : NEG_ * e1;
    float x0 = __expf(e0), x1 = __expf(e1);
    ex[(size_t)e * 2 + 0] = x0;
    ex[(size_t)e * 2 + 1] = x1;
    atomicAdd(&den[d * 2 + 0], x0);
    atomicAdd(&den[d * 2 + 1], x1);
}

// ---------------- edge pass 2: o[dst] += hs[src] * alpha ----------------

__global__ void edge_pass2(const int* __restrict__ src, const int* __restrict__ dst,
                           const float* __restrict__ hs, const float* __restrict__ ex,
                           const float* __restrict__ den, float* __restrict__ o, int E) {
    int e = blockIdx.x * 2 + (threadIdx.x >> 7);
    int f = threadIdx.x & 127;
    if (e >= E) return;
    int s = src[e], d = dst[e];
    int h = f >> 6;
    float alpha = ex[(size_t)e * 2 + h] / den[d * 2 + h];
    float v = hs[(size_t)s * 128 + f] * alpha;
    atomicAdd(&o[(size_t)d * 128 + f], v);
}

// ---------------- BatchNorm (training stats) + leaky-relu ----------------

__global__ void bn_stats(const float* __restrict__ o, float scale, int N,
                         float* __restrict__ sums, float* __restrict__ sumsq) {
    int c = threadIdx.x;              // 128
    int r0 = blockIdx.x * 256;
    int rend = r0 + 256;
    if (rend > N) rend = N;
    float s = 0.f, s2 = 0.f;
    for (int r = r0; r < rend; ++r) {
        float v = o[(size_t)r * 128 + c] * scale;
        s += v;
        s2 += v * v;
    }
    atomicAdd(&sums[c], s);
    atomicAdd(&sumsq[c], s2);
}

__global__ void bn_norm(const float* __restrict__ o, float scale, int N, float invN,
                        const float* __restrict__ sums, const float* __restrict__ sumsq,
                        const float* __restrict__ gamma, const float* __restrict__ beta,
                        float* __restrict__ x) {
    size_t idx = blockIdx.x * (size_t)blockDim.x + threadIdx.x;
    if (idx >= (size_t)N * 128) return;
    int c = (int)(idx & 127);
    float mu = sums[c] * invN;
    float var = sumsq[c] * invN - mu * mu;
    float v = (o[idx] * scale - mu) * rsqrtf(var + EPS_) * gamma[c] + beta[c];
    x[idx] = (v >= 0.f) ? v : NEG_ * v;
}

// ---------------- final head: per-node scores against Wlin halves ----------------

__global__ void final_scores(const float* __restrict__ x, const float* __restrict__ Wlin,
                             float* __restrict__ ssrc, float* __restrict__ sdst, int N) {
    int wave = (int)((blockIdx.x * (size_t)blockDim.x + threadIdx.x) >> 6);
    int lane = threadIdx.x & 63;
    if (wave >= N) return;
    float a0 = 0.f, a1 = 0.f, b0 = 0.f, b1 = 0.f;
    for (int k = lane; k < 128; k += 64) {
        float v = x[(size_t)wave * 128 + k];
        a0 += v * Wlin[k * 2 + 0];
        a1 += v * Wlin[k * 2 + 1];
        b0 += v * Wlin[(192 + k) * 2 + 0];
        b1 += v * Wlin[(192 + k) * 2 + 1];
    }
    for (int off = 32; off; off >>= 1) {
        a0 += __shfl_down(a0, off);
        a1 += __shfl_down(a1, off);
        b0 += __shfl_down(b0, off);
        b1 += __shfl_down(b1, off);
    }
    if (lane == 0) {
        ssrc[wave * 2 + 0] = a0; ssrc[wave * 2 + 1] = a1;
        sdst[wave * 2 + 0] = b0; sdst[wave * 2 + 1] = b1;
    }
}

__global__ void final_edge(const int* __restrict__ src, const int* __restrict__ dst,
                           const float* __restrict__ ea,
                           const float* __restrict__ ssrc, const float* __restrict__ sdst,
                           const float* __restrict__ wp2, const float* __restrict__ cterm,
                           float* __restrict__ out, int E) {
    int e = blockIdx.x * blockDim.x + threadIdx.x;
    if (e >= E) return;
    int s = src[e], d = dst[e];
    float l0 = ssrc[s * 2 + 0] + sdst[d * 2 + 0] + cterm[0];
    float l1 = ssrc[s * 2 + 1] + sdst[d * 2 + 1] + cterm[1];
#pragma unroll
    for (int k = 0; k < 8; ++k) {
        float v = ea[(size_t)e * 8 + k];
        l0 += v * wp2[k * 2 + 0];
        l1 += v * wp2[k * 2 + 1];
    }
    float m = fmaxf(l0, l1);
    float p0 = __expf(l0 - m), p1 = __expf(l1 - m);
    float inv = 1.f / (p0 + p1);
    out[(size_t)e * 2 + 0] = p0 * inv;
    out[(size_t)e * 2 + 1] = p1 * inv;
}

// ---------------- host orchestration ----------------

extern "C" void kernel_launch(void* const* d_in, const int* in_sizes, int n_in,
                              void* d_out, int out_size, void* d_ws, size_t ws_size,
                              hipStream_t stream) {
    const float* x_req = (const float*)d_in[0];
    const float* x_veh = (const float*)d_in[1];
    const int* ei_rr = (const int*)d_in[2];
    const int* ei_vr = (const int*)d_in[3];
    const int* ei_rv = (const int*)d_in[4];
    const float* ea_rr = (const float*)d_in[5];
    const float* ea_vr = (const float*)d_in[6];
    const float* ea_rv = (const float*)d_in[7];
    const float* Wsrc1 = (const float*)d_in[8];
    const float* Wdst1 = (const float*)d_in[9];
    const float* asrc1 = (const float*)d_in[10];
    const float* adst1 = (const float*)d_in[11];
    // d_in[12] = bias1: cancels under BatchNorm, unused
    const float* Wsrc2 = (const float*)d_in[13];
    const float* Wdst2 = (const float*)d_in[14];
    const float* asrc2 = (const float*)d_in[15];
    const float* adst2 = (const float*)d_in[16];
    // d_in[17] = bias2: cancels under BatchNorm, unused
    const float* bn_gamma = (const float*)d_in[18];   // [2,2,128]
    const float* bn_beta  = (const float*)d_in[19];
    const float* Wp   = (const float*)d_in[20];       // [3,8,64]
    const float* bp   = (const float*)d_in[21];       // [3,64]
    const float* Wlin = (const float*)d_in[22];       // [320,2]
    const float* blin = (const float*)d_in[23];       // [2]
    float* out = (float*)d_out;

    // workspace layout (floats)
    float* w = (float*)d_ws;
    size_t off = 0;
    float* xr    = w + off; off += (size_t)NR_ * 128;
    float* xv    = w + off; off += (size_t)NV_ * 128;
    float* hs    = w + off; off += (size_t)NR_ * 128;
    float* o_r   = w + off; off += (size_t)NR_ * 128;
    float* o_v   = w + off; off += (size_t)NV_ * 128;
    float* es    = w + off; off += (size_t)NR_ * 2;
    float* ed    = w + off; off += (size_t)NR_ * 2;
    float* ex    = w + off; off += (size_t)ERR_ * 2;
    float* den   = w + off; off += (size_t)NR_ * 2;
    float* sums  = w + off; off += 128;
    float* sumsq = w + off; off += 128;
    float* folds = w + off; off += 2 * 3 * 2 * 128 * 2;
    float* wp2   = w + off; off += 48;
    float* cterm = w + off; off += 8;
    float* ssrc_r = w + off; off += (size_t)NR_ * 2;
    float* sdst_r = w + off; off += (size_t)NR_ * 2;
    float* ssrc_v = w + off; off += (size_t)NV_ * 2;
    float* sdst_v = w + off; off += (size_t)NV_ * 2;

    // tiny precomputes
    fold_kernel<<<12, 128, 0, stream>>>(Wsrc1, Wdst1, asrc1, adst1, Wsrc2, Wdst2, asrc2, adst2, folds);
    wp_fold_kernel<<<1, 64, 0, stream>>>(Wp, bp, Wlin, blin, wp2, cterm);

    const int* srcs[3] = { ei_rr, ei_vr, ei_rv };
    const int* dsts[3] = { ei_rr + ERR_, ei_vr + EVR_, ei_rv + ERV_ };
    const int Es[3] = { ERR_, EVR_, ERV_ };

    for (int l = 0; l < 2; ++l) {
        const float* xs_[3];
        const float* xd_[3];
        int Ns_[3], Nd_[3];
        if (l == 0) {
            xs_[0] = x_req; xs_[1] = x_veh; xs_[2] = x_req;
            xd_[0] = x_req; xd_[1] = x_req; xd_[2] = x_veh;
        } else {
            xs_[0] = xr; xs_[1] = xv; xs_[2] = xr;
            xd_[0] = xr; xd_[1] = xr; xd_[2] = xv;
        }
        Ns_[0] = NR_; Ns_[1] = NV_; Ns_[2] = NR_;
        Nd_[0] = NR_; Nd_[1] = NR_; Nd_[2] = NV_;
        float* o_of[3] = { o_r, o_r, o_v };
        const int K = (l == 0) ? 16 : 128;
        const float* Ws = (l == 0) ? Wsrc1 : Wsrc2;

        hipMemsetAsync(o_r, 0, (size_t)NR_ * 128 * 4, stream);
        hipMemsetAsync(o_v, 0, (size_t)NV_ * 128 * 4, stream);

        for (int rel = 0; rel < 3; ++rel) {
            int Ns = Ns_[rel], Nd = Nd_[rel], E = Es[rel];
            const float* Wrel = Ws + (size_t)rel * K * 128;
            // hs = x_src @ W
            if (l == 0)
                proj_kernel<16, 32><<<(Ns + 31) / 32, 128, 0, stream>>>(xs_[rel], Wrel, hs, Ns);
            else
                proj_kernel<128, 32><<<(Ns + 31) / 32, 128, 0, stream>>>(xs_[rel], Wrel, hs, Ns);
            // es, ed
            const float* fs = folds + (size_t)((l * 3 + rel) * 2 + 0) * 256;
            const float* fd = folds + (size_t)((l * 3 + rel) * 2 + 1) * 256;
            if (l == 0) {
                scores_kernel<16><<<(Ns + 3) / 4, 256, 0, stream>>>(xs_[rel], fs, es, Ns);
                scores_kernel<16><<<(Nd + 3) / 4, 256, 0, stream>>>(xd_[rel], fd, ed, Nd);
            } else {
                scores_kernel<128><<<(Ns + 3) / 4, 256, 0, stream>>>(xs_[rel], fs, es, Ns);
                scores_kernel<128><<<(Nd + 3) / 4, 256, 0, stream>>>(xd_[rel], fd, ed, Nd);
            }
            hipMemsetAsync(den, 0, (size_t)Nd * 2 * 4, stream);
            edge_pass1<<<(E + 255) / 256, 256, 0, stream>>>(srcs[rel], dsts[rel], es, ed, ex, den, E);
            edge_pass2<<<(E + 1) / 2, 256, 0, stream>>>(srcs[rel], dsts[rel], hs, ex, den, o_of[rel], E);
        }

        // BN + lrelu: request nodes get mean of (o_rr+o_vr) -> scale 0.5; vehicle gets o_rv
        hipMemsetAsync(sums, 0, 128 * 4, stream);
        hipMemsetAsync(sumsq, 0, 128 * 4, stream);
        bn_stats<<<(NR_ + 255) / 256, 128, 0, stream>>>(o_r, 0.5f, NR_, sums, sumsq);
        bn_norm<<<((size_t)NR_ * 128 + 255) / 256, 256, 0, stream>>>(
            o_r, 0.5f, NR_, 1.f / NR_, sums, sumsq,
            bn_gamma + (l * 2 + 0) * 128, bn_beta + (l * 2 + 0) * 128, xr);

        hipMemsetAsync(sums, 0, 128 * 4, stream);
        hipMemsetAsync(sumsq, 0, 128 * 4, stream);
        bn_stats<<<(NV_ + 255) / 256, 128, 0, stream>>>(o_v, 1.0f, NV_, sums, sumsq);
        bn_norm<<<((size_t)NV_ * 128 + 255) / 256, 256, 0, stream>>>(
            o_v, 1.0f, NV_, 1.f / NV_, sums, sumsq,
            bn_gamma + (l * 2 + 1) * 128, bn_beta + (l * 2 + 1) * 128, xv);
    }

    // final head
    final_scores<<<(NR_ + 3) / 4, 256, 0, stream>>>(xr, Wlin, ssrc_r, sdst_r, NR_);
    final_scores<<<(NV_ + 3) / 4, 256, 0, stream>>>(xv, Wlin, ssrc_v, sdst_v, NV_);

    final_edge<<<(ERR_ + 255) / 256, 256, 0, stream>>>(
        ei_rr, ei_rr + ERR_, ea_rr, ssrc_r, sdst_r, wp2 + 0, cterm + 0, out, ERR_);
    final_edge<<<(EVR_ + 255) / 256, 256, 0, stream>>>(
        ei_vr, ei_vr + EVR_, ea_vr, ssrc_v, sdst_r, wp2 + 16, cterm + 2, out + (size_t)ERR_ * 2, EVR_);
    final_edge<<<(ERV_ + 255) / 256, 256, 0, stream>>>(
        ei_rv, ei_rv + ERV_, ea_rv, ssrc_r, sdst_v, wp2 + 32, cterm + 4, out + (size_t)(ERR_ + EVR_) * 2, ERV_);
}

// Round 2
// 1483.260 us; speedup vs baseline: 1.2366x; 1.2366x over previous
//
#include <hip/hip_runtime.h>
#include <hip/hip_bf16.h>

#define NR_ 40000
#define NV_ 4000
#define ERR_ 400000
#define EVR_ 150000
#define ERV_ 150000
#define NEG_ 0.2f
#define EPS_ 1e-5f

// ---------------- fold kernels (tiny precompute) ----------------

__global__ void fold_kernel(const float* __restrict__ Wsrc1, const float* __restrict__ Wdst1,
                            const float* __restrict__ asrc1, const float* __restrict__ adst1,
                            const float* __restrict__ Wsrc2, const float* __restrict__ Wdst2,
                            const float* __restrict__ asrc2, const float* __restrict__ adst2,
                            float* __restrict__ folds /* [2][3][2][128][2] */) {
    int b = blockIdx.x;               // 0..11
    int layer = b / 6;
    int rel = (b % 6) / 2;
    int side = b & 1;
    int K = (layer == 0) ? 16 : 128;
    const float* W;
    const float* a;
    if (layer == 0) { W = side ? Wdst1 : Wsrc1; a = side ? adst1 : asrc1; }
    else            { W = side ? Wdst2 : Wsrc2; a = side ? adst2 : asrc2; }
    W += (size_t)rel * K * 128;
    a += rel * 128;
    float* out = folds + (size_t)(((layer * 3 + rel) * 2 + side)) * 256;
    int k = threadIdx.x;
    if (k < K) {
        for (int h = 0; h < 2; ++h) {
            float s = 0.f;
            for (int c = 0; c < 64; ++c) s += W[k * 128 + h * 64 + c] * a[h * 64 + c];
            out[k * 2 + h] = s;
        }
    }
}

__global__ void wp_fold_kernel(const float* __restrict__ Wp, const float* __restrict__ bp,
                               const float* __restrict__ Wlin, const float* __restrict__ blin,
                               float* __restrict__ wp2 /*[3][8][2]*/, float* __restrict__ cterm /*[3][2]*/) {
    int t = threadIdx.x;
    if (t < 48) {
        int i = t / 16, k = (t / 2) % 8, o = t & 1;
        float s = 0.f;
        for (int c = 0; c < 64; ++c) s += Wp[(i * 8 + k) * 64 + c] * Wlin[(128 + c) * 2 + o];
        wp2[t] = s;
    } else if (t < 54) {
        int i = (t - 48) / 2, o = (t - 48) & 1;
        float s = blin[o];
        for (int c = 0; c < 64; ++c) s += bp[i * 64 + c] * Wlin[(128 + c) * 2 + o];
        cterm[i * 2 + o] = s;
    }
}

// ---------------- CSR build ----------------

__global__ void hist_kernel(const int* __restrict__ dst, int* __restrict__ cnt, int E) {
    int e = blockIdx.x * blockDim.x + threadIdx.x;
    if (e < E) atomicAdd(&cnt[dst[e]], 1);
}

// grid = 3 blocks of 1024 threads; each block exclusive-scans one rel's counts.
__global__ void scan3_kernel(const int* __restrict__ cnt_rr, int* __restrict__ row_rr,
                             const int* __restrict__ cnt_vr, int* __restrict__ row_vr,
                             const int* __restrict__ cnt_rv, int* __restrict__ row_rv) {
    const int* cnt; int* row; int N;
    if (blockIdx.x == 0)      { cnt = cnt_rr; row = row_rr; N = NR_; }
    else if (blockIdx.x == 1) { cnt = cnt_vr; row = row_vr; N = NR_; }
    else                      { cnt = cnt_rv; row = row_rv; N = NV_; }
    int t = threadIdx.x;
    int CH = (N + 1023) / 1024;
    int base = t * CH;
    int end = base + CH; if (end > N) end = N;
    int s = 0;
    for (int i = base; i < end; ++i) s += cnt[i];
    __shared__ int buf[1024];
    buf[t] = s;
    __syncthreads();
    for (int off = 1; off < 1024; off <<= 1) {
        int v = (t >= off) ? buf[t - off] : 0;
        __syncthreads();
        buf[t] += v;
        __syncthreads();
    }
    int run = buf[t] - s;      // exclusive offset of this thread's chunk
    for (int i = base; i < end; ++i) { row[i] = run; run += cnt[i]; }
    if (t == 0) row[N] = buf[1023];
}

__global__ void scatter_kernel(const int* __restrict__ src, const int* __restrict__ dst,
                               int* __restrict__ cursor, int* __restrict__ csr_src,
                               int* __restrict__ csr_dst, int E) {
    int e = blockIdx.x * blockDim.x + threadIdx.x;
    if (e >= E) return;
    int d = dst[e];
    int j = atomicAdd(&cursor[d], 1);
    csr_src[j] = src[e];
    csr_dst[j] = d;
}

// ---------------- projection: hs = x @ W  ([N,K] @ [K,128]) ----------------

template <int K, int ROWS>
__global__ void proj_kernel(const float* __restrict__ x, const float* __restrict__ W,
                            float* __restrict__ hs, int N) {
    __shared__ float sx[ROWS][K];
    int c = threadIdx.x;              // 0..127
    int row0 = blockIdx.x * ROWS;
    for (int i = threadIdx.x; i < ROWS * K; i += 128) {
        int r = i / K, k = i % K;
        int rr = row0 + r;
        sx[r][k] = (rr < N) ? x[(size_t)rr * K + k] : 0.f;
    }
    __syncthreads();
    float acc[ROWS];
#pragma unroll
    for (int r = 0; r < ROWS; ++r) acc[r] = 0.f;
    for (int k = 0; k < K; ++k) {
        float wk = W[k * 128 + c];
#pragma unroll
        for (int r = 0; r < ROWS; ++r) acc[r] += sx[r][k] * wk;
    }
#pragma unroll
    for (int r = 0; r < ROWS; ++r) {
        int rr = row0 + r;
        if (rr < N) hs[(size_t)rr * 128 + c] = acc[r];
    }
}

// ---------------- per-node attention scalars ----------------

template <int K>
__global__ void scores_kernel(const float* __restrict__ x, const float* __restrict__ fold,
                              float* __restrict__ out, int N) {
    int wave = (int)((blockIdx.x * (size_t)blockDim.x + threadIdx.x) >> 6);
    int lane = threadIdx.x & 63;
    if (wave >= N) return;
    float s0 = 0.f, s1 = 0.f;
    for (int k = lane; k < K; k += 64) {
        float v = x[(size_t)wave * K + k];
        s0 += v * fold[k * 2 + 0];
        s1 += v * fold[k * 2 + 1];
    }
    for (int off = 32; off; off >>= 1) {
        s0 += __shfl_down(s0, off);
        s1 += __shfl_down(s1, off);
    }
    if (lane == 0) { out[wave * 2 + 0] = s0; out[wave * 2 + 1] = s1; }
}

// ---------------- pass1: ex[j] = exp(lrelu(es[src]+ed[dst])) in CSR order ----------------

__global__ void pass1_csr(const int* __restrict__ csr_src, const int* __restrict__ csr_dst,
                          const float* __restrict__ es, const float* __restrict__ ed,
                          float* __restrict__ ex, int M) {
    int j = blockIdx.x * blockDim.x + threadIdx.x;
    if (j >= M) return;
    int s = csr_src[j], d = csr_dst[j];
    float e0 = es[s * 2 + 0] + ed[d * 2 + 0];
    float e1 = es[s * 2 + 1] + ed[d * 2 + 1];
    e0 = (e0 >= 0.f) ? e0 : NEG_ * e0;
    e1 = (e1 >= 0.f) ? e1 : NEG_ * e1;
    ex[(size_t)j * 2 + 0] = __expf(e0);
    ex[(size_t)j * 2 + 1] = __expf(e1);
}

// ---------------- gather-aggregate ----------------
// one node per 128 threads (2 waves: wave0 = head 0, wave1 = head 1); block = 256 -> 2 nodes

__device__ __forceinline__ float agg_rel(int node, int t, int lane, int h,
                                         const int* __restrict__ row, const int* __restrict__ csr_src,
                                         const float* __restrict__ ex, const float* __restrict__ hs) {
    int r0 = row[node], r1 = row[node + 1];
    float den = 0.f;
    for (int j = r0 + lane; j < r1; j += 64) den += ex[(size_t)j * 2 + h];
    #pragma unroll
    for (int off = 32; off; off >>= 1) den += __shfl_xor(den, off);
    float acc = 0.f;
    if (r1 > r0) {
        float inv = 1.f / den;
        for (int j = r0; j < r1; ++j) {
            int s = csr_src[j];
            acc += hs[(size_t)s * 128 + t] * (ex[(size_t)j * 2 + h] * inv);
        }
    }
    return acc;
}

__global__ void agg_req(const int* __restrict__ row_rr, const int* __restrict__ csr_src_rr,
                        const float* __restrict__ ex_rr, const float* __restrict__ hs_rr,
                        const int* __restrict__ row_vr, const int* __restrict__ csr_src_vr,
                        const float* __restrict__ ex_vr, const float* __restrict__ hs_vr,
                        float* __restrict__ o, int N) {
    int node = blockIdx.x * 2 + (threadIdx.x >> 7);
    if (node >= N) return;
    int t = threadIdx.x & 127;
    int lane = t & 63;
    int h = t >> 6;  // wave-uniform
    float acc = agg_rel(node, t, lane, h, row_rr, csr_src_rr, ex_rr, hs_rr)
              + agg_rel(node, t, lane, h, row_vr, csr_src_vr, ex_vr, hs_vr);
    o[(size_t)node * 128 + t] = acc * 0.5f;
}

__global__ void agg_veh(const int* __restrict__ row, const int* __restrict__ csr_src,
                        const float* __restrict__ ex, const float* __restrict__ hs,
                        float* __restrict__ o, int N) {
    int node = blockIdx.x * 2 + (threadIdx.x >> 7);
    if (node >= N) return;
    int t = threadIdx.x & 127;
    int lane = t & 63;
    int h = t >> 6;
    o[(size_t)node * 128 + t] = agg_rel(node, t, lane, h, row, csr_src, ex, hs);
}

// ---------------- BatchNorm (training stats) + leaky-relu ----------------

__global__ void bn_stats(const float* __restrict__ o, float scale, int N,
                         float* __restrict__ sums, float* __restrict__ sumsq) {
    int c = threadIdx.x;              // 128
    int r0 = blockIdx.x * 256;
    int rend = r0 + 256;
    if (rend > N) rend = N;
    float s = 0.f, s2 = 0.f;
    for (int r = r0; r < rend; ++r) {
        float v = o[(size_t)r * 128 + c] * scale;
        s += v;
        s2 += v * v;
    }
    atomicAdd(&sums[c], s);
    atomicAdd(&sumsq[c], s2);
}

__global__ void bn_norm(const float* __restrict__ o, float scale, int N, float invN,
                        const float* __restrict__ sums, const float* __restrict__ sumsq,
                        const float* __restrict__ gamma, const float* __restrict__ beta,
                        float* __restrict__ x) {
    size_t idx = blockIdx.x * (size_t)blockDim.x + threadIdx.x;
    if (idx >= (size_t)N * 128) return;
    int c = (int)(idx & 127);
    float mu = sums[c] * invN;
    float var = sumsq[c] * invN - mu * mu;
    float v = (o[idx] * scale - mu) * rsqrtf(var + EPS_) * gamma[c] + beta[c];
    x[idx] = (v >= 0.f) ? v : NEG_ * v;
}

// ---------------- final head ----------------

__global__ void final_scores(const float* __restrict__ x, const float* __restrict__ Wlin,
                             float* __restrict__ ssrc, float* __restrict__ sdst, int N) {
    int wave = (int)((blockIdx.x * (size_t)blockDim.x + threadIdx.x) >> 6);
    int lane = threadIdx.x & 63;
    if (wave >= N) return;
    float a0 = 0.f, a1 = 0.f, b0 = 0.f, b1 = 0.f;
    for (int k = lane; k < 128; k += 64) {
        float v = x[(size_t)wave * 128 + k];
        a0 += v * Wlin[k * 2 + 0];
        a1 += v * Wlin[k * 2 + 1];
        b0 += v * Wlin[(192 + k) * 2 + 0];
        b1 += v * Wlin[(192 + k) * 2 + 1];
    }
    for (int off = 32; off; off >>= 1) {
        a0 += __shfl_down(a0, off);
        a1 += __shfl_down(a1, off);
        b0 += __shfl_down(b0, off);
        b1 += __shfl_down(b1, off);
    }
    if (lane == 0) {
        ssrc[wave * 2 + 0] = a0; ssrc[wave * 2 + 1] = a1;
        sdst[wave * 2 + 0] = b0; sdst[wave * 2 + 1] = b1;
    }
}

__global__ void final_edge(const int* __restrict__ src, const int* __restrict__ dst,
                           const float* __restrict__ ea,
                           const float* __restrict__ ssrc, const float* __restrict__ sdst,
                           const float* __restrict__ wp2, const float* __restrict__ cterm,
                           float* __restrict__ out, int E) {
    int e = blockIdx.x * blockDim.x + threadIdx.x;
    if (e >= E) return;
    int s = src[e], d = dst[e];
    float l0 = ssrc[s * 2 + 0] + sdst[d * 2 + 0] + cterm[0];
    float l1 = ssrc[s * 2 + 1] + sdst[d * 2 + 1] + cterm[1];
#pragma unroll
    for (int k = 0; k < 8; ++k) {
        float v = ea[(size_t)e * 8 + k];
        l0 += v * wp2[k * 2 + 0];
        l1 += v * wp2[k * 2 + 1];
    }
    float m = fmaxf(l0, l1);
    float p0 = __expf(l0 - m), p1 = __expf(l1 - m);
    float inv = 1.f / (p0 + p1);
    out[(size_t)e * 2 + 0] = p0 * inv;
    out[(size_t)e * 2 + 1] = p1 * inv;
}

// ---------------- host orchestration ----------------

extern "C" void kernel_launch(void* const* d_in, const int* in_sizes, int n_in,
                              void* d_out, int out_size, void* d_ws, size_t ws_size,
                              hipStream_t stream) {
    const float* x_req = (const float*)d_in[0];
    const float* x_veh = (const float*)d_in[1];
    const int* ei_rr = (const int*)d_in[2];
    const int* ei_vr = (const int*)d_in[3];
    const int* ei_rv = (const int*)d_in[4];
    const float* ea_rr = (const float*)d_in[5];
    const float* ea_vr = (const float*)d_in[6];
    const float* ea_rv = (const float*)d_in[7];
    const float* Wsrc1 = (const float*)d_in[8];
    const float* Wdst1 = (const float*)d_in[9];
    const float* asrc1 = (const float*)d_in[10];
    const float* adst1 = (const float*)d_in[11];
    const float* Wsrc2 = (const float*)d_in[13];
    const float* Wdst2 = (const float*)d_in[14];
    const float* asrc2 = (const float*)d_in[15];
    const float* adst2 = (const float*)d_in[16];
    const float* bn_gamma = (const float*)d_in[18];   // [2,2,128]
    const float* bn_beta  = (const float*)d_in[19];
    const float* Wp   = (const float*)d_in[20];       // [3,8,64]
    const float* bp   = (const float*)d_in[21];       // [3,64]
    const float* Wlin = (const float*)d_in[22];       // [320,2]
    const float* blin = (const float*)d_in[23];       // [2]
    float* out = (float*)d_out;

    // ---- workspace layout ----
    float* w = (float*)d_ws;
    size_t off = 0;
    float* xr    = w + off; off += (size_t)NR_ * 128;
    float* xv    = w + off; off += (size_t)NV_ * 128;
    float* hs_a  = w + off; off += (size_t)NR_ * 128;   // req-src projections (rr, rv)
    float* hs_b  = w + off; off += (size_t)NV_ * 128;   // veh-src projections (vr)
    float* o_r   = w + off; off += (size_t)NR_ * 128;
    float* o_v   = w + off; off += (size_t)NV_ * 128;
    float* es    = w + off; off += (size_t)NR_ * 2;
    float* ed    = w + off; off += (size_t)NR_ * 2;
    float* ex_rr = w + off; off += (size_t)ERR_ * 2;
    float* ex_vr = w + off; off += (size_t)EVR_ * 2;
    float* ex_rv = w + off; off += (size_t)ERV_ * 2;
    float* sums  = w + off; off += 128;
    float* sumsq = w + off; off += 128;
    float* folds = w + off; off += 2 * 3 * 2 * 128 * 2;
    float* wp2   = w + off; off += 48;
    float* cterm = w + off; off += 8;
    float* ssrc_r = w + off; off += (size_t)NR_ * 2;
    float* sdst_r = w + off; off += (size_t)NR_ * 2;
    float* ssrc_v = w + off; off += (size_t)NV_ * 2;
    float* sdst_v = w + off; off += (size_t)NV_ * 2;
    int* iw = (int*)(w + off);
    size_t ioff = 0;
    int* row_rr = iw + ioff; ioff += NR_ + 1;
    int* row_vr = iw + ioff; ioff += NR_ + 1;
    int* row_rv = iw + ioff; ioff += NV_ + 1;
    int* cur_rr = iw + ioff; ioff += NR_;      // doubles as cnt
    int* cur_vr = iw + ioff; ioff += NR_;
    int* cur_rv = iw + ioff; ioff += NV_;
    int* csr_src_rr = iw + ioff; ioff += ERR_;
    int* csr_dst_rr = iw + ioff; ioff += ERR_;
    int* csr_src_vr = iw + ioff; ioff += EVR_;
    int* csr_dst_vr = iw + ioff; ioff += EVR_;
    int* csr_src_rv = iw + ioff; ioff += ERV_;
    int* csr_dst_rv = iw + ioff; ioff += ERV_;

    const int* src_rr = ei_rr;            const int* dst_rr = ei_rr + ERR_;
    const int* src_vr = ei_vr;            const int* dst_vr = ei_vr + EVR_;
    const int* src_rv = ei_rv;            const int* dst_rv = ei_rv + ERV_;

    // ---- tiny precomputes ----
    fold_kernel<<<12, 128, 0, stream>>>(Wsrc1, Wdst1, asrc1, adst1, Wsrc2, Wdst2, asrc2, adst2, folds);
    wp_fold_kernel<<<1, 64, 0, stream>>>(Wp, bp, Wlin, blin, wp2, cterm);

    // ---- CSR build (once; shared across both layers) ----
    hipMemsetAsync(cur_rr, 0, (2 * NR_ + NV_) * sizeof(int), stream);  // cur_rr, cur_vr, cur_rv contiguous
    hist_kernel<<<(ERR_ + 255) / 256, 256, 0, stream>>>(dst_rr, cur_rr, ERR_);
    hist_kernel<<<(EVR_ + 255) / 256, 256, 0, stream>>>(dst_vr, cur_vr, EVR_);
    hist_kernel<<<(ERV_ + 255) / 256, 256, 0, stream>>>(dst_rv, cur_rv, ERV_);
    scan3_kernel<<<3, 1024, 0, stream>>>(cur_rr, row_rr, cur_vr, row_vr, cur_rv, row_rv);
    hipMemcpyAsync(cur_rr, row_rr, NR_ * sizeof(int), hipMemcpyDeviceToDevice, stream);
    hipMemcpyAsync(cur_vr, row_vr, NR_ * sizeof(int), hipMemcpyDeviceToDevice, stream);
    hipMemcpyAsync(cur_rv, row_rv, NV_ * sizeof(int), hipMemcpyDeviceToDevice, stream);
    scatter_kernel<<<(ERR_ + 255) / 256, 256, 0, stream>>>(src_rr, dst_rr, cur_rr, csr_src_rr, csr_dst_rr, ERR_);
    scatter_kernel<<<(EVR_ + 255) / 256, 256, 0, stream>>>(src_vr, dst_vr, cur_vr, csr_src_vr, csr_dst_vr, EVR_);
    scatter_kernel<<<(ERV_ + 255) / 256, 256, 0, stream>>>(src_rv, dst_rv, cur_rv, csr_src_rv, csr_dst_rv, ERV_);

    for (int l = 0; l < 2; ++l) {
        const float* xreq_in = (l == 0) ? x_req : xr;
        const float* xveh_in = (l == 0) ? x_veh : xv;
        const int K = (l == 0) ? 16 : 128;
        const float* Ws = (l == 0) ? Wsrc1 : Wsrc2;
        const float* foldL = folds + (size_t)l * 3 * 2 * 256;

        // --- rel 0: rr (req -> req) ---
        if (l == 0) proj_kernel<16, 32><<<(NR_ + 31) / 32, 128, 0, stream>>>(xreq_in, Ws + 0 * K * 128, hs_a, NR_);
        else        proj_kernel<128, 32><<<(NR_ + 31) / 32, 128, 0, stream>>>(xreq_in, Ws + 0 * K * 128, hs_a, NR_);
        if (l == 0) {
            scores_kernel<16><<<(NR_ + 3) / 4, 256, 0, stream>>>(xreq_in, foldL + 0 * 256, es, NR_);
            scores_kernel<16><<<(NR_ + 3) / 4, 256, 0, stream>>>(xreq_in, foldL + 1 * 256, ed, NR_);
        } else {
            scores_kernel<128><<<(NR_ + 3) / 4, 256, 0, stream>>>(xreq_in, foldL + 0 * 256, es, NR_);
            scores_kernel<128><<<(NR_ + 3) / 4, 256, 0, stream>>>(xreq_in, foldL + 1 * 256, ed, NR_);
        }
        pass1_csr<<<(ERR_ + 255) / 256, 256, 0, stream>>>(csr_src_rr, csr_dst_rr, es, ed, ex_rr, ERR_);

        // --- rel 1: vr (veh -> req) ---
        if (l == 0) proj_kernel<16, 32><<<(NV_ + 31) / 32, 128, 0, stream>>>(xveh_in, Ws + 1 * K * 128, hs_b, NV_);
        else        proj_kernel<128, 32><<<(NV_ + 31) / 32, 128, 0, stream>>>(xveh_in, Ws + 1 * K * 128, hs_b, NV_);
        if (l == 0) {
            scores_kernel<16><<<(NV_ + 3) / 4, 256, 0, stream>>>(xveh_in, foldL + 2 * 256, es, NV_);
            scores_kernel<16><<<(NR_ + 3) / 4, 256, 0, stream>>>(xreq_in, foldL + 3 * 256, ed, NR_);
        } else {
            scores_kernel<128><<<(NV_ + 3) / 4, 256, 0, stream>>>(xveh_in, foldL + 2 * 256, es, NV_);
            scores_kernel<128><<<(NR_ + 3) / 4, 256, 0, stream>>>(xreq_in, foldL + 3 * 256, ed, NR_);
        }
        pass1_csr<<<(EVR_ + 255) / 256, 256, 0, stream>>>(csr_src_vr, csr_dst_vr, es, ed, ex_vr, EVR_);

        // request aggregation: mean of rr + vr, single write
        agg_req<<<(NR_ + 1) / 2, 256, 0, stream>>>(row_rr, csr_src_rr, ex_rr, hs_a,
                                                   row_vr, csr_src_vr, ex_vr, hs_b, o_r, NR_);

        // --- rel 2: rv (req -> veh) --- (hs_a reused; req agg already consumed it)
        if (l == 0) proj_kernel<16, 32><<<(NR_ + 31) / 32, 128, 0, stream>>>(xreq_in, Ws + 2 * K * 128, hs_a, NR_);
        else        proj_kernel<128, 32><<<(NR_ + 31) / 32, 128, 0, stream>>>(xreq_in, Ws + 2 * K * 128, hs_a, NR_);
        if (l == 0) {
            scores_kernel<16><<<(NR_ + 3) / 4, 256, 0, stream>>>(xreq_in, foldL + 4 * 256, es, NR_);
            scores_kernel<16><<<(NV_ + 3) / 4, 256, 0, stream>>>(xveh_in, foldL + 5 * 256, ed, NV_);
        } else {
            scores_kernel<128><<<(NR_ + 3) / 4, 256, 0, stream>>>(xreq_in, foldL + 4 * 256, es, NR_);
            scores_kernel<128><<<(NV_ + 3) / 4, 256, 0, stream>>>(xveh_in, foldL + 5 * 256, ed, NV_);
        }
        pass1_csr<<<(ERV_ + 255) / 256, 256, 0, stream>>>(csr_src_rv, csr_dst_rv, es, ed, ex_rv, ERV_);
        agg_veh<<<(NV_ + 1) / 2, 256, 0, stream>>>(row_rv, csr_src_rv, ex_rv, hs_a, o_v, NV_);

        // --- BN + lrelu ---
        hipMemsetAsync(sums, 0, 256 * sizeof(float), stream);  // sums+sumsq contiguous
        bn_stats<<<(NR_ + 255) / 256, 128, 0, stream>>>(o_r, 1.0f, NR_, sums, sumsq);
        bn_norm<<<((size_t)NR_ * 128 + 255) / 256, 256, 0, stream>>>(
            o_r, 1.0f, NR_, 1.f / NR_, sums, sumsq,
            bn_gamma + (l * 2 + 0) * 128, bn_beta + (l * 2 + 0) * 128, xr);

        hipMemsetAsync(sums, 0, 256 * sizeof(float), stream);
        bn_stats<<<(NV_ + 255) / 256, 128, 0, stream>>>(o_v, 1.0f, NV_, sums, sumsq);
        bn_norm<<<((size_t)NV_ * 128 + 255) / 256, 256, 0, stream>>>(
            o_v, 1.0f, NV_, 1.f / NV_, sums, sumsq,
            bn_gamma + (l * 2 + 1) * 128, bn_beta + (l * 2 + 1) * 128, xv);
    }

    // ---- final head ----
    final_scores<<<(NR_ + 3) / 4, 256, 0, stream>>>(xr, Wlin, ssrc_r, sdst_r, NR_);
    final_scores<<<(NV_ + 3) / 4, 256, 0, stream>>>(xv, Wlin, ssrc_v, sdst_v, NV_);

    final_edge<<<(ERR_ + 255) / 256, 256, 0, stream>>>(
        src_rr, dst_rr, ea_rr, ssrc_r, sdst_r, wp2 + 0, cterm + 0, out, ERR_);
    final_edge<<<(EVR_ + 255) / 256, 256, 0, stream>>>(
        src_vr, dst_vr, ea_vr, ssrc_v, sdst_r, wp2 + 16, cterm + 2, out + (size_t)ERR_ * 2, EVR_);
    final_edge<<<(ERV_ + 255) / 256, 256, 0, stream>>>(
        src_rv, dst_rv, ea_rv, ssrc_r, sdst_v, wp2 + 32, cterm + 4, out + (size_t)(ERR_ + EVR_) * 2, ERV_);
}

// Round 3
// 921.903 us; speedup vs baseline: 1.9896x; 1.6089x over previous
//
#include <hip/hip_runtime.h>
#include <hip/hip_bf16.h>

#define NR_ 40000
#define NV_ 4000
#define ERR_ 400000
#define EVR_ 150000
#define ERV_ 150000
#define ETOT_ (ERR_ + EVR_ + ERV_)
#define NEG_ 0.2f
#define EPS_ 1e-5f

// ================= precompute: attention folds, edge-proj fold, final fold =================
// foldR[l][k][8] cols: es_rr(0,1) ed_rr(2,3) ed_vr(4,5) es_rv(6,7)
// foldV[l][k][4] cols: es_vr(0,1) ed_rv(2,3)
// fw[k][4]: Wlin cols for src half (0,1) and dst half (2,3)
__global__ void precompute_kernel(const float* __restrict__ Wsrc1, const float* __restrict__ Wdst1,
                                  const float* __restrict__ asrc1, const float* __restrict__ adst1,
                                  const float* __restrict__ Wsrc2, const float* __restrict__ Wdst2,
                                  const float* __restrict__ asrc2, const float* __restrict__ adst2,
                                  const float* __restrict__ Wp, const float* __restrict__ bp,
                                  const float* __restrict__ Wlin, const float* __restrict__ blin,
                                  float* __restrict__ foldR, float* __restrict__ foldV,
                                  float* __restrict__ wp2, float* __restrict__ cterm,
                                  float* __restrict__ fw) {
    int b = blockIdx.x;
    int t = threadIdx.x;  // 128
    if (b < 12) {
        int layer = b / 6, rel = (b % 6) / 2, side = b & 1;
        int K = (layer == 0) ? 16 : 128;
        const float* W = (layer == 0) ? (side ? Wdst1 : Wsrc1) : (side ? Wdst2 : Wsrc2);
        const float* a = (layer == 0) ? (side ? adst1 : asrc1) : (side ? adst2 : asrc2);
        W += (size_t)rel * K * 128;
        a += rel * 128;
        float* dst; int P; int colbase;
        if (rel == 0 && side == 0)      { dst = foldR; P = 8; colbase = 0; }
        else if (rel == 0)              { dst = foldR; P = 8; colbase = 2; }
        else if (rel == 1 && side == 0) { dst = foldV; P = 4; colbase = 0; }
        else if (rel == 1)              { dst = foldR; P = 8; colbase = 4; }
        else if (side == 0)             { dst = foldR; P = 8; colbase = 6; }
        else                            { dst = foldV; P = 4; colbase = 2; }
        dst += (size_t)layer * 128 * P;
        if (t < K) {
            for (int h = 0; h < 2; ++h) {
                float s = 0.f;
                for (int c = 0; c < 64; ++c) s += W[t * 128 + h * 64 + c] * a[h * 64 + c];
                dst[t * P + colbase + h] = s;
            }
        }
    } else if (b == 12) {
        if (t < 48) {
            int i = t / 16, k = (t / 2) % 8, o = t & 1;
            float s = 0.f;
            for (int c = 0; c < 64; ++c) s += Wp[(i * 8 + k) * 64 + c] * Wlin[(128 + c) * 2 + o];
            wp2[t] = s;
        } else if (t < 54) {
            int i = (t - 48) / 2, o = (t - 48) & 1;
            float s = blin[o];
            for (int c = 0; c < 64; ++c) s += bp[i * 64 + c] * Wlin[(128 + c) * 2 + o];
            cterm[i * 2 + o] = s;
        }
    } else {
        // fw: 128 k x 4 cols = 512 entries, 4 per thread
        for (int idx = t; idx < 512; idx += 128) {
            int k = idx >> 2, c = idx & 3;
            fw[idx] = Wlin[(k + ((c >= 2) ? 192 : 0)) * 2 + (c & 1)];
        }
    }
}

// ================= CSR build =================

__global__ void hist_all(const int* __restrict__ dst_rr, const int* __restrict__ dst_vr,
                         const int* __restrict__ dst_rv, int* __restrict__ cnt_rr,
                         int* __restrict__ cnt_vr, int* __restrict__ cnt_rv) {
    int j = blockIdx.x * blockDim.x + threadIdx.x;
    if (j < ERR_) atomicAdd(&cnt_rr[dst_rr[j]], 1);
    else if (j < ERR_ + EVR_) atomicAdd(&cnt_vr[dst_vr[j - ERR_]], 1);
    else if (j < ETOT_) atomicAdd(&cnt_rv[dst_rv[j - ERR_ - EVR_]], 1);
}

// 3 blocks x 1024 threads; block scans one rel; writes row[] and cursor[]
__global__ void scan3_kernel(const int* __restrict__ cnt_rr, int* __restrict__ row_rr, int* __restrict__ cur_rr,
                             const int* __restrict__ cnt_vr, int* __restrict__ row_vr, int* __restrict__ cur_vr,
                             const int* __restrict__ cnt_rv, int* __restrict__ row_rv, int* __restrict__ cur_rv) {
    const int* cnt; int* row; int* cur; int N;
    if (blockIdx.x == 0)      { cnt = cnt_rr; row = row_rr; cur = cur_rr; N = NR_; }
    else if (blockIdx.x == 1) { cnt = cnt_vr; row = row_vr; cur = cur_vr; N = NR_; }
    else                      { cnt = cnt_rv; row = row_rv; cur = cur_rv; N = NV_; }
    int t = threadIdx.x;
    int CH = (N + 1023) / 1024;
    int base = t * CH;
    int end = base + CH; if (end > N) end = N;
    int s = 0;
    for (int i = base; i < end; ++i) s += cnt[i];
    __shared__ int buf[1024];
    buf[t] = s;
    __syncthreads();
    for (int off = 1; off < 1024; off <<= 1) {
        int v = (t >= off) ? buf[t - off] : 0;
        __syncthreads();
        buf[t] += v;
        __syncthreads();
    }
    int run = buf[t] - s;
    for (int i = base; i < end; ++i) { row[i] = run; cur[i] = run; run += cnt[i]; }
    if (t == 0) row[N] = buf[1023];
}

__global__ void scatter_all(const int* __restrict__ ei_rr, const int* __restrict__ ei_vr,
                            const int* __restrict__ ei_rv,
                            int* __restrict__ cur_rr, int* __restrict__ cur_vr, int* __restrict__ cur_rv,
                            int* __restrict__ cs_rr, int* __restrict__ cd_rr,
                            int* __restrict__ cs_vr, int* __restrict__ cd_vr,
                            int* __restrict__ cs_rv, int* __restrict__ cd_rv) {
    int j = blockIdx.x * blockDim.x + threadIdx.x;
    const int* src; const int* dst; int* cur; int* cs; int* cd; int jj;
    if (j < ERR_)             { jj = j;               src = ei_rr; dst = ei_rr + ERR_; cur = cur_rr; cs = cs_rr; cd = cd_rr; }
    else if (j < ERR_ + EVR_) { jj = j - ERR_;        src = ei_vr; dst = ei_vr + EVR_; cur = cur_vr; cs = cs_vr; cd = cd_vr; }
    else if (j < ETOT_)       { jj = j - ERR_ - EVR_; src = ei_rv; dst = ei_rv + ERV_; cur = cur_rv; cs = cs_rv; cd = cd_rv; }
    else return;
    int d = dst[jj];
    int p = atomicAdd(&cur[d], 1);
    cs[p] = src[jj];
    cd[p] = d;
}

// ================= register-blocked GEMM: hs = x @ W  ([N,K] @ [K,128]) =================
// 256 threads, tile 64 rows x 128 cols, thread = 8 rows x 4 cols, K-chunked LDS staging.

template <int K>
__global__ __launch_bounds__(256) void gemm_kernel(const float* __restrict__ x,
                                                   const float* __restrict__ W,
                                                   float* __restrict__ hs, int N) {
    constexpr int KC = (K < 32) ? K : 32;
    __shared__ float xs[64][KC];
    __shared__ float ws[KC][128];
    int t = threadIdx.x;
    int cg4 = (t & 31) * 4;   // col 0..124
    int rg8 = (t >> 5) * 8;   // row 0..56
    int row0 = blockIdx.x * 64;
    float acc[8][4];
#pragma unroll
    for (int i = 0; i < 8; ++i)
#pragma unroll
        for (int j = 0; j < 4; ++j) acc[i][j] = 0.f;

    for (int k0 = 0; k0 < K; k0 += KC) {
        // stage x tile (64 x KC)
        constexpr int XV = 64 * KC / 4;      // float4 count
        constexpr int KV = KC / 4;           // float4 per row
        for (int v = t; v < XV; v += 256) {
            int r = v / KV, kk = (v % KV) * 4;
            int rr = row0 + r;
            float4 val = make_float4(0.f, 0.f, 0.f, 0.f);
            if (rr < N) val = *(const float4*)&x[(size_t)rr * K + k0 + kk];
            *(float4*)&xs[r][kk] = val;
        }
        // stage W chunk (KC x 128, contiguous)
        constexpr int WV = KC * 128 / 4;
        const float4* Wv = (const float4*)&W[(size_t)k0 * 128];
        for (int v = t; v < WV; v += 256) ((float4*)&ws[0][0])[v] = Wv[v];
        __syncthreads();

#pragma unroll
        for (int k = 0; k < KC; k += 4) {
            float4 w0 = *(const float4*)&ws[k + 0][cg4];
            float4 w1 = *(const float4*)&ws[k + 1][cg4];
            float4 w2 = *(const float4*)&ws[k + 2][cg4];
            float4 w3 = *(const float4*)&ws[k + 3][cg4];
#pragma unroll
            for (int i = 0; i < 8; ++i) {
                float4 xv = *(const float4*)&xs[rg8 + i][k];
                acc[i][0] += xv.x * w0.x + xv.y * w1.x + xv.z * w2.x + xv.w * w3.x;
                acc[i][1] += xv.x * w0.y + xv.y * w1.y + xv.z * w2.y + xv.w * w3.y;
                acc[i][2] += xv.x * w0.z + xv.y * w1.z + xv.z * w2.z + xv.w * w3.z;
                acc[i][3] += xv.x * w0.w + xv.y * w1.w + xv.z * w2.w + xv.w * w3.w;
            }
        }
        __syncthreads();
    }
#pragma unroll
    for (int i = 0; i < 8; ++i) {
        int rr = row0 + rg8 + i;
        if (rr < N)
            *(float4*)&hs[(size_t)rr * 128 + cg4] =
                make_float4(acc[i][0], acc[i][1], acc[i][2], acc[i][3]);
    }
}

// ================= multi-score: sc[n][P] = x[n,:] @ fold[K][P] =================

template <int K, int P>
__global__ void scores_multi(const float* __restrict__ x, const float* __restrict__ fold,
                             float* __restrict__ sc, int N) {
    __shared__ float sf[K * P];
    for (int i = threadIdx.x; i < K * P; i += 256) sf[i] = fold[i];
    __syncthreads();
    int n = blockIdx.x * 256 + threadIdx.x;
    if (n >= N) return;
    float a[P];
#pragma unroll
    for (int p = 0; p < P; ++p) a[p] = 0.f;
    const float* xp = x + (size_t)n * K;
    for (int k = 0; k < K; k += 4) {
        float4 xv = *(const float4*)&xp[k];
#pragma unroll
        for (int p = 0; p < P; ++p)
            a[p] += xv.x * sf[k * P + p] + xv.y * sf[(k + 1) * P + p] +
                    xv.z * sf[(k + 2) * P + p] + xv.w * sf[(k + 3) * P + p];
    }
    float* o = sc + (size_t)n * P;
    *(float4*)o = make_float4(a[0], a[1], a[2], a[3]);
    if (P == 8) *(float4*)(o + 4) = make_float4(a[4], a[5], a[6], a[7]);
}

// ================= pass1 (all rels): ex[j] = exp(lrelu(es+ed)) in CSR slot order =================

__global__ void pass1_all(const int* __restrict__ cs_rr, const int* __restrict__ cd_rr,
                          const int* __restrict__ cs_vr, const int* __restrict__ cd_vr,
                          const int* __restrict__ cs_rv, const int* __restrict__ cd_rv,
                          const float* __restrict__ scR, const float* __restrict__ scV,
                          float* __restrict__ ex) {
    int j = blockIdx.x * blockDim.x + threadIdx.x;
    if (j >= ETOT_) return;
    float e0, e1;
    if (j < ERR_) {
        int s = cs_rr[j], d = cd_rr[j];
        e0 = scR[s * 8 + 0] + scR[d * 8 + 2];
        e1 = scR[s * 8 + 1] + scR[d * 8 + 3];
    } else if (j < ERR_ + EVR_) {
        int jj = j - ERR_;
        int s = cs_vr[jj], d = cd_vr[jj];
        e0 = scV[s * 4 + 0] + scR[d * 8 + 4];
        e1 = scV[s * 4 + 1] + scR[d * 8 + 5];
    } else {
        int jj = j - ERR_ - EVR_;
        int s = cs_rv[jj], d = cd_rv[jj];
        e0 = scR[s * 8 + 6] + scV[d * 4 + 2];
        e1 = scR[s * 8 + 7] + scV[d * 4 + 3];
    }
    e0 = (e0 >= 0.f) ? e0 : NEG_ * e0;
    e1 = (e1 >= 0.f) ? e1 : NEG_ * e1;
    ex[(size_t)j * 2 + 0] = __expf(e0);
    ex[(size_t)j * 2 + 1] = __expf(e1);
}

// ================= gather-aggregate =================

__device__ __forceinline__ float agg_rel(int node, int t, int lane, int h,
                                         const int* __restrict__ row, const int* __restrict__ csr_src,
                                         const float* __restrict__ ex, const float* __restrict__ hs) {
    int r0 = row[node], r1 = row[node + 1];
    float den = 0.f;
    for (int j = r0 + lane; j < r1; j += 64) den += ex[(size_t)j * 2 + h];
#pragma unroll
    for (int off = 32; off; off >>= 1) den += __shfl_xor(den, off);
    float acc = 0.f;
    if (r1 > r0) {
        float inv = 1.f / den;
        for (int j = r0; j < r1; ++j) {
            int s = csr_src[j];
            acc += hs[(size_t)s * 128 + t] * (ex[(size_t)j * 2 + h] * inv);
        }
    }
    return acc;
}

__global__ void agg_req(const int* __restrict__ row_rr, const int* __restrict__ cs_rr,
                        const float* __restrict__ ex_rr, const float* __restrict__ hs_rr,
                        const int* __restrict__ row_vr, const int* __restrict__ cs_vr,
                        const float* __restrict__ ex_vr, const float* __restrict__ hs_vr,
                        float* __restrict__ o, int N) {
    int node = blockIdx.x * 2 + (threadIdx.x >> 7);
    if (node >= N) return;
    int t = threadIdx.x & 127;
    int lane = t & 63;
    int h = t >> 6;
    float acc = agg_rel(node, t, lane, h, row_rr, cs_rr, ex_rr, hs_rr)
              + agg_rel(node, t, lane, h, row_vr, cs_vr, ex_vr, hs_vr);
    o[(size_t)node * 128 + t] = acc * 0.5f;
}

__global__ void agg_veh(const int* __restrict__ row, const int* __restrict__ cs,
                        const float* __restrict__ ex, const float* __restrict__ hs,
                        float* __restrict__ o, int N) {
    int node = blockIdx.x * 2 + (threadIdx.x >> 7);
    if (node >= N) return;
    int t = threadIdx.x & 127;
    int lane = t & 63;
    int h = t >> 6;
    o[(size_t)node * 128 + t] = agg_rel(node, t, lane, h, row, cs, ex, hs);
}

// ================= BatchNorm (training stats) + leaky-relu, both node types =================
// s4 layout: [0..127] sum_req, [128..255] sum_veh, [256..383] sumsq_req, [384..511] sumsq_veh

__global__ void bn_stats_all(const float* __restrict__ o_r, const float* __restrict__ o_v,
                             float* __restrict__ s4) {
    int b = blockIdx.x;
    int c = threadIdx.x;  // 128
    const float* o; int N; int r0; int soff;
    if (b < 157) { o = o_r; N = NR_; r0 = b * 256; soff = 0; }
    else         { o = o_v; N = NV_; r0 = (b - 157) * 256; soff = 128; }
    int rend = r0 + 256; if (rend > N) rend = N;
    float s = 0.f, s2 = 0.f;
    for (int r = r0; r < rend; ++r) {
        float v = o[(size_t)r * 128 + c];
        s += v; s2 += v * v;
    }
    atomicAdd(&s4[soff + c], s);
    atomicAdd(&s4[256 + soff + c], s2);
}

__global__ void bn_norm_all(const float* __restrict__ o_r, const float* __restrict__ o_v,
                            const float* __restrict__ s4,
                            const float* __restrict__ gammaL, const float* __restrict__ betaL,
                            float* __restrict__ xr, float* __restrict__ xv) {
    size_t idx = blockIdx.x * (size_t)256 + threadIdx.x;
    const size_t nr = (size_t)NR_ * 128;
    const float* o; float* x; int soff; float invN; size_t i;
    if (idx < nr) { o = o_r; x = xr; soff = 0;   invN = 1.f / NR_; i = idx; }
    else          { o = o_v; x = xv; soff = 128; invN = 1.f / NV_; i = idx - nr; }
    int c = (int)(i & 127);
    float mu = s4[soff + c] * invN;
    float var = s4[256 + soff + c] * invN - mu * mu;
    float v = (o[i] - mu) * rsqrtf(var + EPS_) * gammaL[soff + c] + betaL[soff + c];
    x[i] = (v >= 0.f) ? v : NEG_ * v;
}

// ================= final head =================

__global__ void final_edge_all(const int* __restrict__ ei_rr, const int* __restrict__ ei_vr,
                               const int* __restrict__ ei_rv,
                               const float* __restrict__ ea_rr, const float* __restrict__ ea_vr,
                               const float* __restrict__ ea_rv,
                               const float* __restrict__ ssR, const float* __restrict__ ssV,
                               const float* __restrict__ wp2, const float* __restrict__ cterm,
                               float* __restrict__ out) {
    int j = blockIdx.x * blockDim.x + threadIdx.x;
    if (j >= ETOT_) return;
    int rel, jj;
    const int* src; const int* dst; const float* ea; const float* ss; const float* sd; float* o;
    if (j < ERR_) {
        rel = 0; jj = j; src = ei_rr; dst = ei_rr + ERR_; ea = ea_rr; ss = ssR; sd = ssR; o = out;
    } else if (j < ERR_ + EVR_) {
        rel = 1; jj = j - ERR_; src = ei_vr; dst = ei_vr + EVR_; ea = ea_vr; ss = ssV; sd = ssR;
        o = out + (size_t)ERR_ * 2;
    } else {
        rel = 2; jj = j - ERR_ - EVR_; src = ei_rv; dst = ei_rv + ERV_; ea = ea_rv; ss = ssR; sd = ssV;
        o = out + (size_t)(ERR_ + EVR_) * 2;
    }
    int s = src[jj], d = dst[jj];
    float l0 = ss[s * 4 + 0] + sd[d * 4 + 2] + cterm[rel * 2 + 0];
    float l1 = ss[s * 4 + 1] + sd[d * 4 + 3] + cterm[rel * 2 + 1];
    const float* w = wp2 + rel * 16;
#pragma unroll
    for (int k = 0; k < 8; ++k) {
        float v = ea[(size_t)jj * 8 + k];
        l0 += v * w[k * 2 + 0];
        l1 += v * w[k * 2 + 1];
    }
    float m = fmaxf(l0, l1);
    float p0 = __expf(l0 - m), p1 = __expf(l1 - m);
    float inv = 1.f / (p0 + p1);
    o[(size_t)jj * 2 + 0] = p0 * inv;
    o[(size_t)jj * 2 + 1] = p1 * inv;
}

// ================= host orchestration =================

extern "C" void kernel_launch(void* const* d_in, const int* in_sizes, int n_in,
                              void* d_out, int out_size, void* d_ws, size_t ws_size,
                              hipStream_t stream) {
    const float* x_req = (const float*)d_in[0];
    const float* x_veh = (const float*)d_in[1];
    const int* ei_rr = (const int*)d_in[2];
    const int* ei_vr = (const int*)d_in[3];
    const int* ei_rv = (const int*)d_in[4];
    const float* ea_rr = (const float*)d_in[5];
    const float* ea_vr = (const float*)d_in[6];
    const float* ea_rv = (const float*)d_in[7];
    const float* Wsrc1 = (const float*)d_in[8];
    const float* Wdst1 = (const float*)d_in[9];
    const float* asrc1 = (const float*)d_in[10];
    const float* adst1 = (const float*)d_in[11];
    const float* Wsrc2 = (const float*)d_in[13];
    const float* Wdst2 = (const float*)d_in[14];
    const float* asrc2 = (const float*)d_in[15];
    const float* adst2 = (const float*)d_in[16];
    const float* bn_gamma = (const float*)d_in[18];   // [2][2][128]
    const float* bn_beta  = (const float*)d_in[19];
    const float* Wp   = (const float*)d_in[20];
    const float* bp   = (const float*)d_in[21];
    const float* Wlin = (const float*)d_in[22];
    const float* blin = (const float*)d_in[23];
    float* out = (float*)d_out;

    // ---- workspace ----
    float* w = (float*)d_ws;
    size_t off = 0;
    float* xr    = w + off; off += (size_t)NR_ * 128;
    float* xv    = w + off; off += (size_t)NV_ * 128;
    float* hs_a  = w + off; off += (size_t)NR_ * 128;   // req-src proj (rr, then rv)
    float* hs_b  = w + off; off += (size_t)NV_ * 128;   // veh-src proj (vr)
    float* o_r   = w + off; off += (size_t)NR_ * 128;
    float* o_v   = w + off; off += (size_t)NV_ * 128;
    float* scR   = w + off; off += (size_t)NR_ * 8;
    float* scV   = w + off; off += (size_t)NV_ * 4;
    float* ex    = w + off; off += (size_t)ETOT_ * 2;
    float* s4    = w + off; off += 512;
    float* foldR = w + off; off += 2 * 128 * 8;
    float* foldV = w + off; off += 2 * 128 * 4;
    float* wp2   = w + off; off += 48;
    float* cterm = w + off; off += 8;
    float* fw    = w + off; off += 512;
    float* ssR   = w + off; off += (size_t)NR_ * 4;
    float* ssV   = w + off; off += (size_t)NV_ * 4;
    int* iw = (int*)(w + off);
    size_t ioff = 0;
    int* row_rr = iw + ioff; ioff += NR_ + 1;
    int* row_vr = iw + ioff; ioff += NR_ + 1;
    int* row_rv = iw + ioff; ioff += NV_ + 1;
    int* cur_rr = iw + ioff; ioff += NR_;      // contiguous cur block for one memset
    int* cur_vr = iw + ioff; ioff += NR_;
    int* cur_rv = iw + ioff; ioff += NV_;
    int* cs_rr = iw + ioff; ioff += ERR_;
    int* cd_rr = iw + ioff; ioff += ERR_;
    int* cs_vr = iw + ioff; ioff += EVR_;
    int* cd_vr = iw + ioff; ioff += EVR_;
    int* cs_rv = iw + ioff; ioff += ERV_;
    int* cd_rv = iw + ioff; ioff += ERV_;

    float* ex_rr = ex;
    float* ex_vr = ex + (size_t)ERR_ * 2;
    float* ex_rv = ex + (size_t)(ERR_ + EVR_) * 2;

    // ---- precompute folds ----
    precompute_kernel<<<14, 128, 0, stream>>>(Wsrc1, Wdst1, asrc1, adst1, Wsrc2, Wdst2, asrc2, adst2,
                                              Wp, bp, Wlin, blin, foldR, foldV, wp2, cterm, fw);

    // ---- CSR build ----
    hipMemsetAsync(cur_rr, 0, (2 * NR_ + NV_) * sizeof(int), stream);
    hist_all<<<(ETOT_ + 255) / 256, 256, 0, stream>>>(ei_rr + ERR_, ei_vr + EVR_, ei_rv + ERV_,
                                                      cur_rr, cur_vr, cur_rv);
    scan3_kernel<<<3, 1024, 0, stream>>>(cur_rr, row_rr, cur_rr,   // cnt==cur in-place rewrite
                                         cur_vr, row_vr, cur_vr,
                                         cur_rv, row_rv, cur_rv);
    scatter_all<<<(ETOT_ + 255) / 256, 256, 0, stream>>>(ei_rr, ei_vr, ei_rv,
                                                         cur_rr, cur_vr, cur_rv,
                                                         cs_rr, cd_rr, cs_vr, cd_vr, cs_rv, cd_rv);

    for (int l = 0; l < 2; ++l) {
        const float* xri = (l == 0) ? x_req : xr;
        const float* xvi = (l == 0) ? x_veh : xv;
        const float* Ws = (l == 0) ? Wsrc1 : Wsrc2;
        const int KW = (l == 0) ? 16 : 128;
        const float* fR = foldR + (size_t)l * 128 * 8;
        const float* fV = foldV + (size_t)l * 128 * 4;

        if (l == 0) {
            gemm_kernel<16><<<(NR_ + 63) / 64, 256, 0, stream>>>(xri, Ws + 0 * KW * 128, hs_a, NR_);
            gemm_kernel<16><<<(NV_ + 63) / 64, 256, 0, stream>>>(xvi, Ws + 1 * KW * 128, hs_b, NV_);
            scores_multi<16, 8><<<(NR_ + 255) / 256, 256, 0, stream>>>(xri, fR, scR, NR_);
            scores_multi<16, 4><<<(NV_ + 255) / 256, 256, 0, stream>>>(xvi, fV, scV, NV_);
        } else {
            gemm_kernel<128><<<(NR_ + 63) / 64, 256, 0, stream>>>(xri, Ws + 0 * KW * 128, hs_a, NR_);
            gemm_kernel<128><<<(NV_ + 63) / 64, 256, 0, stream>>>(xvi, Ws + 1 * KW * 128, hs_b, NV_);
            scores_multi<128, 8><<<(NR_ + 255) / 256, 256, 0, stream>>>(xri, fR, scR, NR_);
            scores_multi<128, 4><<<(NV_ + 255) / 256, 256, 0, stream>>>(xvi, fV, scV, NV_);
        }
        pass1_all<<<(ETOT_ + 255) / 256, 256, 0, stream>>>(cs_rr, cd_rr, cs_vr, cd_vr, cs_rv, cd_rv,
                                                           scR, scV, ex);
        agg_req<<<(NR_ + 1) / 2, 256, 0, stream>>>(row_rr, cs_rr, ex_rr, hs_a,
                                                   row_vr, cs_vr, ex_vr, hs_b, o_r, NR_);
        // rv projection reuses hs_a (consumed by agg_req)
        if (l == 0)
            gemm_kernel<16><<<(NR_ + 63) / 64, 256, 0, stream>>>(xri, Ws + 2 * KW * 128, hs_a, NR_);
        else
            gemm_kernel<128><<<(NR_ + 63) / 64, 256, 0, stream>>>(xri, Ws + 2 * KW * 128, hs_a, NR_);
        agg_veh<<<(NV_ + 1) / 2, 256, 0, stream>>>(row_rv, cs_rv, ex_rv, hs_a, o_v, NV_);

        hipMemsetAsync(s4, 0, 512 * sizeof(float), stream);
        bn_stats_all<<<157 + 16, 128, 0, stream>>>(o_r, o_v, s4);
        bn_norm_all<<<(int)(((size_t)(NR_ + NV_) * 128 + 255) / 256), 256, 0, stream>>>(
            o_r, o_v, s4, bn_gamma + l * 256, bn_beta + l * 256, xr, xv);
    }

    // ---- final head ----
    scores_multi<128, 4><<<(NR_ + 255) / 256, 256, 0, stream>>>(xr, fw, ssR, NR_);
    scores_multi<128, 4><<<(NV_ + 255) / 256, 256, 0, stream>>>(xv, fw, ssV, NV_);
    final_edge_all<<<(ETOT_ + 255) / 256, 256, 0, stream>>>(ei_rr, ei_vr, ei_rv, ea_rr, ea_vr, ea_rv,
                                                            ssR, ssV, wp2, cterm, out);
}

// Round 4
// 747.409 us; speedup vs baseline: 2.4541x; 1.2335x over previous
//
#include <hip/hip_runtime.h>
#include <hip/hip_bf16.h>

#define NR_ 40000
#define NV_ 4000
#define ERR_ 400000
#define EVR_ 150000
#define ERV_ 150000
#define ETOT_ (ERR_ + EVR_ + ERV_)
#define NEG_ 0.2f
#define EPS_ 1e-5f

// ================= precompute: attention folds, edge-proj fold, final fold =================
// foldR[l][k][8] cols: es_rr(0,1) ed_rr(2,3) ed_vr(4,5) es_rv(6,7)
// foldV[l][k][4] cols: es_vr(0,1) ed_rv(2,3)
// fw[k][4]: Wlin cols for src half (0,1) and dst half (2,3)
__global__ void precompute_kernel(const float* __restrict__ Wsrc1, const float* __restrict__ Wdst1,
                                  const float* __restrict__ asrc1, const float* __restrict__ adst1,
                                  const float* __restrict__ Wsrc2, const float* __restrict__ Wdst2,
                                  const float* __restrict__ asrc2, const float* __restrict__ adst2,
                                  const float* __restrict__ Wp, const float* __restrict__ bp,
                                  const float* __restrict__ Wlin, const float* __restrict__ blin,
                                  float* __restrict__ foldR, float* __restrict__ foldV,
                                  float* __restrict__ wp2, float* __restrict__ cterm,
                                  float* __restrict__ fw) {
    int b = blockIdx.x;
    int t = threadIdx.x;  // 128
    if (b < 12) {
        int layer = b / 6, rel = (b % 6) / 2, side = b & 1;
        int K = (layer == 0) ? 16 : 128;
        const float* W = (layer == 0) ? (side ? Wdst1 : Wsrc1) : (side ? Wdst2 : Wsrc2);
        const float* a = (layer == 0) ? (side ? adst1 : asrc1) : (side ? adst2 : asrc2);
        W += (size_t)rel * K * 128;
        a += rel * 128;
        float* dst; int P; int colbase;
        if (rel == 0 && side == 0)      { dst = foldR; P = 8; colbase = 0; }
        else if (rel == 0)              { dst = foldR; P = 8; colbase = 2; }
        else if (rel == 1 && side == 0) { dst = foldV; P = 4; colbase = 0; }
        else if (rel == 1)              { dst = foldR; P = 8; colbase = 4; }
        else if (side == 0)             { dst = foldR; P = 8; colbase = 6; }
        else                            { dst = foldV; P = 4; colbase = 2; }
        dst += (size_t)layer * 128 * P;
        if (t < K) {
            for (int h = 0; h < 2; ++h) {
                float s = 0.f;
                for (int c = 0; c < 64; ++c) s += W[t * 128 + h * 64 + c] * a[h * 64 + c];
                dst[t * P + colbase + h] = s;
            }
        }
    } else if (b == 12) {
        if (t < 48) {
            int i = t / 16, k = (t / 2) % 8, o = t & 1;
            float s = 0.f;
            for (int c = 0; c < 64; ++c) s += Wp[(i * 8 + k) * 64 + c] * Wlin[(128 + c) * 2 + o];
            wp2[t] = s;
        } else if (t < 54) {
            int i = (t - 48) / 2, o = (t - 48) & 1;
            float s = blin[o];
            for (int c = 0; c < 64; ++c) s += bp[i * 64 + c] * Wlin[(128 + c) * 2 + o];
            cterm[i * 2 + o] = s;
        }
    } else {
        for (int idx = t; idx < 512; idx += 128) {
            int k = idx >> 2, c = idx & 3;
            fw[idx] = Wlin[(k + ((c >= 2) ? 192 : 0)) * 2 + (c & 1)];
        }
    }
}

// ================= CSR build =================

__global__ void hist_all(const int* __restrict__ dst_rr, const int* __restrict__ dst_vr,
                         const int* __restrict__ dst_rv, int* __restrict__ cnt_rr,
                         int* __restrict__ cnt_vr, int* __restrict__ cnt_rv) {
    int j = blockIdx.x * blockDim.x + threadIdx.x;
    if (j < ERR_) atomicAdd(&cnt_rr[dst_rr[j]], 1);
    else if (j < ERR_ + EVR_) atomicAdd(&cnt_vr[dst_vr[j - ERR_]], 1);
    else if (j < ETOT_) atomicAdd(&cnt_rv[dst_rv[j - ERR_ - EVR_]], 1);
}

__global__ void scan3_kernel(const int* __restrict__ cnt_rr, int* __restrict__ row_rr, int* __restrict__ cur_rr,
                             const int* __restrict__ cnt_vr, int* __restrict__ row_vr, int* __restrict__ cur_vr,
                             const int* __restrict__ cnt_rv, int* __restrict__ row_rv, int* __restrict__ cur_rv) {
    const int* cnt; int* row; int* cur; int N;
    if (blockIdx.x == 0)      { cnt = cnt_rr; row = row_rr; cur = cur_rr; N = NR_; }
    else if (blockIdx.x == 1) { cnt = cnt_vr; row = row_vr; cur = cur_vr; N = NR_; }
    else                      { cnt = cnt_rv; row = row_rv; cur = cur_rv; N = NV_; }
    int t = threadIdx.x;
    int CH = (N + 1023) / 1024;
    int base = t * CH;
    int end = base + CH; if (end > N) end = N;
    int s = 0;
    for (int i = base; i < end; ++i) s += cnt[i];
    __shared__ int buf[1024];
    buf[t] = s;
    __syncthreads();
    for (int off = 1; off < 1024; off <<= 1) {
        int v = (t >= off) ? buf[t - off] : 0;
        __syncthreads();
        buf[t] += v;
        __syncthreads();
    }
    int run = buf[t] - s;
    for (int i = base; i < end; ++i) { row[i] = run; cur[i] = run; run += cnt[i]; }
    if (t == 0) row[N] = buf[1023];
}

__global__ void scatter_all(const int* __restrict__ ei_rr, const int* __restrict__ ei_vr,
                            const int* __restrict__ ei_rv,
                            int* __restrict__ cur_rr, int* __restrict__ cur_vr, int* __restrict__ cur_rv,
                            int* __restrict__ cs_rr, int* __restrict__ cd_rr,
                            int* __restrict__ cs_vr, int* __restrict__ cd_vr,
                            int* __restrict__ cs_rv, int* __restrict__ cd_rv) {
    int j = blockIdx.x * blockDim.x + threadIdx.x;
    const int* src; const int* dst; int* cur; int* cs; int* cd; int jj;
    if (j < ERR_)             { jj = j;               src = ei_rr; dst = ei_rr + ERR_; cur = cur_rr; cs = cs_rr; cd = cd_rr; }
    else if (j < ERR_ + EVR_) { jj = j - ERR_;        src = ei_vr; dst = ei_vr + EVR_; cur = cur_vr; cs = cs_vr; cd = cd_vr; }
    else if (j < ETOT_)       { jj = j - ERR_ - EVR_; src = ei_rv; dst = ei_rv + ERV_; cur = cur_rv; cs = cs_rv; cd = cd_rv; }
    else return;
    int d = dst[jj];
    int p = atomicAdd(&cur[d], 1);
    cs[p] = src[jj];
    cd[p] = d;
}

// ================= register-blocked GEMM: hs = x @ W  ([N,K] @ [K,128]) =================

template <int K>
__global__ __launch_bounds__(256) void gemm_kernel(const float* __restrict__ x,
                                                   const float* __restrict__ W,
                                                   float* __restrict__ hs, int N) {
    constexpr int KC = (K < 32) ? K : 32;
    __shared__ float xs[64][KC];
    __shared__ float ws[KC][128];
    int t = threadIdx.x;
    int cg4 = (t & 31) * 4;
    int rg8 = (t >> 5) * 8;
    int row0 = blockIdx.x * 64;
    float acc[8][4];
#pragma unroll
    for (int i = 0; i < 8; ++i)
#pragma unroll
        for (int j = 0; j < 4; ++j) acc[i][j] = 0.f;

    for (int k0 = 0; k0 < K; k0 += KC) {
        constexpr int XV = 64 * KC / 4;
        constexpr int KV = KC / 4;
        for (int v = t; v < XV; v += 256) {
            int r = v / KV, kk = (v % KV) * 4;
            int rr = row0 + r;
            float4 val = make_float4(0.f, 0.f, 0.f, 0.f);
            if (rr < N) val = *(const float4*)&x[(size_t)rr * K + k0 + kk];
            *(float4*)&xs[r][kk] = val;
        }
        constexpr int WV = KC * 128 / 4;
        const float4* Wv = (const float4*)&W[(size_t)k0 * 128];
        for (int v = t; v < WV; v += 256) ((float4*)&ws[0][0])[v] = Wv[v];
        __syncthreads();

#pragma unroll
        for (int k = 0; k < KC; k += 4) {
            float4 w0 = *(const float4*)&ws[k + 0][cg4];
            float4 w1 = *(const float4*)&ws[k + 1][cg4];
            float4 w2 = *(const float4*)&ws[k + 2][cg4];
            float4 w3 = *(const float4*)&ws[k + 3][cg4];
#pragma unroll
            for (int i = 0; i < 8; ++i) {
                float4 xv = *(const float4*)&xs[rg8 + i][k];
                acc[i][0] += xv.x * w0.x + xv.y * w1.x + xv.z * w2.x + xv.w * w3.x;
                acc[i][1] += xv.x * w0.y + xv.y * w1.y + xv.z * w2.y + xv.w * w3.y;
                acc[i][2] += xv.x * w0.z + xv.y * w1.z + xv.z * w2.z + xv.w * w3.z;
                acc[i][3] += xv.x * w0.w + xv.y * w1.w + xv.z * w2.w + xv.w * w3.w;
            }
        }
        __syncthreads();
    }
#pragma unroll
    for (int i = 0; i < 8; ++i) {
        int rr = row0 + rg8 + i;
        if (rr < N)
            *(float4*)&hs[(size_t)rr * 128 + cg4] =
                make_float4(acc[i][0], acc[i][1], acc[i][2], acc[i][3]);
    }
}

// ================= multi-score: sc[n][P] = x[n,:] @ fold[K][P] =================

template <int K, int P>
__global__ void scores_multi(const float* __restrict__ x, const float* __restrict__ fold,
                             float* __restrict__ sc, int N) {
    __shared__ float sf[K * P];
    for (int i = threadIdx.x; i < K * P; i += 256) sf[i] = fold[i];
    __syncthreads();
    int n = blockIdx.x * 256 + threadIdx.x;
    if (n >= N) return;
    float a[P];
#pragma unroll
    for (int p = 0; p < P; ++p) a[p] = 0.f;
    const float* xp = x + (size_t)n * K;
    for (int k = 0; k < K; k += 4) {
        float4 xv = *(const float4*)&xp[k];
#pragma unroll
        for (int p = 0; p < P; ++p)
            a[p] += xv.x * sf[k * P + p] + xv.y * sf[(k + 1) * P + p] +
                    xv.z * sf[(k + 2) * P + p] + xv.w * sf[(k + 3) * P + p];
    }
    float* o = sc + (size_t)n * P;
    *(float4*)o = make_float4(a[0], a[1], a[2], a[3]);
    if (P == 8) *(float4*)(o + 4) = make_float4(a[4], a[5], a[6], a[7]);
}

// ================= pass1 (all rels): ex[j] = exp(lrelu(es+ed)) in CSR slot order =================

__global__ void pass1_all(const int* __restrict__ cs_rr, const int* __restrict__ cd_rr,
                          const int* __restrict__ cs_vr, const int* __restrict__ cd_vr,
                          const int* __restrict__ cs_rv, const int* __restrict__ cd_rv,
                          const float* __restrict__ scR, const float* __restrict__ scV,
                          float* __restrict__ ex) {
    int j = blockIdx.x * blockDim.x + threadIdx.x;
    if (j >= ETOT_) return;
    float e0, e1;
    if (j < ERR_) {
        int s = cs_rr[j], d = cd_rr[j];
        e0 = scR[s * 8 + 0] + scR[d * 8 + 2];
        e1 = scR[s * 8 + 1] + scR[d * 8 + 3];
    } else if (j < ERR_ + EVR_) {
        int jj = j - ERR_;
        int s = cs_vr[jj], d = cd_vr[jj];
        e0 = scV[s * 4 + 0] + scR[d * 8 + 4];
        e1 = scV[s * 4 + 1] + scR[d * 8 + 5];
    } else {
        int jj = j - ERR_ - EVR_;
        int s = cs_rv[jj], d = cd_rv[jj];
        e0 = scR[s * 8 + 6] + scV[d * 4 + 2];
        e1 = scR[s * 8 + 7] + scV[d * 4 + 3];
    }
    e0 = (e0 >= 0.f) ? e0 : NEG_ * e0;
    e1 = (e1 >= 0.f) ? e1 : NEG_ * e1;
    ex[(size_t)j * 2 + 0] = __expf(e0);
    ex[(size_t)j * 2 + 1] = __expf(e1);
}

// ================= gather-aggregate: 1 wave per node, float2 per lane, unroll-4 =================
// lane owns features {2*lane, 2*lane+1}; head = lane>>5 (features 0..63 -> head0, 64..127 -> head1)
// single pass: acc = sum(hs*ex), den = sum(ex), result = acc/den (0 if no edges)

__device__ __forceinline__ void agg_rel_f2(int node, int lane,
                                           const int* __restrict__ row, const int* __restrict__ cs,
                                           const float* __restrict__ ex, const float* __restrict__ hs,
                                           float& ox, float& oy) {
    int r0 = row[node], r1 = row[node + 1];
    if (r1 <= r0) return;
    float ax = 0.f, ay = 0.f, den = 0.f;
    int j = r0;
    for (; j + 4 <= r1; j += 4) {
        int s0 = cs[j + 0], s1 = cs[j + 1], s2 = cs[j + 2], s3 = cs[j + 3];
        float2 e0 = *(const float2*)&ex[(size_t)(j + 0) * 2];
        float2 e1 = *(const float2*)&ex[(size_t)(j + 1) * 2];
        float2 e2 = *(const float2*)&ex[(size_t)(j + 2) * 2];
        float2 e3 = *(const float2*)&ex[(size_t)(j + 3) * 2];
        float2 v0 = *(const float2*)&hs[(size_t)s0 * 128 + lane * 2];
        float2 v1 = *(const float2*)&hs[(size_t)s1 * 128 + lane * 2];
        float2 v2 = *(const float2*)&hs[(size_t)s2 * 128 + lane * 2];
        float2 v3 = *(const float2*)&hs[(size_t)s3 * 128 + lane * 2];
        float w0 = (lane < 32) ? e0.x : e0.y;
        float w1 = (lane < 32) ? e1.x : e1.y;
        float w2 = (lane < 32) ? e2.x : e2.y;
        float w3 = (lane < 32) ? e3.x : e3.y;
        ax += v0.x * w0 + v1.x * w1 + v2.x * w2 + v3.x * w3;
        ay += v0.y * w0 + v1.y * w1 + v2.y * w2 + v3.y * w3;
        den += w0 + w1 + w2 + w3;
    }
    for (; j < r1; ++j) {
        int s = cs[j];
        float2 e = *(const float2*)&ex[(size_t)j * 2];
        float2 v = *(const float2*)&hs[(size_t)s * 128 + lane * 2];
        float w = (lane < 32) ? e.x : e.y;
        ax += v.x * w;
        ay += v.y * w;
        den += w;
    }
    float inv = 1.f / den;
    ox += ax * inv;
    oy += ay * inv;
}

__global__ __launch_bounds__(256) void agg_req(
        const int* __restrict__ row_rr, const int* __restrict__ cs_rr,
        const float* __restrict__ ex_rr, const float* __restrict__ hs_rr,
        const int* __restrict__ row_vr, const int* __restrict__ cs_vr,
        const float* __restrict__ ex_vr, const float* __restrict__ hs_vr,
        float* __restrict__ o, int N) {
    int node = blockIdx.x * 4 + (threadIdx.x >> 6);
    if (node >= N) return;
    int lane = threadIdx.x & 63;
    float ox = 0.f, oy = 0.f;
    agg_rel_f2(node, lane, row_rr, cs_rr, ex_rr, hs_rr, ox, oy);
    agg_rel_f2(node, lane, row_vr, cs_vr, ex_vr, hs_vr, ox, oy);
    *(float2*)&o[(size_t)node * 128 + lane * 2] = make_float2(ox * 0.5f, oy * 0.5f);
}

__global__ __launch_bounds__(256) void agg_veh(
        const int* __restrict__ row, const int* __restrict__ cs,
        const float* __restrict__ ex, const float* __restrict__ hs,
        float* __restrict__ o, int N) {
    int node = blockIdx.x * 4 + (threadIdx.x >> 6);
    if (node >= N) return;
    int lane = threadIdx.x & 63;
    float ox = 0.f, oy = 0.f;
    agg_rel_f2(node, lane, row, cs, ex, hs, ox, oy);
    *(float2*)&o[(size_t)node * 128 + lane * 2] = make_float2(ox, oy);
}

// ================= BatchNorm (training stats) + leaky-relu, both node types =================
// s4 layout: [0..127] sum_req, [128..255] sum_veh, [256..383] sumsq_req, [384..511] sumsq_veh

__global__ void bn_stats_all(const float* __restrict__ o_r, const float* __restrict__ o_v,
                             float* __restrict__ s4) {
    int b = blockIdx.x;
    int c = threadIdx.x;  // 128
    const float* o; int N; int r0; int soff;
    if (b < 157) { o = o_r; N = NR_; r0 = b * 256; soff = 0; }
    else         { o = o_v; N = NV_; r0 = (b - 157) * 256; soff = 128; }
    int rend = r0 + 256; if (rend > N) rend = N;
    float s = 0.f, s2 = 0.f;
    for (int r = r0; r < rend; ++r) {
        float v = o[(size_t)r * 128 + c];
        s += v; s2 += v * v;
    }
    atomicAdd(&s4[soff + c], s);
    atomicAdd(&s4[256 + soff + c], s2);
}

__global__ void bn_norm_all(const float* __restrict__ o_r, const float* __restrict__ o_v,
                            const float* __restrict__ s4,
                            const float* __restrict__ gammaL, const float* __restrict__ betaL,
                            float* __restrict__ xr, float* __restrict__ xv) {
    size_t idx = blockIdx.x * (size_t)256 + threadIdx.x;
    const size_t nr = (size_t)NR_ * 128;
    const float* o; float* x; int soff; float invN; size_t i;
    if (idx < nr) { o = o_r; x = xr; soff = 0;   invN = 1.f / NR_; i = idx; }
    else          { o = o_v; x = xv; soff = 128; invN = 1.f / NV_; i = idx - nr; }
    int c = (int)(i & 127);
    float mu = s4[soff + c] * invN;
    float var = s4[256 + soff + c] * invN - mu * mu;
    float v = (o[i] - mu) * rsqrtf(var + EPS_) * gammaL[soff + c] + betaL[soff + c];
    x[i] = (v >= 0.f) ? v : NEG_ * v;
}

// ================= final head =================

__global__ void final_edge_all(const int* __restrict__ ei_rr, const int* __restrict__ ei_vr,
                               const int* __restrict__ ei_rv,
                               const float* __restrict__ ea_rr, const float* __restrict__ ea_vr,
                               const float* __restrict__ ea_rv,
                               const float* __restrict__ ssR, const float* __restrict__ ssV,
                               const float* __restrict__ wp2, const float* __restrict__ cterm,
                               float* __restrict__ out) {
    int j = blockIdx.x * blockDim.x + threadIdx.x;
    if (j >= ETOT_) return;
    int rel, jj;
    const int* src; const int* dst; const float* ea; const float* ss; const float* sd; float* o;
    if (j < ERR_) {
        rel = 0; jj = j; src = ei_rr; dst = ei_rr + ERR_; ea = ea_rr; ss = ssR; sd = ssR; o = out;
    } else if (j < ERR_ + EVR_) {
        rel = 1; jj = j - ERR_; src = ei_vr; dst = ei_vr + EVR_; ea = ea_vr; ss = ssV; sd = ssR;
        o = out + (size_t)ERR_ * 2;
    } else {
        rel = 2; jj = j - ERR_ - EVR_; src = ei_rv; dst = ei_rv + ERV_; ea = ea_rv; ss = ssR; sd = ssV;
        o = out + (size_t)(ERR_ + EVR_) * 2;
    }
    int s = src[jj], d = dst[jj];
    float l0 = ss[s * 4 + 0] + sd[d * 4 + 2] + cterm[rel * 2 + 0];
    float l1 = ss[s * 4 + 1] + sd[d * 4 + 3] + cterm[rel * 2 + 1];
    const float* w = wp2 + rel * 16;
#pragma unroll
    for (int k = 0; k < 8; ++k) {
        float v = ea[(size_t)jj * 8 + k];
        l0 += v * w[k * 2 + 0];
        l1 += v * w[k * 2 + 1];
    }
    float m = fmaxf(l0, l1);
    float p0 = __expf(l0 - m), p1 = __expf(l1 - m);
    float inv = 1.f / (p0 + p1);
    o[(size_t)jj * 2 + 0] = p0 * inv;
    o[(size_t)jj * 2 + 1] = p1 * inv;
}

// ================= host orchestration =================

extern "C" void kernel_launch(void* const* d_in, const int* in_sizes, int n_in,
                              void* d_out, int out_size, void* d_ws, size_t ws_size,
                              hipStream_t stream) {
    const float* x_req = (const float*)d_in[0];
    const float* x_veh = (const float*)d_in[1];
    const int* ei_rr = (const int*)d_in[2];
    const int* ei_vr = (const int*)d_in[3];
    const int* ei_rv = (const int*)d_in[4];
    const float* ea_rr = (const float*)d_in[5];
    const float* ea_vr = (const float*)d_in[6];
    const float* ea_rv = (const float*)d_in[7];
    const float* Wsrc1 = (const float*)d_in[8];
    const float* Wdst1 = (const float*)d_in[9];
    const float* asrc1 = (const float*)d_in[10];
    const float* adst1 = (const float*)d_in[11];
    const float* Wsrc2 = (const float*)d_in[13];
    const float* Wdst2 = (const float*)d_in[14];
    const float* asrc2 = (const float*)d_in[15];
    const float* adst2 = (const float*)d_in[16];
    const float* bn_gamma = (const float*)d_in[18];   // [2][2][128]
    const float* bn_beta  = (const float*)d_in[19];
    const float* Wp   = (const float*)d_in[20];
    const float* bp   = (const float*)d_in[21];
    const float* Wlin = (const float*)d_in[22];
    const float* blin = (const float*)d_in[23];
    float* out = (float*)d_out;

    // ---- workspace ----
    float* w = (float*)d_ws;
    size_t off = 0;
    float* xr    = w + off; off += (size_t)NR_ * 128;
    float* xv    = w + off; off += (size_t)NV_ * 128;
    float* hs_a  = w + off; off += (size_t)NR_ * 128;
    float* hs_b  = w + off; off += (size_t)NV_ * 128;
    float* o_r   = w + off; off += (size_t)NR_ * 128;
    float* o_v   = w + off; off += (size_t)NV_ * 128;
    float* scR   = w + off; off += (size_t)NR_ * 8;
    float* scV   = w + off; off += (size_t)NV_ * 4;
    float* ex    = w + off; off += (size_t)ETOT_ * 2;
    float* s4    = w + off; off += 512;
    float* foldR = w + off; off += 2 * 128 * 8;
    float* foldV = w + off; off += 2 * 128 * 4;
    float* wp2   = w + off; off += 48;
    float* cterm = w + off; off += 8;
    float* fw    = w + off; off += 512;
    float* ssR   = w + off; off += (size_t)NR_ * 4;
    float* ssV   = w + off; off += (size_t)NV_ * 4;
    int* iw = (int*)(w + off);
    size_t ioff = 0;
    int* row_rr = iw + ioff; ioff += NR_ + 1;
    int* row_vr = iw + ioff; ioff += NR_ + 1;
    int* row_rv = iw + ioff; ioff += NV_ + 1;
    int* cur_rr = iw + ioff; ioff += NR_;
    int* cur_vr = iw + ioff; ioff += NR_;
    int* cur_rv = iw + ioff; ioff += NV_;
    int* cs_rr = iw + ioff; ioff += ERR_;
    int* cd_rr = iw + ioff; ioff += ERR_;
    int* cs_vr = iw + ioff; ioff += EVR_;
    int* cd_vr = iw + ioff; ioff += EVR_;
    int* cs_rv = iw + ioff; ioff += ERV_;
    int* cd_rv = iw + ioff; ioff += ERV_;

    float* ex_rr = ex;
    float* ex_vr = ex + (size_t)ERR_ * 2;
    float* ex_rv = ex + (size_t)(ERR_ + EVR_) * 2;

    // ---- precompute folds ----
    precompute_kernel<<<14, 128, 0, stream>>>(Wsrc1, Wdst1, asrc1, adst1, Wsrc2, Wdst2, asrc2, adst2,
                                              Wp, bp, Wlin, blin, foldR, foldV, wp2, cterm, fw);

    // ---- CSR build ----
    hipMemsetAsync(cur_rr, 0, (2 * NR_ + NV_) * sizeof(int), stream);
    hist_all<<<(ETOT_ + 255) / 256, 256, 0, stream>>>(ei_rr + ERR_, ei_vr + EVR_, ei_rv + ERV_,
                                                      cur_rr, cur_vr, cur_rv);
    scan3_kernel<<<3, 1024, 0, stream>>>(cur_rr, row_rr, cur_rr,
                                         cur_vr, row_vr, cur_vr,
                                         cur_rv, row_rv, cur_rv);
    scatter_all<<<(ETOT_ + 255) / 256, 256, 0, stream>>>(ei_rr, ei_vr, ei_rv,
                                                         cur_rr, cur_vr, cur_rv,
                                                         cs_rr, cd_rr, cs_vr, cd_vr, cs_rv, cd_rv);

    for (int l = 0; l < 2; ++l) {
        const float* xri = (l == 0) ? x_req : xr;
        const float* xvi = (l == 0) ? x_veh : xv;
        const float* Ws = (l == 0) ? Wsrc1 : Wsrc2;
        const int KW = (l == 0) ? 16 : 128;
        const float* fR = foldR + (size_t)l * 128 * 8;
        const float* fV = foldV + (size_t)l * 128 * 4;

        if (l == 0) {
            gemm_kernel<16><<<(NR_ + 63) / 64, 256, 0, stream>>>(xri, Ws + 0 * KW * 128, hs_a, NR_);
            gemm_kernel<16><<<(NV_ + 63) / 64, 256, 0, stream>>>(xvi, Ws + 1 * KW * 128, hs_b, NV_);
            scores_multi<16, 8><<<(NR_ + 255) / 256, 256, 0, stream>>>(xri, fR, scR, NR_);
            scores_multi<16, 4><<<(NV_ + 255) / 256, 256, 0, stream>>>(xvi, fV, scV, NV_);
        } else {
            gemm_kernel<128><<<(NR_ + 63) / 64, 256, 0, stream>>>(xri, Ws + 0 * KW * 128, hs_a, NR_);
            gemm_kernel<128><<<(NV_ + 63) / 64, 256, 0, stream>>>(xvi, Ws + 1 * KW * 128, hs_b, NV_);
            scores_multi<128, 8><<<(NR_ + 255) / 256, 256, 0, stream>>>(xri, fR, scR, NR_);
            scores_multi<128, 4><<<(NV_ + 255) / 256, 256, 0, stream>>>(xvi, fV, scV, NV_);
        }
        pass1_all<<<(ETOT_ + 255) / 256, 256, 0, stream>>>(cs_rr, cd_rr, cs_vr, cd_vr, cs_rv, cd_rv,
                                                           scR, scV, ex);
        agg_req<<<(NR_ + 3) / 4, 256, 0, stream>>>(row_rr, cs_rr, ex_rr, hs_a,
                                                   row_vr, cs_vr, ex_vr, hs_b, o_r, NR_);
        if (l == 0)
            gemm_kernel<16><<<(NR_ + 63) / 64, 256, 0, stream>>>(xri, Ws + 2 * KW * 128, hs_a, NR_);
        else
            gemm_kernel<128><<<(NR_ + 63) / 64, 256, 0, stream>>>(xri, Ws + 2 * KW * 128, hs_a, NR_);
        agg_veh<<<(NV_ + 3) / 4, 256, 0, stream>>>(row_rv, cs_rv, ex_rv, hs_a, o_v, NV_);

        hipMemsetAsync(s4, 0, 512 * sizeof(float), stream);
        bn_stats_all<<<157 + 16, 128, 0, stream>>>(o_r, o_v, s4);
        bn_norm_all<<<(int)(((size_t)(NR_ + NV_) * 128 + 255) / 256), 256, 0, stream>>>(
            o_r, o_v, s4, bn_gamma + l * 256, bn_beta + l * 256, xr, xv);
    }

    // ---- final head ----
    scores_multi<128, 4><<<(NR_ + 255) / 256, 256, 0, stream>>>(xr, fw, ssR, NR_);
    scores_multi<128, 4><<<(NV_ + 255) / 256, 256, 0, stream>>>(xv, fw, ssV, NV_);
    final_edge_all<<<(ETOT_ + 255) / 256, 256, 0, stream>>>(ei_rr, ei_vr, ei_rv, ea_rr, ea_vr, ea_rv,
                                                            ssR, ssV, wp2, cterm, out);
}

// Round 5
// 678.362 us; speedup vs baseline: 2.7039x; 1.1018x over previous
//
#include <hip/hip_runtime.h>
#include <hip/hip_bf16.h>

#define NR_ 40000
#define NV_ 4000
#define ERR_ 400000
#define EVR_ 150000
#define ERV_ 150000
#define ETOT_ (ERR_ + EVR_ + ERV_)
#define NTOT_ (NR_ + NR_ + NV_)          // concatenated node-slot space: rr | vr | rv
#define SCAN_ELEMS 512
#define SCAN_NB ((NTOT_ + SCAN_ELEMS - 1) / SCAN_ELEMS)   // 165
#define NEG_ 0.2f
#define EPS_ 1e-5f

// ================= precompute: attention folds, edge-proj fold, final fold =================
// foldR[l][k][8] cols: es_rr(0,1) ed_rr(2,3) ed_vr(4,5) es_rv(6,7)
// foldV[l][k][4] cols: es_vr(0,1) ed_rv(2,3)
// fw[k][4]: Wlin cols for src half (0,1) and dst half (2,3)
__global__ void precompute_kernel(const float* __restrict__ Wsrc1, const float* __restrict__ Wdst1,
                                  const float* __restrict__ asrc1, const float* __restrict__ adst1,
                                  const float* __restrict__ Wsrc2, const float* __restrict__ Wdst2,
                                  const float* __restrict__ asrc2, const float* __restrict__ adst2,
                                  const float* __restrict__ Wp, const float* __restrict__ bp,
                                  const float* __restrict__ Wlin, const float* __restrict__ blin,
                                  float* __restrict__ foldR, float* __restrict__ foldV,
                                  float* __restrict__ wp2, float* __restrict__ cterm,
                                  float* __restrict__ fw) {
    int b = blockIdx.x;
    int t = threadIdx.x;  // 128
    if (b < 12) {
        int layer = b / 6, rel = (b % 6) / 2, side = b & 1;
        int K = (layer == 0) ? 16 : 128;
        const float* W = (layer == 0) ? (side ? Wdst1 : Wsrc1) : (side ? Wdst2 : Wsrc2);
        const float* a = (layer == 0) ? (side ? adst1 : asrc1) : (side ? adst2 : asrc2);
        W += (size_t)rel * K * 128;
        a += rel * 128;
        float* dst; int P; int colbase;
        if (rel == 0 && side == 0)      { dst = foldR; P = 8; colbase = 0; }
        else if (rel == 0)              { dst = foldR; P = 8; colbase = 2; }
        else if (rel == 1 && side == 0) { dst = foldV; P = 4; colbase = 0; }
        else if (rel == 1)              { dst = foldR; P = 8; colbase = 4; }
        else if (side == 0)             { dst = foldR; P = 8; colbase = 6; }
        else                            { dst = foldV; P = 4; colbase = 2; }
        dst += (size_t)layer * 128 * P;
        if (t < K) {
            for (int h = 0; h < 2; ++h) {
                float s = 0.f;
                for (int c = 0; c < 64; ++c) s += W[t * 128 + h * 64 + c] * a[h * 64 + c];
                dst[t * P + colbase + h] = s;
            }
        }
    } else if (b == 12) {
        if (t < 48) {
            int i = t / 16, k = (t / 2) % 8, o = t & 1;
            float s = 0.f;
            for (int c = 0; c < 64; ++c) s += Wp[(i * 8 + k) * 64 + c] * Wlin[(128 + c) * 2 + o];
            wp2[t] = s;
        } else if (t < 54) {
            int i = (t - 48) / 2, o = (t - 48) & 1;
            float s = blin[o];
            for (int c = 0; c < 64; ++c) s += bp[i * 64 + c] * Wlin[(128 + c) * 2 + o];
            cterm[i * 2 + o] = s;
        }
    } else {
        for (int idx = t; idx < 512; idx += 128) {
            int k = idx >> 2, c = idx & 3;
            fw[idx] = Wlin[(k + ((c >= 2) ? 192 : 0)) * 2 + (c & 1)];
        }
    }
}

// ================= CSR build (concatenated slot space) =================

__global__ void hist_all(const int* __restrict__ ei_rr, const int* __restrict__ ei_vr,
                         const int* __restrict__ ei_rv, int* __restrict__ cnt) {
    int j = blockIdx.x * blockDim.x + threadIdx.x;
    if (j < ERR_) atomicAdd(&cnt[ei_rr[ERR_ + j]], 1);
    else if (j < ERR_ + EVR_) atomicAdd(&cnt[NR_ + ei_vr[EVR_ + (j - ERR_)]], 1);
    else if (j < ETOT_) atomicAdd(&cnt[2 * NR_ + ei_rv[ERV_ + (j - ERR_ - EVR_)]], 1);
}

// k1: per-block totals of 512-element tiles
__global__ __launch_bounds__(256) void scan_reduce(const int* __restrict__ cnt, int* __restrict__ bsum) {
    __shared__ int buf[256];
    int t = threadIdx.x;
    int i0 = blockIdx.x * SCAN_ELEMS + t * 2;
    int s = 0;
    if (i0 + 1 < NTOT_) { int2 v = *(const int2*)&cnt[i0]; s = v.x + v.y; }
    else if (i0 < NTOT_) s = cnt[i0];
    buf[t] = s;
    __syncthreads();
    for (int off = 128; off; off >>= 1) {
        if (t < off) buf[t] += buf[t + off];
        __syncthreads();
    }
    if (t == 0) bsum[blockIdx.x] = buf[0];
}

// k2: one block scans the 165 block sums -> exclusive offsets; also writes row[NTOT_]
__global__ __launch_bounds__(256) void scan_bsums(const int* __restrict__ bsum, int* __restrict__ boff,
                                                  int* __restrict__ row) {
    __shared__ int buf[256];
    int t = threadIdx.x;
    int s = (t < SCAN_NB) ? bsum[t] : 0;
    buf[t] = s;
    __syncthreads();
    for (int off = 1; off < 256; off <<= 1) {
        int v = (t >= off) ? buf[t - off] : 0;
        __syncthreads();
        buf[t] += v;
        __syncthreads();
    }
    if (t < SCAN_NB) boff[t] = buf[t] - s;
    if (t == 0) row[NTOT_] = ETOT_;
}

// k3: block-level exclusive scan + global offset; writes row and cur
__global__ __launch_bounds__(256) void scan_write(const int* __restrict__ cnt, const int* __restrict__ boff,
                                                  int* __restrict__ row, int* __restrict__ cur) {
    __shared__ int buf[256];
    int t = threadIdx.x;
    int i0 = blockIdx.x * SCAN_ELEMS + t * 2;
    int vx = 0, vy = 0;
    if (i0 + 1 < NTOT_) { int2 v = *(const int2*)&cnt[i0]; vx = v.x; vy = v.y; }
    else if (i0 < NTOT_) vx = cnt[i0];
    int s = vx + vy;
    buf[t] = s;
    __syncthreads();
    for (int off = 1; off < 256; off <<= 1) {
        int v = (t >= off) ? buf[t - off] : 0;
        __syncthreads();
        buf[t] += v;
        __syncthreads();
    }
    int ex = buf[t] - s + boff[blockIdx.x];
    if (i0 + 1 < NTOT_) {
        *(int2*)&row[i0] = make_int2(ex, ex + vx);
        *(int2*)&cur[i0] = make_int2(ex, ex + vx);
    } else if (i0 < NTOT_) {
        row[i0] = ex;
        cur[i0] = ex;
    }
}

// scatter into global slot arrays (cs/cd sized ETOT_)
__global__ void scatter_all(const int* __restrict__ ei_rr, const int* __restrict__ ei_vr,
                            const int* __restrict__ ei_rv,
                            int* __restrict__ cur, int* __restrict__ cs, int* __restrict__ cd) {
    int j = blockIdx.x * blockDim.x + threadIdx.x;
    int s, d, nidx;
    if (j < ERR_)             { s = ei_rr[j]; d = ei_rr[ERR_ + j]; nidx = d; }
    else if (j < ERR_ + EVR_) { int jj = j - ERR_; s = ei_vr[jj]; d = ei_vr[EVR_ + jj]; nidx = NR_ + d; }
    else if (j < ETOT_)       { int jj = j - ERR_ - EVR_; s = ei_rv[jj]; d = ei_rv[ERV_ + jj]; nidx = 2 * NR_ + d; }
    else return;
    int p = atomicAdd(&cur[nidx], 1);
    cs[p] = s;
    cd[p] = d;
}

// ================= register-blocked GEMM: hs = x @ W  ([N,K] @ [K,128]) =================

template <int K>
__global__ __launch_bounds__(256) void gemm_kernel(const float* __restrict__ x,
                                                   const float* __restrict__ W,
                                                   float* __restrict__ hs, int N) {
    constexpr int KC = (K < 32) ? K : 32;
    __shared__ float xs[64][KC];
    __shared__ float ws[KC][128];
    int t = threadIdx.x;
    int cg4 = (t & 31) * 4;
    int rg8 = (t >> 5) * 8;
    int row0 = blockIdx.x * 64;
    float acc[8][4];
#pragma unroll
    for (int i = 0; i < 8; ++i)
#pragma unroll
        for (int j = 0; j < 4; ++j) acc[i][j] = 0.f;

    for (int k0 = 0; k0 < K; k0 += KC) {
        constexpr int XV = 64 * KC / 4;
        constexpr int KV = KC / 4;
        for (int v = t; v < XV; v += 256) {
            int r = v / KV, kk = (v % KV) * 4;
            int rr = row0 + r;
            float4 val = make_float4(0.f, 0.f, 0.f, 0.f);
            if (rr < N) val = *(const float4*)&x[(size_t)rr * K + k0 + kk];
            *(float4*)&xs[r][kk] = val;
        }
        constexpr int WV = KC * 128 / 4;
        const float4* Wv = (const float4*)&W[(size_t)k0 * 128];
        for (int v = t; v < WV; v += 256) ((float4*)&ws[0][0])[v] = Wv[v];
        __syncthreads();

#pragma unroll
        for (int k = 0; k < KC; k += 4) {
            float4 w0 = *(const float4*)&ws[k + 0][cg4];
            float4 w1 = *(const float4*)&ws[k + 1][cg4];
            float4 w2 = *(const float4*)&ws[k + 2][cg4];
            float4 w3 = *(const float4*)&ws[k + 3][cg4];
#pragma unroll
            for (int i = 0; i < 8; ++i) {
                float4 xv = *(const float4*)&xs[rg8 + i][k];
                acc[i][0] += xv.x * w0.x + xv.y * w1.x + xv.z * w2.x + xv.w * w3.x;
                acc[i][1] += xv.x * w0.y + xv.y * w1.y + xv.z * w2.y + xv.w * w3.y;
                acc[i][2] += xv.x * w0.z + xv.y * w1.z + xv.z * w2.z + xv.w * w3.z;
                acc[i][3] += xv.x * w0.w + xv.y * w1.w + xv.z * w2.w + xv.w * w3.w;
            }
        }
        __syncthreads();
    }
#pragma unroll
    for (int i = 0; i < 8; ++i) {
        int rr = row0 + rg8 + i;
        if (rr < N)
            *(float4*)&hs[(size_t)rr * 128 + cg4] =
                make_float4(acc[i][0], acc[i][1], acc[i][2], acc[i][3]);
    }
}

// ================= multi-score: sc[n][P] = x[n,:] @ fold[K][P] =================

template <int K, int P>
__global__ void scores_multi(const float* __restrict__ x, const float* __restrict__ fold,
                             float* __restrict__ sc, int N) {
    __shared__ float sf[K * P];
    for (int i = threadIdx.x; i < K * P; i += 256) sf[i] = fold[i];
    __syncthreads();
    int n = blockIdx.x * 256 + threadIdx.x;
    if (n >= N) return;
    float a[P];
#pragma unroll
    for (int p = 0; p < P; ++p) a[p] = 0.f;
    const float* xp = x + (size_t)n * K;
    for (int k = 0; k < K; k += 4) {
        float4 xv = *(const float4*)&xp[k];
#pragma unroll
        for (int p = 0; p < P; ++p)
            a[p] += xv.x * sf[k * P + p] + xv.y * sf[(k + 1) * P + p] +
                    xv.z * sf[(k + 2) * P + p] + xv.w * sf[(k + 3) * P + p];
    }
    float* o = sc + (size_t)n * P;
    *(float4*)o = make_float4(a[0], a[1], a[2], a[3]);
    if (P == 8) *(float4*)(o + 4) = make_float4(a[4], a[5], a[6], a[7]);
}

// ================= pass1 (all rels): ex[j] = exp(lrelu(es+ed)) in global slot order =================

__global__ void pass1_all(const int* __restrict__ cs, const int* __restrict__ cd,
                          const float* __restrict__ scR, const float* __restrict__ scV,
                          float* __restrict__ ex) {
    int j = blockIdx.x * blockDim.x + threadIdx.x;
    if (j >= ETOT_) return;
    int s = cs[j], d = cd[j];
    float e0, e1;
    if (j < ERR_) {
        e0 = scR[s * 8 + 0] + scR[d * 8 + 2];
        e1 = scR[s * 8 + 1] + scR[d * 8 + 3];
    } else if (j < ERR_ + EVR_) {
        e0 = scV[s * 4 + 0] + scR[d * 8 + 4];
        e1 = scV[s * 4 + 1] + scR[d * 8 + 5];
    } else {
        e0 = scR[s * 8 + 6] + scV[d * 4 + 2];
        e1 = scR[s * 8 + 7] + scV[d * 4 + 3];
    }
    e0 = (e0 >= 0.f) ? e0 : NEG_ * e0;
    e1 = (e1 >= 0.f) ? e1 : NEG_ * e1;
    ex[(size_t)j * 2 + 0] = __expf(e0);
    ex[(size_t)j * 2 + 1] = __expf(e1);
}

// ================= gather-aggregate: 1 wave per node, float2 per lane, unroll-4 =================

__device__ __forceinline__ void agg_rel_f2(int node, int lane,
                                           const int* __restrict__ row, const int* __restrict__ cs,
                                           const float* __restrict__ ex, const float* __restrict__ hs,
                                           float& ox, float& oy) {
    int r0 = row[node], r1 = row[node + 1];
    if (r1 <= r0) return;
    float ax = 0.f, ay = 0.f, den = 0.f;
    int j = r0;
    for (; j + 4 <= r1; j += 4) {
        int s0 = cs[j + 0], s1 = cs[j + 1], s2 = cs[j + 2], s3 = cs[j + 3];
        float2 e0 = *(const float2*)&ex[(size_t)(j + 0) * 2];
        float2 e1 = *(const float2*)&ex[(size_t)(j + 1) * 2];
        float2 e2 = *(const float2*)&ex[(size_t)(j + 2) * 2];
        float2 e3 = *(const float2*)&ex[(size_t)(j + 3) * 2];
        float2 v0 = *(const float2*)&hs[(size_t)s0 * 128 + lane * 2];
        float2 v1 = *(const float2*)&hs[(size_t)s1 * 128 + lane * 2];
        float2 v2 = *(const float2*)&hs[(size_t)s2 * 128 + lane * 2];
        float2 v3 = *(const float2*)&hs[(size_t)s3 * 128 + lane * 2];
        float w0 = (lane < 32) ? e0.x : e0.y;
        float w1 = (lane < 32) ? e1.x : e1.y;
        float w2 = (lane < 32) ? e2.x : e2.y;
        float w3 = (lane < 32) ? e3.x : e3.y;
        ax += v0.x * w0 + v1.x * w1 + v2.x * w2 + v3.x * w3;
        ay += v0.y * w0 + v1.y * w1 + v2.y * w2 + v3.y * w3;
        den += w0 + w1 + w2 + w3;
    }
    for (; j < r1; ++j) {
        int s = cs[j];
        float2 e = *(const float2*)&ex[(size_t)j * 2];
        float2 v = *(const float2*)&hs[(size_t)s * 128 + lane * 2];
        float w = (lane < 32) ? e.x : e.y;
        ax += v.x * w;
        ay += v.y * w;
        den += w;
    }
    float inv = 1.f / den;
    ox += ax * inv;
    oy += ay * inv;
}

__global__ __launch_bounds__(256) void agg_req(
        const int* __restrict__ row, const int* __restrict__ cs, const float* __restrict__ ex,
        const float* __restrict__ hs_rr, const float* __restrict__ hs_vr,
        float* __restrict__ o, int N) {
    int node = blockIdx.x * 4 + (threadIdx.x >> 6);
    if (node >= N) return;
    int lane = threadIdx.x & 63;
    float ox = 0.f, oy = 0.f;
    agg_rel_f2(node, lane, row, cs, ex, hs_rr, ox, oy);          // rr region
    agg_rel_f2(node, lane, row + NR_, cs, ex, hs_vr, ox, oy);    // vr region
    *(float2*)&o[(size_t)node * 128 + lane * 2] = make_float2(ox * 0.5f, oy * 0.5f);
}

__global__ __launch_bounds__(256) void agg_veh(
        const int* __restrict__ row, const int* __restrict__ cs, const float* __restrict__ ex,
        const float* __restrict__ hs, float* __restrict__ o, int N) {
    int node = blockIdx.x * 4 + (threadIdx.x >> 6);
    if (node >= N) return;
    int lane = threadIdx.x & 63;
    float ox = 0.f, oy = 0.f;
    agg_rel_f2(node, lane, row + 2 * NR_, cs, ex, hs, ox, oy);   // rv region
    *(float2*)&o[(size_t)node * 128 + lane * 2] = make_float2(ox, oy);
}

// ================= BatchNorm (training stats) + leaky-relu, both node types =================
// s4 layout: [0..127] sum_req, [128..255] sum_veh, [256..383] sumsq_req, [384..511] sumsq_veh

__global__ void bn_stats_all(const float* __restrict__ o_r, const float* __restrict__ o_v,
                             float* __restrict__ s4) {
    int b = blockIdx.x;
    int c = threadIdx.x;  // 128
    const float* o; int N; int r0; int soff;
    if (b < 157) { o = o_r; N = NR_; r0 = b * 256; soff = 0; }
    else         { o = o_v; N = NV_; r0 = (b - 157) * 256; soff = 128; }
    int rend = r0 + 256; if (rend > N) rend = N;
    float s = 0.f, s2 = 0.f;
    for (int r = r0; r < rend; ++r) {
        float v = o[(size_t)r * 128 + c];
        s += v; s2 += v * v;
    }
    atomicAdd(&s4[soff + c], s);
    atomicAdd(&s4[256 + soff + c], s2);
}

__global__ void bn_norm_all(const float* __restrict__ o_r, const float* __restrict__ o_v,
                            const float* __restrict__ s4,
                            const float* __restrict__ gammaL, const float* __restrict__ betaL,
                            float* __restrict__ xr, float* __restrict__ xv) {
    size_t idx = blockIdx.x * (size_t)256 + threadIdx.x;
    const size_t nr = (size_t)NR_ * 128;
    const float* o; float* x; int soff; float invN; size_t i;
    if (idx < nr) { o = o_r; x = xr; soff = 0;   invN = 1.f / NR_; i = idx; }
    else          { o = o_v; x = xv; soff = 128; invN = 1.f / NV_; i = idx - nr; }
    int c = (int)(i & 127);
    float mu = s4[soff + c] * invN;
    float var = s4[256 + soff + c] * invN - mu * mu;
    float v = (o[i] - mu) * rsqrtf(var + EPS_) * gammaL[soff + c] + betaL[soff + c];
    x[i] = (v >= 0.f) ? v : NEG_ * v;
}

// ================= final head =================

__global__ void final_edge_all(const int* __restrict__ ei_rr, const int* __restrict__ ei_vr,
                               const int* __restrict__ ei_rv,
                               const float* __restrict__ ea_rr, const float* __restrict__ ea_vr,
                               const float* __restrict__ ea_rv,
                               const float* __restrict__ ssR, const float* __restrict__ ssV,
                               const float* __restrict__ wp2, const float* __restrict__ cterm,
                               float* __restrict__ out) {
    int j = blockIdx.x * blockDim.x + threadIdx.x;
    if (j >= ETOT_) return;
    int rel, jj;
    const int* src; const int* dst; const float* ea; const float* ss; const float* sd; float* o;
    if (j < ERR_) {
        rel = 0; jj = j; src = ei_rr; dst = ei_rr + ERR_; ea = ea_rr; ss = ssR; sd = ssR; o = out;
    } else if (j < ERR_ + EVR_) {
        rel = 1; jj = j - ERR_; src = ei_vr; dst = ei_vr + EVR_; ea = ea_vr; ss = ssV; sd = ssR;
        o = out + (size_t)ERR_ * 2;
    } else {
        rel = 2; jj = j - ERR_ - EVR_; src = ei_rv; dst = ei_rv + ERV_; ea = ea_rv; ss = ssR; sd = ssV;
        o = out + (size_t)(ERR_ + EVR_) * 2;
    }
    int s = src[jj], d = dst[jj];
    float l0 = ss[s * 4 + 0] + sd[d * 4 + 2] + cterm[rel * 2 + 0];
    float l1 = ss[s * 4 + 1] + sd[d * 4 + 3] + cterm[rel * 2 + 1];
    const float* w = wp2 + rel * 16;
#pragma unroll
    for (int k = 0; k < 8; ++k) {
        float v = ea[(size_t)jj * 8 + k];
        l0 += v * w[k * 2 + 0];
        l1 += v * w[k * 2 + 1];
    }
    float m = fmaxf(l0, l1);
    float p0 = __expf(l0 - m), p1 = __expf(l1 - m);
    float inv = 1.f / (p0 + p1);
    o[(size_t)jj * 2 + 0] = p0 * inv;
    o[(size_t)jj * 2 + 1] = p1 * inv;
}

// ================= host orchestration =================

extern "C" void kernel_launch(void* const* d_in, const int* in_sizes, int n_in,
                              void* d_out, int out_size, void* d_ws, size_t ws_size,
                              hipStream_t stream) {
    const float* x_req = (const float*)d_in[0];
    const float* x_veh = (const float*)d_in[1];
    const int* ei_rr = (const int*)d_in[2];
    const int* ei_vr = (const int*)d_in[3];
    const int* ei_rv = (const int*)d_in[4];
    const float* ea_rr = (const float*)d_in[5];
    const float* ea_vr = (const float*)d_in[6];
    const float* ea_rv = (const float*)d_in[7];
    const float* Wsrc1 = (const float*)d_in[8];
    const float* Wdst1 = (const float*)d_in[9];
    const float* asrc1 = (const float*)d_in[10];
    const float* adst1 = (const float*)d_in[11];
    const float* Wsrc2 = (const float*)d_in[13];
    const float* Wdst2 = (const float*)d_in[14];
    const float* asrc2 = (const float*)d_in[15];
    const float* adst2 = (const float*)d_in[16];
    const float* bn_gamma = (const float*)d_in[18];   // [2][2][128]
    const float* bn_beta  = (const float*)d_in[19];
    const float* Wp   = (const float*)d_in[20];
    const float* bp   = (const float*)d_in[21];
    const float* Wlin = (const float*)d_in[22];
    const float* blin = (const float*)d_in[23];
    float* out = (float*)d_out;

    // ---- workspace ----
    float* w = (float*)d_ws;
    size_t off = 0;
    float* xr    = w + off; off += (size_t)NR_ * 128;
    float* xv    = w + off; off += (size_t)NV_ * 128;
    float* hs_a  = w + off; off += (size_t)NR_ * 128;
    float* hs_b  = w + off; off += (size_t)NV_ * 128;
    float* o_r   = w + off; off += (size_t)NR_ * 128;
    float* o_v   = w + off; off += (size_t)NV_ * 128;
    float* scR   = w + off; off += (size_t)NR_ * 8;
    float* scV   = w + off; off += (size_t)NV_ * 4;
    float* ex    = w + off; off += (size_t)ETOT_ * 2;
    float* s4    = w + off; off += 512;
    float* foldR = w + off; off += 2 * 128 * 8;
    float* foldV = w + off; off += 2 * 128 * 4;
    float* wp2   = w + off; off += 48;
    float* cterm = w + off; off += 8;
    float* fw    = w + off; off += 512;
    float* ssR   = w + off; off += (size_t)NR_ * 4;
    float* ssV   = w + off; off += (size_t)NV_ * 4;
    int* iw = (int*)(w + off);
    size_t ioff = 0;
    int* row  = iw + ioff; ioff += NTOT_ + 1;
    int* cur  = iw + ioff; ioff += NTOT_;       // doubles as cnt (hist target)
    int* bsum = iw + ioff; ioff += SCAN_NB;
    int* boff = iw + ioff; ioff += SCAN_NB;
    int* cs   = iw + ioff; ioff += ETOT_;
    int* cd   = iw + ioff; ioff += ETOT_;

    // ---- precompute folds ----
    precompute_kernel<<<14, 128, 0, stream>>>(Wsrc1, Wdst1, asrc1, adst1, Wsrc2, Wdst2, asrc2, adst2,
                                              Wp, bp, Wlin, blin, foldR, foldV, wp2, cterm, fw);

    // ---- CSR build (concatenated slot space) ----
    hipMemsetAsync(cur, 0, NTOT_ * sizeof(int), stream);   // cur used as cnt first
    hist_all<<<(ETOT_ + 255) / 256, 256, 0, stream>>>(ei_rr, ei_vr, ei_rv, cur);
    scan_reduce<<<SCAN_NB, 256, 0, stream>>>(cur, bsum);
    scan_bsums<<<1, 256, 0, stream>>>(bsum, boff, row);
    scan_write<<<SCAN_NB, 256, 0, stream>>>(cur, boff, row, cur);   // reads cnt, overwrites as cursor
    scatter_all<<<(ETOT_ + 255) / 256, 256, 0, stream>>>(ei_rr, ei_vr, ei_rv, cur, cs, cd);

    for (int l = 0; l < 2; ++l) {
        const float* xri = (l == 0) ? x_req : xr;
        const float* xvi = (l == 0) ? x_veh : xv;
        const float* Ws = (l == 0) ? Wsrc1 : Wsrc2;
        const int KW = (l == 0) ? 16 : 128;
        const float* fR = foldR + (size_t)l * 128 * 8;
        const float* fV = foldV + (size_t)l * 128 * 4;

        if (l == 0) {
            gemm_kernel<16><<<(NR_ + 63) / 64, 256, 0, stream>>>(xri, Ws + 0 * KW * 128, hs_a, NR_);
            gemm_kernel<16><<<(NV_ + 63) / 64, 256, 0, stream>>>(xvi, Ws + 1 * KW * 128, hs_b, NV_);
            scores_multi<16, 8><<<(NR_ + 255) / 256, 256, 0, stream>>>(xri, fR, scR, NR_);
            scores_multi<16, 4><<<(NV_ + 255) / 256, 256, 0, stream>>>(xvi, fV, scV, NV_);
        } else {
            gemm_kernel<128><<<(NR_ + 63) / 64, 256, 0, stream>>>(xri, Ws + 0 * KW * 128, hs_a, NR_);
            gemm_kernel<128><<<(NV_ + 63) / 64, 256, 0, stream>>>(xvi, Ws + 1 * KW * 128, hs_b, NV_);
            scores_multi<128, 8><<<(NR_ + 255) / 256, 256, 0, stream>>>(xri, fR, scR, NR_);
            scores_multi<128, 4><<<(NV_ + 255) / 256, 256, 0, stream>>>(xvi, fV, scV, NV_);
        }
        pass1_all<<<(ETOT_ + 255) / 256, 256, 0, stream>>>(cs, cd, scR, scV, ex);
        agg_req<<<(NR_ + 3) / 4, 256, 0, stream>>>(row, cs, ex, hs_a, hs_b, o_r, NR_);
        if (l == 0)
            gemm_kernel<16><<<(NR_ + 63) / 64, 256, 0, stream>>>(xri, Ws + 2 * KW * 128, hs_a, NR_);
        else
            gemm_kernel<128><<<(NR_ + 63) / 64, 256, 0, stream>>>(xri, Ws + 2 * KW * 128, hs_a, NR_);
        agg_veh<<<(NV_ + 3) / 4, 256, 0, stream>>>(row, cs, ex, hs_a, o_v, NV_);

        hipMemsetAsync(s4, 0, 512 * sizeof(float), stream);
        bn_stats_all<<<157 + 16, 128, 0, stream>>>(o_r, o_v, s4);
        bn_norm_all<<<(int)(((size_t)(NR_ + NV_) * 128 + 255) / 256), 256, 0, stream>>>(
            o_r, o_v, s4, bn_gamma + l * 256, bn_beta + l * 256, xr, xv);
    }

    // ---- final head ----
    scores_multi<128, 4><<<(NR_ + 255) / 256, 256, 0, stream>>>(xr, fw, ssR, NR_);
    scores_multi<128, 4><<<(NV_ + 255) / 256, 256, 0, stream>>>(xv, fw, ssV, NV_);
    final_edge_all<<<(ETOT_ + 255) / 256, 256, 0, stream>>>(ei_rr, ei_vr, ei_rv, ea_rr, ea_vr, ea_rv,
                                                            ssR, ssV, wp2, cterm, out);
}

// Round 6
// 570.141 us; speedup vs baseline: 3.2172x; 1.1898x over previous
//
#include <hip/hip_runtime.h>
#include <hip/hip_bf16.h>

#define NR_ 40000
#define NV_ 4000
#define ERR_ 400000
#define EVR_ 150000
#define ERV_ 150000
#define ETOT_ (ERR_ + EVR_ + ERV_)
#define NTOT_ (NR_ + NR_ + NV_)          // concatenated node-slot space: rr | vr | rv
#define SCAN_ELEMS 512
#define SCAN_NB ((NTOT_ + SCAN_ELEMS - 1) / SCAN_ELEMS)   // 165
#define BN_BLKS_R ((NR_ + 63) / 64)      // 625
#define BN_BLKS_V ((NV_ + 63) / 64)      // 63
#define NEG_ 0.2f
#define EPS_ 1e-5f

// ================= precompute: attention folds, edge-proj fold, final fold =================
// foldR[l][k][8] cols: es_rr(0,1) ed_rr(2,3) ed_vr(4,5) es_rv(6,7)
// foldV[l][k][4] cols: es_vr(0,1) ed_rv(2,3)
// fw[k][4]: Wlin cols for src half (0,1) and dst half (2,3)
__global__ void precompute_kernel(const float* __restrict__ Wsrc1, const float* __restrict__ Wdst1,
                                  const float* __restrict__ asrc1, const float* __restrict__ adst1,
                                  const float* __restrict__ Wsrc2, const float* __restrict__ Wdst2,
                                  const float* __restrict__ asrc2, const float* __restrict__ adst2,
                                  const float* __restrict__ Wp, const float* __restrict__ bp,
                                  const float* __restrict__ Wlin, const float* __restrict__ blin,
                                  float* __restrict__ foldR, float* __restrict__ foldV,
                                  float* __restrict__ wp2, float* __restrict__ cterm,
                                  float* __restrict__ fw) {
    int b = blockIdx.x;
    int t = threadIdx.x;  // 128
    if (b < 12) {
        int layer = b / 6, rel = (b % 6) / 2, side = b & 1;
        int K = (layer == 0) ? 16 : 128;
        const float* W = (layer == 0) ? (side ? Wdst1 : Wsrc1) : (side ? Wdst2 : Wsrc2);
        const float* a = (layer == 0) ? (side ? adst1 : asrc1) : (side ? adst2 : asrc2);
        W += (size_t)rel * K * 128;
        a += rel * 128;
        float* dst; int P; int colbase;
        if (rel == 0 && side == 0)      { dst = foldR; P = 8; colbase = 0; }
        else if (rel == 0)              { dst = foldR; P = 8; colbase = 2; }
        else if (rel == 1 && side == 0) { dst = foldV; P = 4; colbase = 0; }
        else if (rel == 1)              { dst = foldR; P = 8; colbase = 4; }
        else if (side == 0)             { dst = foldR; P = 8; colbase = 6; }
        else                            { dst = foldV; P = 4; colbase = 2; }
        dst += (size_t)layer * 128 * P;
        if (t < K) {
            for (int h = 0; h < 2; ++h) {
                float s = 0.f;
                for (int c = 0; c < 64; ++c) s += W[t * 128 + h * 64 + c] * a[h * 64 + c];
                dst[t * P + colbase + h] = s;
            }
        }
    } else if (b == 12) {
        if (t < 48) {
            int i = t / 16, k = (t / 2) % 8, o = t & 1;
            float s = 0.f;
            for (int c = 0; c < 64; ++c) s += Wp[(i * 8 + k) * 64 + c] * Wlin[(128 + c) * 2 + o];
            wp2[t] = s;
        } else if (t < 54) {
            int i = (t - 48) / 2, o = (t - 48) & 1;
            float s = blin[o];
            for (int c = 0; c < 64; ++c) s += bp[i * 64 + c] * Wlin[(128 + c) * 2 + o];
            cterm[i * 2 + o] = s;
        }
    } else {
        for (int idx = t; idx < 512; idx += 128) {
            int k = idx >> 2, c = idx & 3;
            fw[idx] = Wlin[(k + ((c >= 2) ? 192 : 0)) * 2 + (c & 1)];
        }
    }
}

// ================= CSR build (concatenated slot space) =================

__global__ void hist_all(const int* __restrict__ ei_rr, const int* __restrict__ ei_vr,
                         const int* __restrict__ ei_rv, int* __restrict__ cnt) {
    int j = blockIdx.x * blockDim.x + threadIdx.x;
    if (j < ERR_) atomicAdd(&cnt[ei_rr[ERR_ + j]], 1);
    else if (j < ERR_ + EVR_) atomicAdd(&cnt[NR_ + ei_vr[EVR_ + (j - ERR_)]], 1);
    else if (j < ETOT_) atomicAdd(&cnt[2 * NR_ + ei_rv[ERV_ + (j - ERR_ - EVR_)]], 1);
}

__global__ __launch_bounds__(256) void scan_reduce(const int* __restrict__ cnt, int* __restrict__ bsum) {
    __shared__ int buf[256];
    int t = threadIdx.x;
    int i0 = blockIdx.x * SCAN_ELEMS + t * 2;
    int s = 0;
    if (i0 + 1 < NTOT_) { int2 v = *(const int2*)&cnt[i0]; s = v.x + v.y; }
    else if (i0 < NTOT_) s = cnt[i0];
    buf[t] = s;
    __syncthreads();
    for (int off = 128; off; off >>= 1) {
        if (t < off) buf[t] += buf[t + off];
        __syncthreads();
    }
    if (t == 0) bsum[blockIdx.x] = buf[0];
}

__global__ __launch_bounds__(256) void scan_bsums(const int* __restrict__ bsum, int* __restrict__ boff,
                                                  int* __restrict__ row) {
    __shared__ int buf[256];
    int t = threadIdx.x;
    int s = (t < SCAN_NB) ? bsum[t] : 0;
    buf[t] = s;
    __syncthreads();
    for (int off = 1; off < 256; off <<= 1) {
        int v = (t >= off) ? buf[t - off] : 0;
        __syncthreads();
        buf[t] += v;
        __syncthreads();
    }
    if (t < SCAN_NB) boff[t] = buf[t] - s;
    if (t == 0) row[NTOT_] = ETOT_;
}

__global__ __launch_bounds__(256) void scan_write(const int* __restrict__ cnt, const int* __restrict__ boff,
                                                  int* __restrict__ row, int* __restrict__ cur) {
    __shared__ int buf[256];
    int t = threadIdx.x;
    int i0 = blockIdx.x * SCAN_ELEMS + t * 2;
    int vx = 0, vy = 0;
    if (i0 + 1 < NTOT_) { int2 v = *(const int2*)&cnt[i0]; vx = v.x; vy = v.y; }
    else if (i0 < NTOT_) vx = cnt[i0];
    int s = vx + vy;
    buf[t] = s;
    __syncthreads();
    for (int off = 1; off < 256; off <<= 1) {
        int v = (t >= off) ? buf[t - off] : 0;
        __syncthreads();
        buf[t] += v;
        __syncthreads();
    }
    int ex = buf[t] - s + boff[blockIdx.x];
    if (i0 + 1 < NTOT_) {
        *(int2*)&row[i0] = make_int2(ex, ex + vx);
        *(int2*)&cur[i0] = make_int2(ex, ex + vx);
    } else if (i0 < NTOT_) {
        row[i0] = ex;
        cur[i0] = ex;
    }
}

// scatter into global slot array (cs only; dst is implied by CSR region)
__global__ void scatter_all(const int* __restrict__ ei_rr, const int* __restrict__ ei_vr,
                            const int* __restrict__ ei_rv,
                            int* __restrict__ cur, int* __restrict__ cs) {
    int j = blockIdx.x * blockDim.x + threadIdx.x;
    int s, nidx;
    if (j < ERR_)             { s = ei_rr[j]; nidx = ei_rr[ERR_ + j]; }
    else if (j < ERR_ + EVR_) { int jj = j - ERR_; s = ei_vr[jj]; nidx = NR_ + ei_vr[EVR_ + jj]; }
    else if (j < ETOT_)       { int jj = j - ERR_ - EVR_; s = ei_rv[jj]; nidx = 2 * NR_ + ei_rv[ERV_ + jj]; }
    else return;
    int p = atomicAdd(&cur[nidx], 1);
    cs[p] = s;
}

// ================= register-blocked GEMM: hs = x @ W  ([N,K] @ [K,128]) =================

template <int K>
__global__ __launch_bounds__(256) void gemm_kernel(const float* __restrict__ x,
                                                   const float* __restrict__ W,
                                                   float* __restrict__ hs, int N) {
    constexpr int KC = (K < 32) ? K : 32;
    __shared__ float xs[64][KC];
    __shared__ float ws[KC][128];
    int t = threadIdx.x;
    int cg4 = (t & 31) * 4;
    int rg8 = (t >> 5) * 8;
    int row0 = blockIdx.x * 64;
    float acc[8][4];
#pragma unroll
    for (int i = 0; i < 8; ++i)
#pragma unroll
        for (int j = 0; j < 4; ++j) acc[i][j] = 0.f;

    for (int k0 = 0; k0 < K; k0 += KC) {
        constexpr int XV = 64 * KC / 4;
        constexpr int KV = KC / 4;
        for (int v = t; v < XV; v += 256) {
            int r = v / KV, kk = (v % KV) * 4;
            int rr = row0 + r;
            float4 val = make_float4(0.f, 0.f, 0.f, 0.f);
            if (rr < N) val = *(const float4*)&x[(size_t)rr * K + k0 + kk];
            *(float4*)&xs[r][kk] = val;
        }
        constexpr int WV = KC * 128 / 4;
        const float4* Wv = (const float4*)&W[(size_t)k0 * 128];
        for (int v = t; v < WV; v += 256) ((float4*)&ws[0][0])[v] = Wv[v];
        __syncthreads();

#pragma unroll
        for (int k = 0; k < KC; k += 4) {
            float4 w0 = *(const float4*)&ws[k + 0][cg4];
            float4 w1 = *(const float4*)&ws[k + 1][cg4];
            float4 w2 = *(const float4*)&ws[k + 2][cg4];
            float4 w3 = *(const float4*)&ws[k + 3][cg4];
#pragma unroll
            for (int i = 0; i < 8; ++i) {
                float4 xv = *(const float4*)&xs[rg8 + i][k];
                acc[i][0] += xv.x * w0.x + xv.y * w1.x + xv.z * w2.x + xv.w * w3.x;
                acc[i][1] += xv.x * w0.y + xv.y * w1.y + xv.z * w2.y + xv.w * w3.y;
                acc[i][2] += xv.x * w0.z + xv.y * w1.z + xv.z * w2.z + xv.w * w3.z;
                acc[i][3] += xv.x * w0.w + xv.y * w1.w + xv.z * w2.w + xv.w * w3.w;
            }
        }
        __syncthreads();
    }
#pragma unroll
    for (int i = 0; i < 8; ++i) {
        int rr = row0 + rg8 + i;
        if (rr < N)
            *(float4*)&hs[(size_t)rr * 128 + cg4] =
                make_float4(acc[i][0], acc[i][1], acc[i][2], acc[i][3]);
    }
}

// ================= multi-score: sc[n][P] = x[n,:] @ fold[K][P] =================

template <int K, int P>
__global__ void scores_multi(const float* __restrict__ x, const float* __restrict__ fold,
                             float* __restrict__ sc, int N) {
    __shared__ float sf[K * P];
    for (int i = threadIdx.x; i < K * P; i += 256) sf[i] = fold[i];
    __syncthreads();
    int n = blockIdx.x * 256 + threadIdx.x;
    if (n >= N) return;
    float a[P];
#pragma unroll
    for (int p = 0; p < P; ++p) a[p] = 0.f;
    const float* xp = x + (size_t)n * K;
    for (int k = 0; k < K; k += 4) {
        float4 xv = *(const float4*)&xp[k];
#pragma unroll
        for (int p = 0; p < P; ++p)
            a[p] += xv.x * sf[k * P + p] + xv.y * sf[(k + 1) * P + p] +
                    xv.z * sf[(k + 2) * P + p] + xv.w * sf[(k + 3) * P + p];
    }
    float* o = sc + (size_t)n * P;
    *(float4*)o = make_float4(a[0], a[1], a[2], a[3]);
    if (P == 8) *(float4*)(o + 4) = make_float4(a[4], a[5], a[6], a[7]);
}

// ================= gather-aggregate with fused edge softmax =================
// 1 wave per node, float2 per lane (features 2*lane, 2*lane+1), head = lane>>5.
// Per edge: e = lrelu(es[src] + ed[node]); w = exp(e); acc += hs[src]*w; den += w.
// sc includes the lane-half column offset; edv is the dst-score for this lane's head.

__device__ __forceinline__ void agg_rel_f2(int node, int lane,
                                           const int* __restrict__ row, const int* __restrict__ cs,
                                           const float* __restrict__ hs,
                                           const float* __restrict__ Ss, int sst, int sc, float edv,
                                           float& ox, float& oy) {
    int r0 = row[node], r1 = row[node + 1];
    if (r1 <= r0) return;
    float ax = 0.f, ay = 0.f, den = 0.f;
    int j = r0;
    for (; j + 4 <= r1; j += 4) {
        int s0 = cs[j + 0], s1 = cs[j + 1], s2 = cs[j + 2], s3 = cs[j + 3];
        float p0 = Ss[s0 * sst + sc];
        float p1 = Ss[s1 * sst + sc];
        float p2 = Ss[s2 * sst + sc];
        float p3 = Ss[s3 * sst + sc];
        float2 v0 = *(const float2*)&hs[(size_t)s0 * 128 + lane * 2];
        float2 v1 = *(const float2*)&hs[(size_t)s1 * 128 + lane * 2];
        float2 v2 = *(const float2*)&hs[(size_t)s2 * 128 + lane * 2];
        float2 v3 = *(const float2*)&hs[(size_t)s3 * 128 + lane * 2];
        float e0 = p0 + edv; e0 = (e0 >= 0.f) ? e0 : NEG_ * e0;
        float e1 = p1 + edv; e1 = (e1 >= 0.f) ? e1 : NEG_ * e1;
        float e2 = p2 + edv; e2 = (e2 >= 0.f) ? e2 : NEG_ * e2;
        float e3 = p3 + edv; e3 = (e3 >= 0.f) ? e3 : NEG_ * e3;
        float w0 = __expf(e0), w1 = __expf(e1), w2 = __expf(e2), w3 = __expf(e3);
        ax += v0.x * w0 + v1.x * w1 + v2.x * w2 + v3.x * w3;
        ay += v0.y * w0 + v1.y * w1 + v2.y * w2 + v3.y * w3;
        den += w0 + w1 + w2 + w3;
    }
    for (; j < r1; ++j) {
        int s = cs[j];
        float p = Ss[s * sst + sc];
        float2 v = *(const float2*)&hs[(size_t)s * 128 + lane * 2];
        float e = p + edv; e = (e >= 0.f) ? e : NEG_ * e;
        float w = __expf(e);
        ax += v.x * w;
        ay += v.y * w;
        den += w;
    }
    float inv = 1.f / den;
    ox += ax * inv;
    oy += ay * inv;
}

__global__ __launch_bounds__(256) void agg_req(
        const int* __restrict__ row, const int* __restrict__ cs,
        const float* __restrict__ hs_rr, const float* __restrict__ hs_vr,
        const float* __restrict__ scR, const float* __restrict__ scV,
        float* __restrict__ o, int N) {
    int node = blockIdx.x * 4 + (threadIdx.x >> 6);
    if (node >= N) return;
    int lane = threadIdx.x & 63;
    int hoff = lane >> 5;              // 0 for head0 lanes, 1 for head1 lanes
    float ed_rr = scR[node * 8 + 2 + hoff];
    float ed_vr = scR[node * 8 + 4 + hoff];
    float ox = 0.f, oy = 0.f;
    agg_rel_f2(node, lane, row, cs, hs_rr, scR, 8, 0 + hoff, ed_rr, ox, oy);        // rr region
    agg_rel_f2(node, lane, row + NR_, cs, hs_vr, scV, 4, 0 + hoff, ed_vr, ox, oy);  // vr region
    *(float2*)&o[(size_t)node * 128 + lane * 2] = make_float2(ox * 0.5f, oy * 0.5f);
}

__global__ __launch_bounds__(256) void agg_veh(
        const int* __restrict__ row, const int* __restrict__ cs,
        const float* __restrict__ hs,
        const float* __restrict__ scR, const float* __restrict__ scV,
        float* __restrict__ o, int N) {
    int node = blockIdx.x * 4 + (threadIdx.x >> 6);
    if (node >= N) return;
    int lane = threadIdx.x & 63;
    int hoff = lane >> 5;
    float ed_rv = scV[node * 4 + 2 + hoff];
    float ox = 0.f, oy = 0.f;
    agg_rel_f2(node, lane, row + 2 * NR_, cs, hs, scR, 8, 6 + hoff, ed_rv, ox, oy); // rv region
    *(float2*)&o[(size_t)node * 128 + lane * 2] = make_float2(ox, oy);
}

// ================= BatchNorm (training stats) + leaky-relu, both node types =================
// s4 layout: [0..127] sum_req, [128..255] sum_veh, [256..383] sumsq_req, [384..511] sumsq_veh

__global__ __launch_bounds__(256) void bn_stats_all(const float* __restrict__ o_r,
                                                    const float* __restrict__ o_v,
                                                    float* __restrict__ s4) {
    int b = blockIdx.x;
    const float* o; int N; int r0; int soff;
    if (b < BN_BLKS_R) { o = o_r; N = NR_; r0 = b * 64; soff = 0; }
    else               { o = o_v; N = NV_; r0 = (b - BN_BLKS_R) * 64; soff = 128; }
    int wave = threadIdx.x >> 6, lane = threadIdx.x & 63;
    int rend = r0 + 64; if (rend > N) rend = N;
    float sx = 0.f, sy = 0.f, qx = 0.f, qy = 0.f;
    for (int r = r0 + wave; r < rend; r += 4) {
        float2 v = *(const float2*)&o[(size_t)r * 128 + lane * 2];
        sx += v.x; sy += v.y;
        qx += v.x * v.x; qy += v.y * v.y;
    }
    __shared__ float bs[4][128];
    __shared__ float bq[4][128];
    bs[wave][lane * 2] = sx;  bs[wave][lane * 2 + 1] = sy;
    bq[wave][lane * 2] = qx;  bq[wave][lane * 2 + 1] = qy;
    __syncthreads();
    if (threadIdx.x < 128) {
        int c = threadIdx.x;
        float s = bs[0][c] + bs[1][c] + bs[2][c] + bs[3][c];
        float q = bq[0][c] + bq[1][c] + bq[2][c] + bq[3][c];
        atomicAdd(&s4[soff + c], s);
        atomicAdd(&s4[256 + soff + c], q);
    }
}

__global__ void bn_norm_all(const float* __restrict__ o_r, const float* __restrict__ o_v,
                            const float* __restrict__ s4,
                            const float* __restrict__ gammaL, const float* __restrict__ betaL,
                            float* __restrict__ xr, float* __restrict__ xv) {
    size_t idx = blockIdx.x * (size_t)256 + threadIdx.x;
    const size_t nr = (size_t)NR_ * 128;
    const float* o; float* x; int soff; float invN; size_t i;
    if (idx < nr) { o = o_r; x = xr; soff = 0;   invN = 1.f / NR_; i = idx; }
    else          { o = o_v; x = xv; soff = 128; invN = 1.f / NV_; i = idx - nr; }
    int c = (int)(i & 127);
    float mu = s4[soff + c] * invN;
    float var = s4[256 + soff + c] * invN - mu * mu;
    float v = (o[i] - mu) * rsqrtf(var + EPS_) * gammaL[soff + c] + betaL[soff + c];
    x[i] = (v >= 0.f) ? v : NEG_ * v;
}

// ================= final head =================

__global__ void final_edge_all(const int* __restrict__ ei_rr, const int* __restrict__ ei_vr,
                               const int* __restrict__ ei_rv,
                               const float* __restrict__ ea_rr, const float* __restrict__ ea_vr,
                               const float* __restrict__ ea_rv,
                               const float* __restrict__ ssR, const float* __restrict__ ssV,
                               const float* __restrict__ wp2, const float* __restrict__ cterm,
                               float* __restrict__ out) {
    int j = blockIdx.x * blockDim.x + threadIdx.x;
    if (j >= ETOT_) return;
    int rel, jj;
    const int* src; const int* dst; const float* ea; const float* ss; const float* sd; float* o;
    if (j < ERR_) {
        rel = 0; jj = j; src = ei_rr; dst = ei_rr + ERR_; ea = ea_rr; ss = ssR; sd = ssR; o = out;
    } else if (j < ERR_ + EVR_) {
        rel = 1; jj = j - ERR_; src = ei_vr; dst = ei_vr + EVR_; ea = ea_vr; ss = ssV; sd = ssR;
        o = out + (size_t)ERR_ * 2;
    } else {
        rel = 2; jj = j - ERR_ - EVR_; src = ei_rv; dst = ei_rv + ERV_; ea = ea_rv; ss = ssR; sd = ssV;
        o = out + (size_t)(ERR_ + EVR_) * 2;
    }
    int s = src[jj], d = dst[jj];
    float l0 = ss[s * 4 + 0] + sd[d * 4 + 2] + cterm[rel * 2 + 0];
    float l1 = ss[s * 4 + 1] + sd[d * 4 + 3] + cterm[rel * 2 + 1];
    const float* w = wp2 + rel * 16;
#pragma unroll
    for (int k = 0; k < 8; ++k) {
        float v = ea[(size_t)jj * 8 + k];
        l0 += v * w[k * 2 + 0];
        l1 += v * w[k * 2 + 1];
    }
    float m = fmaxf(l0, l1);
    float p0 = __expf(l0 - m), p1 = __expf(l1 - m);
    float inv = 1.f / (p0 + p1);
    o[(size_t)jj * 2 + 0] = p0 * inv;
    o[(size_t)jj * 2 + 1] = p1 * inv;
}

// ================= host orchestration =================

extern "C" void kernel_launch(void* const* d_in, const int* in_sizes, int n_in,
                              void* d_out, int out_size, void* d_ws, size_t ws_size,
                              hipStream_t stream) {
    const float* x_req = (const float*)d_in[0];
    const float* x_veh = (const float*)d_in[1];
    const int* ei_rr = (const int*)d_in[2];
    const int* ei_vr = (const int*)d_in[3];
    const int* ei_rv = (const int*)d_in[4];
    const float* ea_rr = (const float*)d_in[5];
    const float* ea_vr = (const float*)d_in[6];
    const float* ea_rv = (const float*)d_in[7];
    const float* Wsrc1 = (const float*)d_in[8];
    const float* Wdst1 = (const float*)d_in[9];
    const float* asrc1 = (const float*)d_in[10];
    const float* adst1 = (const float*)d_in[11];
    const float* Wsrc2 = (const float*)d_in[13];
    const float* Wdst2 = (const float*)d_in[14];
    const float* asrc2 = (const float*)d_in[15];
    const float* adst2 = (const float*)d_in[16];
    const float* bn_gamma = (const float*)d_in[18];   // [2][2][128]
    const float* bn_beta  = (const float*)d_in[19];
    const float* Wp   = (const float*)d_in[20];
    const float* bp   = (const float*)d_in[21];
    const float* Wlin = (const float*)d_in[22];
    const float* blin = (const float*)d_in[23];
    float* out = (float*)d_out;

    // ---- workspace ----
    float* w = (float*)d_ws;
    size_t off = 0;
    float* xr    = w + off; off += (size_t)NR_ * 128;
    float* xv    = w + off; off += (size_t)NV_ * 128;
    float* hs_a  = w + off; off += (size_t)NR_ * 128;
    float* hs_b  = w + off; off += (size_t)NV_ * 128;
    float* o_r   = w + off; off += (size_t)NR_ * 128;
    float* o_v   = w + off; off += (size_t)NV_ * 128;
    float* scR   = w + off; off += (size_t)NR_ * 8;
    float* scV   = w + off; off += (size_t)NV_ * 4;
    float* s4    = w + off; off += 512;
    float* foldR = w + off; off += 2 * 128 * 8;
    float* foldV = w + off; off += 2 * 128 * 4;
    float* wp2   = w + off; off += 48;
    float* cterm = w + off; off += 8;
    float* fw    = w + off; off += 512;
    float* ssR   = w + off; off += (size_t)NR_ * 4;
    float* ssV   = w + off; off += (size_t)NV_ * 4;
    int* iw = (int*)(w + off);
    size_t ioff = 0;
    int* row  = iw + ioff; ioff += NTOT_ + 1;
    int* cur  = iw + ioff; ioff += NTOT_;       // doubles as cnt (hist target)
    int* bsum = iw + ioff; ioff += SCAN_NB;
    int* boff = iw + ioff; ioff += SCAN_NB;
    int* cs   = iw + ioff; ioff += ETOT_;

    // ---- precompute folds ----
    precompute_kernel<<<14, 128, 0, stream>>>(Wsrc1, Wdst1, asrc1, adst1, Wsrc2, Wdst2, asrc2, adst2,
                                              Wp, bp, Wlin, blin, foldR, foldV, wp2, cterm, fw);

    // ---- CSR build (concatenated slot space) ----
    hipMemsetAsync(cur, 0, NTOT_ * sizeof(int), stream);   // cur used as cnt first
    hist_all<<<(ETOT_ + 255) / 256, 256, 0, stream>>>(ei_rr, ei_vr, ei_rv, cur);
    scan_reduce<<<SCAN_NB, 256, 0, stream>>>(cur, bsum);
    scan_bsums<<<1, 256, 0, stream>>>(bsum, boff, row);
    scan_write<<<SCAN_NB, 256, 0, stream>>>(cur, boff, row, cur);
    scatter_all<<<(ETOT_ + 255) / 256, 256, 0, stream>>>(ei_rr, ei_vr, ei_rv, cur, cs);

    for (int l = 0; l < 2; ++l) {
        const float* xri = (l == 0) ? x_req : xr;
        const float* xvi = (l == 0) ? x_veh : xv;
        const float* Ws = (l == 0) ? Wsrc1 : Wsrc2;
        const int KW = (l == 0) ? 16 : 128;
        const float* fR = foldR + (size_t)l * 128 * 8;
        const float* fV = foldV + (size_t)l * 128 * 4;

        if (l == 0) {
            gemm_kernel<16><<<(NR_ + 63) / 64, 256, 0, stream>>>(xri, Ws + 0 * KW * 128, hs_a, NR_);
            gemm_kernel<16><<<(NV_ + 63) / 64, 256, 0, stream>>>(xvi, Ws + 1 * KW * 128, hs_b, NV_);
            scores_multi<16, 8><<<(NR_ + 255) / 256, 256, 0, stream>>>(xri, fR, scR, NR_);
            scores_multi<16, 4><<<(NV_ + 255) / 256, 256, 0, stream>>>(xvi, fV, scV, NV_);
        } else {
            gemm_kernel<128><<<(NR_ + 63) / 64, 256, 0, stream>>>(xri, Ws + 0 * KW * 128, hs_a, NR_);
            gemm_kernel<128><<<(NV_ + 63) / 64, 256, 0, stream>>>(xvi, Ws + 1 * KW * 128, hs_b, NV_);
            scores_multi<128, 8><<<(NR_ + 255) / 256, 256, 0, stream>>>(xri, fR, scR, NR_);
            scores_multi<128, 4><<<(NV_ + 255) / 256, 256, 0, stream>>>(xvi, fV, scV, NV_);
        }
        agg_req<<<(NR_ + 3) / 4, 256, 0, stream>>>(row, cs, hs_a, hs_b, scR, scV, o_r, NR_);
        if (l == 0)
            gemm_kernel<16><<<(NR_ + 63) / 64, 256, 0, stream>>>(xri, Ws + 2 * KW * 128, hs_a, NR_);
        else
            gemm_kernel<128><<<(NR_ + 63) / 64, 256, 0, stream>>>(xri, Ws + 2 * KW * 128, hs_a, NR_);
        agg_veh<<<(NV_ + 3) / 4, 256, 0, stream>>>(row, cs, hs_a, scR, scV, o_v, NV_);

        hipMemsetAsync(s4, 0, 512 * sizeof(float), stream);
        bn_stats_all<<<BN_BLKS_R + BN_BLKS_V, 256, 0, stream>>>(o_r, o_v, s4);
        bn_norm_all<<<(int)(((size_t)(NR_ + NV_) * 128 + 255) / 256), 256, 0, stream>>>(
            o_r, o_v, s4, bn_gamma + l * 256, bn_beta + l * 256, xr, xv);
    }

    // ---- final head ----
    scores_multi<128, 4><<<(NR_ + 255) / 256, 256, 0, stream>>>(xr, fw, ssR, NR_);
    scores_multi<128, 4><<<(NV_ + 255) / 256, 256, 0, stream>>>(xv, fw, ssV, NV_);
    final_edge_all<<<(ETOT_ + 255) / 256, 256, 0, stream>>>(ei_rr, ei_vr, ei_rv, ea_rr, ea_vr, ea_rv,
                                                            ssR, ssV, wp2, cterm, out);
}

// Round 7
// 559.234 us; speedup vs baseline: 3.2799x; 1.0195x over previous
//
#include <hip/hip_runtime.h>
#include <hip/hip_bf16.h>

#define NR_ 40000
#define NV_ 4000
#define ERR_ 400000
#define EVR_ 150000
#define ERV_ 150000
#define ETOT_ (ERR_ + EVR_ + ERV_)
#define NTOT_ (NR_ + NR_ + NV_)
#define SCAN_ELEMS 512
#define SCAN_NB ((NTOT_ + SCAN_ELEMS - 1) / SCAN_ELEMS)
#define BN_BLKS_R ((NR_ + 63) / 64)
#define BN_BLKS_V ((NV_ + 63) / 64)
#define NEG_ 0.2f
#define EPS_ 1e-5f

__global__ void precompute_kernel(const float* __restrict__ Wsrc1, const float* __restrict__ Wdst1,
                                  const float* __restrict__ asrc1, const float* __restrict__ adst1,
                                  const float* __restrict__ Wsrc2, const float* __restrict__ Wdst2,
                                  const float* __restrict__ asrc2, const float* __restrict__ adst2,
                                  const float* __restrict__ Wp, const float* __restrict__ bp,
                                  const float* __restrict__ Wlin, const float* __restrict__ blin,
                                  float* __restrict__ foldR, float* __restrict__ foldV,
                                  float* __restrict__ wp2, float* __restrict__ cterm,
                                  float* __restrict__ fw) {
    int b = blockIdx.x;
    int t = threadIdx.x;  // 128
    if (b < 12) {
        int layer = b / 6, rel = (b % 6) / 2, side = b & 1;
        int K = (layer == 0) ? 16 : 128;
        const float* W = (layer == 0) ? (side ? Wdst1 : Wsrc1) : (side ? Wdst2 : Wsrc2);
        const float* a = (layer == 0) ? (side ? adst1 : asrc1) : (side ? adst2 : asrc2);
        W += (size_t)rel * K * 128;
        a += rel * 128;
        float* dst; int P; int colbase;
        if (rel == 0 && side == 0)      { dst = foldR; P = 8; colbase = 0; }
        else if (rel == 0)              { dst = foldR; P = 8; colbase = 2; }
        else if (rel == 1 && side == 0) { dst = foldV; P = 4; colbase = 0; }
        else if (rel == 1)              { dst = foldR; P = 8; colbase = 4; }
        else if (side == 0)             { dst = foldR; P = 8; colbase = 6; }
        else                            { dst = foldV; P = 4; colbase = 2; }
        dst += (size_t)layer * 128 * P;
        if (t < K) {
            for (int h = 0; h < 2; ++h) {
                float s = 0.f;
                for (int c = 0; c < 64; ++c) s += W[t * 128 + h * 64 + c] * a[h * 64 + c];
                dst[t * P + colbase + h] = s;
            }
        }
    } else if (b == 12) {
        if (t < 48) {
            int i = t / 16, k = (t / 2) % 8, o = t & 1;
            float s = 0.f;
            for (int c = 0; c < 64; ++c) s += Wp[(i * 8 + k) * 64 + c] * Wlin[(128 + c) * 2 + o];
            wp2[t] = s;
        } else if (t < 54) {
            int i = (t - 48) / 2, o = (t - 48) & 1;
            float s = blin[o];
            for (int c = 0; c < 64; ++c) s += bp[i * 64 + c] * Wlin[(128 + c) * 2 + o];
            cterm[i * 2 + o] = s;
        }
    } else {
        for (int idx = t; idx < 512; idx += 128) {
            int k = idx >> 2, c = idx & 3;
            fw[idx] = Wlin[(k + ((c >= 2) ? 192 : 0)) * 2 + (c & 1)];
        }
    }
}

__global__ void hist_all(const int* __restrict__ ei_rr, const int* __restrict__ ei_vr,
                         const int* __restrict__ ei_rv, int* __restrict__ cnt) {
    int j = blockIdx.x * blockDim.x + threadIdx.x;
    if (j < ERR_) atomicAdd(&cnt[ei_rr[ERR_ + j]], 1);
    else if (j < ERR_ + EVR_) atomicAdd(&cnt[NR_ + ei_vr[EVR_ + (j - ERR_)]], 1);
    else if (j < ETOT_) atomicAdd(&cnt[2 * NR_ + ei_rv[ERV_ + (j - ERR_ - EVR_)]], 1);
}

__global__ __launch_bounds__(256) void scan_reduce(const int* __restrict__ cnt, int* __restrict__ bsum) {
    __shared__ int buf[256];
    int t = threadIdx.x;
    int i0 = blockIdx.x * SCAN_ELEMS + t * 2;
    int s = 0;
    if (i0 + 1 < NTOT_) { int2 v = *(const int2*)&cnt[i0]; s = v.x + v.y; }
    else if (i0 < NTOT_) s = cnt[i0];
    buf[t] = s;
    __syncthreads();
    for (int off = 128; off; off >>= 1) {
        if (t < off) buf[t] += buf[t + off];
        __syncthreads();
    }
    if (t == 0) bsum[blockIdx.x] = buf[0];
}

__global__ __launch_bounds__(256) void scan_bsums(const int* __restrict__ bsum, int* __restrict__ boff,
                                                  int* __restrict__ row) {
    __shared__ int buf[256];
    int t = threadIdx.x;
    int s = (t < SCAN_NB) ? bsum[t] : 0;
    buf[t] = s;
    __syncthreads();
    for (int off = 1; off < 256; off <<= 1) {
        int v = (t >= off) ? buf[t - off] : 0;
        __syncthreads();
        buf[t] += v;
        __syncthreads();
    }
    if (t < SCAN_NB) boff[t] = buf[t] - s;
    if (t == 0) row[NTOT_] = ETOT_;
}

__global__ __launch_bounds__(256) void scan_write(const int* __restrict__ cnt, const int* __restrict__ boff,
                                                  int* __restrict__ row, int* __restrict__ cur) {
    __shared__ int buf[256];
    int t = threadIdx.x;
    int i0 = blockIdx.x * SCAN_ELEMS + t * 2;
    int vx = 0, vy = 0;
    if (i0 + 1 < NTOT_) { int2 v = *(const int2*)&cnt[i0]; vx = v.x; vy = v.y; }
    else if (i0 < NTOT_) vx = cnt[i0];
    int s = vx + vy;
    buf[t] = s;
    __syncthreads();
    for (int off = 1; off < 256; off <<= 1) {
        int v = (t >= off) ? buf[t - off] : 0;
        __syncthreads();
        buf[t] += v;
        __syncthreads();
    }
    int ex = buf[t] - s + boff[blockIdx.x];
    if (i0 + 1 < NTOT_) {
        *(int2*)&row[i0] = make_int2(ex, ex + vx);
        *(int2*)&cur[i0] = make_int2(ex, ex + vx);
    } else if (i0 < NTOT_) {
        row[i0] = ex;
        cur[i0] = ex;
    }
}

__global__ void scatter_all(const int* __restrict__ ei_rr, const int* __restrict__ ei_vr,
                            const int* __restrict__ ei_rv,
                            int* __restrict__ cur, int* __restrict__ cs) {
    int j = blockIdx.x * blockDim.x + threadIdx.x;
    int s, nidx;
    if (j < ERR_)             { s = ei_rr[j]; nidx = ei_rr[ERR_ + j]; }
    else if (j < ERR_ + EVR_) { int jj = j - ERR_; s = ei_vr[jj]; nidx = NR_ + ei_vr[EVR_ + jj]; }
    else if (j < ETOT_)       { int jj = j - ERR_ - EVR_; s = ei_rv[jj]; nidx = 2 * NR_ + ei_rv[ERV_ + jj]; }
    else return;
    int p = atomicAdd(&cur[nidx], 1);
    cs[p] = s;
}

// ===== fused projection GEMM: hs[0..NOUT) = x @ W_o, sc[n][P] = x @ fold; 32-row tiles =====

template <int K, int NOUT, int P>
__global__ __launch_bounds__(256) void gemm_fused(const float* __restrict__ x,
                                                  const float* __restrict__ W0,
                                                  const float* __restrict__ W1,
                                                  const float* __restrict__ fold,
                                                  float* __restrict__ h0, float* __restrict__ h1,
                                                  float* __restrict__ sc, int N) {
    constexpr int KC = (K < 32) ? K : 32;
    __shared__ float xs[32][KC];
    __shared__ float ws[NOUT][KC][128];
    __shared__ float fs[KC][P];
    int t = threadIdx.x;
    int cg4 = (t & 31) * 4;
    int rg4 = (t >> 5) * 4;
    int row0 = blockIdx.x * 32;
    float acc0[4][4] = {{0.f}};
    float acc1[4][4] = {{0.f}};
    float sacc = 0.f;
    int srow = t / P, scol = t % P;

    for (int k0 = 0; k0 < K; k0 += KC) {
        constexpr int KV = KC / 4;
        for (int v = t; v < 32 * KV; v += 256) {
            int r = v / KV, kk = (v % KV) * 4;
            int rr = row0 + r;
            float4 val = make_float4(0.f, 0.f, 0.f, 0.f);
            if (rr < N) val = *(const float4*)&x[(size_t)rr * K + k0 + kk];
            *(float4*)&xs[r][kk] = val;
        }
        constexpr int WV = KC * 128 / 4;
        {
            const float4* Wv = (const float4*)&W0[(size_t)k0 * 128];
            for (int v = t; v < WV; v += 256) ((float4*)&ws[0][0][0])[v] = Wv[v];
        }
        if (NOUT == 2) {
            const float4* Wv = (const float4*)&W1[(size_t)k0 * 128];
            for (int v = t; v < WV; v += 256) ((float4*)&ws[NOUT - 1][0][0])[v] = Wv[v];
        }
        for (int v = t; v < KC * P; v += 256) (&fs[0][0])[v] = fold[k0 * P + v];
        __syncthreads();

#pragma unroll
        for (int k = 0; k < KC; k += 4) {
            float4 xv[4];
#pragma unroll
            for (int i = 0; i < 4; ++i) xv[i] = *(const float4*)&xs[rg4 + i][k];
            {
                float4 w0 = *(const float4*)&ws[0][k + 0][cg4];
                float4 w1 = *(const float4*)&ws[0][k + 1][cg4];
                float4 w2 = *(const float4*)&ws[0][k + 2][cg4];
                float4 w3 = *(const float4*)&ws[0][k + 3][cg4];
#pragma unroll
                for (int i = 0; i < 4; ++i) {
                    acc0[i][0] += xv[i].x * w0.x + xv[i].y * w1.x + xv[i].z * w2.x + xv[i].w * w3.x;
                    acc0[i][1] += xv[i].x * w0.y + xv[i].y * w1.y + xv[i].z * w2.y + xv[i].w * w3.y;
                    acc0[i][2] += xv[i].x * w0.z + xv[i].y * w1.z + xv[i].z * w2.z + xv[i].w * w3.z;
                    acc0[i][3] += xv[i].x * w0.w + xv[i].y * w1.w + xv[i].z * w2.w + xv[i].w * w3.w;
                }
            }
            if (NOUT == 2) {
                float4 w0 = *(const float4*)&ws[NOUT - 1][k + 0][cg4];
                float4 w1 = *(const float4*)&ws[NOUT - 1][k + 1][cg4];
                float4 w2 = *(const float4*)&ws[NOUT - 1][k + 2][cg4];
                float4 w3 = *(const float4*)&ws[NOUT - 1][k + 3][cg4];
#pragma unroll
                for (int i = 0; i < 4; ++i) {
                    acc1[i][0] += xv[i].x * w0.x + xv[i].y * w1.x + xv[i].z * w2.x + xv[i].w * w3.x;
                    acc1[i][1] += xv[i].x * w0.y + xv[i].y * w1.y + xv[i].z * w2.y + xv[i].w * w3.y;
                    acc1[i][2] += xv[i].x * w0.z + xv[i].y * w1.z + xv[i].z * w2.z + xv[i].w * w3.z;
                    acc1[i][3] += xv[i].x * w0.w + xv[i].y * w1.w + xv[i].z * w2.w + xv[i].w * w3.w;
                }
            }
        }
        if (t < 32 * P) {
            float s = 0.f;
            for (int k = 0; k < KC; ++k) s += xs[srow][k] * fs[k][scol];
            sacc += s;
        }
        __syncthreads();
    }
#pragma unroll
    for (int i = 0; i < 4; ++i) {
        int rr = row0 + rg4 + i;
        if (rr < N) {
            *(float4*)&h0[(size_t)rr * 128 + cg4] =
                make_float4(acc0[i][0], acc0[i][1], acc0[i][2], acc0[i][3]);
            if (NOUT == 2)
                *(float4*)&h1[(size_t)rr * 128 + cg4] =
                    make_float4(acc1[i][0], acc1[i][1], acc1[i][2], acc1[i][3]);
        }
    }
    if (t < 32 * P && row0 + srow < N) sc[(size_t)(row0 + srow) * P + scol] = sacc;
}

template <int K, int P>
__global__ void scores_multi(const float* __restrict__ x, const float* __restrict__ fold,
                             float* __restrict__ sc, int N) {
    __shared__ float sf[K * P];
    for (int i = threadIdx.x; i < K * P; i += 256) sf[i] = fold[i];
    __syncthreads();
    int n = blockIdx.x * 256 + threadIdx.x;
    if (n >= N) return;
    float a[P];
#pragma unroll
    for (int p = 0; p < P; ++p) a[p] = 0.f;
    const float* xp = x + (size_t)n * K;
    for (int k = 0; k < K; k += 4) {
        float4 xv = *(const float4*)&xp[k];
#pragma unroll
        for (int p = 0; p < P; ++p)
            a[p] += xv.x * sf[k * P + p] + xv.y * sf[(k + 1) * P + p] +
                    xv.z * sf[(k + 2) * P + p] + xv.w * sf[(k + 3) * P + p];
    }
    float* o = sc + (size_t)n * P;
    *(float4*)o = make_float4(a[0], a[1], a[2], a[3]);
    if (P == 8) *(float4*)(o + 4) = make_float4(a[4], a[5], a[6], a[7]);
}

__device__ __forceinline__ void agg_rel_f2(int node, int lane,
                                           const int* __restrict__ row, const int* __restrict__ cs,
                                           const float* __restrict__ hs,
                                           const float* __restrict__ Ss, int sst, int sc, float edv,
                                           float& ox, float& oy) {
    int r0 = row[node], r1 = row[node + 1];
    if (r1 <= r0) return;
    float ax = 0.f, ay = 0.f, den = 0.f;
    int j = r0;
    for (; j + 4 <= r1; j += 4) {
        int s0 = cs[j + 0], s1 = cs[j + 1], s2 = cs[j + 2], s3 = cs[j + 3];
        float p0 = Ss[s0 * sst + sc];
        float p1 = Ss[s1 * sst + sc];
        float p2 = Ss[s2 * sst + sc];
        float p3 = Ss[s3 * sst + sc];
        float2 v0 = *(const float2*)&hs[(size_t)s0 * 128 + lane * 2];
        float2 v1 = *(const float2*)&hs[(size_t)s1 * 128 + lane * 2];
        float2 v2 = *(const float2*)&hs[(size_t)s2 * 128 + lane * 2];
        float2 v3 = *(const float2*)&hs[(size_t)s3 * 128 + lane * 2];
        float e0 = p0 + edv; e0 = (e0 >= 0.f) ? e0 : NEG_ * e0;
        float e1 = p1 + edv; e1 = (e1 >= 0.f) ? e1 : NEG_ * e1;
        float e2 = p2 + edv; e2 = (e2 >= 0.f) ? e2 : NEG_ * e2;
        float e3 = p3 + edv; e3 = (e3 >= 0.f) ? e3 : NEG_ * e3;
        float w0 = __expf(e0), w1 = __expf(e1), w2 = __expf(e2), w3 = __expf(e3);
        ax += v0.x * w0 + v1.x * w1 + v2.x * w2 + v3.x * w3;
        ay += v0.y * w0 + v1.y * w1 + v2.y * w2 + v3.y * w3;
        den += w0 + w1 + w2 + w3;
    }
    for (; j < r1; ++j) {
        int s = cs[j];
        float p = Ss[s * sst + sc];
        float2 v = *(const float2*)&hs[(size_t)s * 128 + lane * 2];
        float e = p + edv; e = (e >= 0.f) ? e : NEG_ * e;
        float w = __expf(e);
        ax += v.x * w;
        ay += v.y * w;
        den += w;
    }
    float inv = 1.f / den;
    ox += ax * inv;
    oy += ay * inv;
}

__global__ __launch_bounds__(256) void agg_req(
        const int* __restrict__ row, const int* __restrict__ cs,
        const float* __restrict__ hs_rr, const float* __restrict__ hs_vr,
        const float* __restrict__ scR, const float* __restrict__ scV,
        float* __restrict__ o, int N) {
    int node = blockIdx.x * 4 + (threadIdx.x >> 6);
    if (node >= N) return;
    int lane = threadIdx.x & 63;
    int hoff = lane >> 5;
    float ed_rr = scR[node * 8 + 2 + hoff];
    float ed_vr = scR[node * 8 + 4 + hoff];
    float ox = 0.f, oy = 0.f;
    agg_rel_f2(node, lane, row, cs, hs_rr, scR, 8, 0 + hoff, ed_rr, ox, oy);
    agg_rel_f2(node, lane, row + NR_, cs, hs_vr, scV, 4, 0 + hoff, ed_vr, ox, oy);
    *(float2*)&o[(size_t)node * 128 + lane * 2] = make_float2(ox * 0.5f, oy * 0.5f);
}

__global__ __launch_bounds__(256) void agg_veh(
        const int* __restrict__ row, const int* __restrict__ cs,
        const float* __restrict__ hs,
        const float* __restrict__ scR, const float* __restrict__ scV,
        float* __restrict__ o, int N) {
    int node = blockIdx.x * 4 + (threadIdx.x >> 6);
    if (node >= N) return;
    int lane = threadIdx.x & 63;
    int hoff = lane >> 5;
    float ed_rv = scV[node * 4 + 2 + hoff];
    float ox = 0.f, oy = 0.f;
    agg_rel_f2(node, lane, row + 2 * NR_, cs, hs, scR, 8, 6 + hoff, ed_rv, ox, oy);
    *(float2*)&o[(size_t)node * 128 + lane * 2] = make_float2(ox, oy);
}

__global__ __launch_bounds__(256) void bn_stats_all(const float* __restrict__ o_r,
                                                    const float* __restrict__ o_v,
                                                    float* __restrict__ s4) {
    int b = blockIdx.x;
    const float* o; int N; int r0; int soff;
    if (b < BN_BLKS_R) { o = o_r; N = NR_; r0 = b * 64; soff = 0; }
    else               { o = o_v; N = NV_; r0 = (b - BN_BLKS_R) * 64; soff = 128; }
    int wave = threadIdx.x >> 6, lane = threadIdx.x & 63;
    int rend = r0 + 64; if (rend > N) rend = N;
    float sx = 0.f, sy = 0.f, qx = 0.f, qy = 0.f;
    for (int r = r0 + wave; r < rend; r += 4) {
        float2 v = *(const float2*)&o[(size_t)r * 128 + lane * 2];
        sx += v.x; sy += v.y;
        qx += v.x * v.x; qy += v.y * v.y;
    }
    __shared__ float bs[4][128];
    __shared__ float bq[4][128];
    bs[wave][lane * 2] = sx;  bs[wave][lane * 2 + 1] = sy;
    bq[wave][lane * 2] = qx;  bq[wave][lane * 2 + 1] = qy;
    __syncthreads();
    if (threadIdx.x < 128) {
        int c = threadIdx.x;
        float s = bs[0][c] + bs[1][c] + bs[2][c] + bs[3][c];
        float q = bq[0][c] + bq[1][c] + bq[2][c] + bq[3][c];
        atomicAdd(&s4[soff + c], s);
        atomicAdd(&s4[256 + soff + c], q);
    }
}

__global__ void bn_norm_all(const float* __restrict__ o_r, const float* __restrict__ o_v,
                            const float* __restrict__ s4,
                            const float* __restrict__ gammaL, const float* __restrict__ betaL,
                            float* __restrict__ xr, float* __restrict__ xv) {
    size_t idx = blockIdx.x * (size_t)256 + threadIdx.x;
    const size_t nr = (size_t)NR_ * 128;
    const float* o; float* x; int soff; float invN; size_t i;
    if (idx < nr) { o = o_r; x = xr; soff = 0;   invN = 1.f / NR_; i = idx; }
    else          { o = o_v; x = xv; soff = 128; invN = 1.f / NV_; i = idx - nr; }
    int c = (int)(i & 127);
    float mu = s4[soff + c] * invN;
    float var = s4[256 + soff + c] * invN - mu * mu;
    float v = (o[i] - mu) * rsqrtf(var + EPS_) * gammaL[soff + c] + betaL[soff + c];
    x[i] = (v >= 0.f) ? v : NEG_ * v;
}

__global__ void final_edge_all(const int* __restrict__ ei_rr, const int* __restrict__ ei_vr,
                               const int* __restrict__ ei_rv,
                               const float* __restrict__ ea_rr, const float* __restrict__ ea_vr,
                               const float* __restrict__ ea_rv,
                               const float* __restrict__ ssR, const float* __restrict__ ssV,
                               const float* __restrict__ wp2, const float* __restrict__ cterm,
                               float* __restrict__ out) {
    int j = blockIdx.x * blockDim.x + threadIdx.x;
    if (j >= ETOT_) return;
    int rel, jj;
    const int* src; const int* dst; const float* ea; const float* ss; const float* sd; float* o;
    if (j < ERR_) {
        rel = 0; jj = j; src = ei_rr; dst = ei_rr + ERR_; ea = ea_rr; ss = ssR; sd = ssR; o = out;
    } else if (j < ERR_ + EVR_) {
        rel = 1; jj = j - ERR_; src = ei_vr; dst = ei_vr + EVR_; ea = ea_vr; ss = ssV; sd = ssR;
        o = out + (size_t)ERR_ * 2;
    } else {
        rel = 2; jj = j - ERR_ - EVR_; src = ei_rv; dst = ei_rv + ERV_; ea = ea_rv; ss = ssR; sd = ssV;
        o = out + (size_t)(ERR_ + EVR_) * 2;
    }
    int s = src[jj], d = dst[jj];
    float l0 = ss[s * 4 + 0] + sd[d * 4 + 2] + cterm[rel * 2 + 0];
    float l1 = ss[s * 4 + 1] + sd[d * 4 + 3] + cterm[rel * 2 + 1];
    const float* w = wp2 + rel * 16;
#pragma unroll
    for (int k = 0; k < 8; ++k) {
        float v = ea[(size_t)jj * 8 + k];
        l0 += v * w[k * 2 + 0];
        l1 += v * w[k * 2 + 1];
    }
    float m = fmaxf(l0, l1);
    float p0 = __expf(l0 - m), p1 = __expf(l1 - m);
    float inv = 1.f / (p0 + p1);
    o[(size_t)jj * 2 + 0] = p0 * inv;
    o[(size_t)jj * 2 + 1] = p1 * inv;
}

extern "C" void kernel_launch(void* const* d_in, const int* in_sizes, int n_in,
                              void* d_out, int out_size, void* d_ws, size_t ws_size,
                              hipStream_t stream) {
    const float* x_req = (const float*)d_in[0];
    const float* x_veh = (const float*)d_in[1];
    const int* ei_rr = (const int*)d_in[2];
    const int* ei_vr = (const int*)d_in[3];
    const int* ei_rv = (const int*)d_in[4];
    const float* ea_rr = (const float*)d_in[5];
    const float* ea_vr = (const float*)d_in[6];
    const float* ea_rv = (const float*)d_in[7];
    const float* Wsrc1 = (const float*)d_in[8];
    const float* Wdst1 = (const float*)d_in[9];
    const float* asrc1 = (const float*)d_in[10];
    const float* adst1 = (const float*)d_in[11];
    const float* Wsrc2 = (const float*)d_in[13];
    const float* Wdst2 = (const float*)d_in[14];
    const float* asrc2 = (const float*)d_in[15];
    const float* adst2 = (const float*)d_in[16];
    const float* bn_gamma = (const float*)d_in[18];
    const float* bn_beta  = (const float*)d_in[19];
    const float* Wp   = (const float*)d_in[20];
    const float* bp   = (const float*)d_in[21];
    const float* Wlin = (const float*)d_in[22];
    const float* blin = (const float*)d_in[23];
    float* out = (float*)d_out;

    float* w = (float*)d_ws;
    size_t off = 0;
    float* xr    = w + off; off += (size_t)NR_ * 128;
    float* xv    = w + off; off += (size_t)NV_ * 128;
    float* hs_a  = w + off; off += (size_t)NR_ * 128;
    float* hs_b  = w + off; off += (size_t)NV_ * 128;
    float* hs_c  = w + off; off += (size_t)NR_ * 128;
    float* o_r   = w + off; off += (size_t)NR_ * 128;
    float* o_v   = w + off; off += (size_t)NV_ * 128;
    float* scR   = w + off; off += (size_t)NR_ * 8;
    float* scV   = w + off; off += (size_t)NV_ * 4;
    float* s4    = w + off; off += 512;
    float* foldR = w + off; off += 2 * 128 * 8;
    float* foldV = w + off; off += 2 * 128 * 4;
    float* wp2   = w + off; off += 48;
    float* cterm = w + off; off += 8;
    float* fw    = w + off; off += 512;
    float* ssR   = w + off; off += (size_t)NR_ * 4;
    float* ssV   = w + off; off += (size_t)NV_ * 4;
    int* iw = (int*)(w + off);
    size_t ioff = 0;
    int* row  = iw + ioff; ioff += NTOT_ + 1;
    int* cur  = iw + ioff; ioff += NTOT_;
    int* bsum = iw + ioff; ioff += SCAN_NB;
    int* boff = iw + ioff; ioff += SCAN_NB;
    int* cs   = iw + ioff; ioff += ETOT_;

    precompute_kernel<<<14, 128, 0, stream>>>(Wsrc1, Wdst1, asrc1, adst1, Wsrc2, Wdst2, asrc2, adst2,
                                              Wp, bp, Wlin, blin, foldR, foldV, wp2, cterm, fw);

    hipMemsetAsync(cur, 0, NTOT_ * sizeof(int), stream);
    hist_all<<<(ETOT_ + 255) / 256, 256, 0, stream>>>(ei_rr, ei_vr, ei_rv, cur);
    scan_reduce<<<SCAN_NB, 256, 0, stream>>>(cur, bsum);
    scan_bsums<<<1, 256, 0, stream>>>(bsum, boff, row);
    scan_write<<<SCAN_NB, 256, 0, stream>>>(cur, boff, row, cur);
    scatter_all<<<(ETOT_ + 255) / 256, 256, 0, stream>>>(ei_rr, ei_vr, ei_rv, cur, cs);

    for (int l = 0; l < 2; ++l) {
        const float* xri = (l == 0) ? x_req : xr;
        const float* xvi = (l == 0) ? x_veh : xv;
        const float* Ws = (l == 0) ? Wsrc1 : Wsrc2;
        const int KW = (l == 0) ? 16 : 128;
        const float* fR = foldR + (size_t)l * 128 * 8;
        const float* fV = foldV + (size_t)l * 128 * 4;

        if (l == 0) {
            gemm_fused<16, 2, 8><<<(NR_ + 31) / 32, 256, 0, stream>>>(
                xri, Ws + 0 * KW * 128, Ws + 2 * KW * 128, fR, hs_a, hs_c, scR, NR_);
            gemm_fused<16, 1, 4><<<(NV_ + 31) / 32, 256, 0, stream>>>(
                xvi, Ws + 1 * KW * 128, nullptr, fV, hs_b, nullptr, scV, NV_);
        } else {
            gemm_fused<128, 2, 8><<<(NR_ + 31) / 32, 256, 0, stream>>>(
                xri, Ws + 0 * KW * 128, Ws + 2 * KW * 128, fR, hs_a, hs_c, scR, NR_);
            gemm_fused<128, 1, 4><<<(NV_ + 31) / 32, 256, 0, stream>>>(
                xvi, Ws + 1 * KW * 128, nullptr, fV, hs_b, nullptr, scV, NV_);
        }
        agg_req<<<(NR_ + 3) / 4, 256, 0, stream>>>(row, cs, hs_a, hs_b, scR, scV, o_r, NR_);
        agg_veh<<<(NV_ + 3) / 4, 256, 0, stream>>>(row, cs, hs_c, scR, scV, o_v, NV_);

        hipMemsetAsync(s4, 0, 512 * sizeof(float), stream);
        bn_stats_all<<<BN_BLKS_R + BN_BLKS_V, 256, 0, stream>>>(o_r, o_v, s4);
        bn_norm_all<<<(int)(((size_t)(NR_ + NV_) * 128 + 255) / 256), 256, 0, stream>>>(
            o_r, o_v, s4, bn_gamma + l * 256, bn_beta + l * 256, xr, xv);
    }

    scores_multi<128, 4><<<(NR_ + 255) / 256, 256, 0, stream>>>(xr, fw, ssR, NR_);
    scores_multi<128, 4><<<(NV_ + 255) / 256, 256, 0, stream>>>(xv, fw, ssV, NV_);
    final_edge_all<<<(ETOT_ + 255) / 256, 256, 0, stream>>>(ei_rr, ei_vr, ei_rv, ea_rr, ea_vr, ea_rv,
                                                            ssR, ssV, wp2, cterm, out);
}

// Round 8
// 542.544 us; speedup vs baseline: 3.3808x; 1.0308x over previous
//
#include <hip/hip_runtime.h>
#include <hip/hip_bf16.h>

#define NR_ 40000
#define NV_ 4000
#define ERR_ 400000
#define EVR_ 150000
#define ERV_ 150000
#define ETOT_ (ERR_ + EVR_ + ERV_)
#define NTOT_ (NR_ + NR_ + NV_)
#define SCAN_ELEMS 512
#define SCAN_NB ((NTOT_ + SCAN_ELEMS - 1) / SCAN_ELEMS)
#define BN_BLKS_R ((NR_ + 63) / 64)
#define BN_BLKS_V ((NV_ + 63) / 64)
#define NEG_ 0.2f
#define EPS_ 1e-5f

__global__ void precompute_kernel(const float* __restrict__ Wsrc1, const float* __restrict__ Wdst1,
                                  const float* __restrict__ asrc1, const float* __restrict__ adst1,
                                  const float* __restrict__ Wsrc2, const float* __restrict__ Wdst2,
                                  const float* __restrict__ asrc2, const float* __restrict__ adst2,
                                  const float* __restrict__ Wp, const float* __restrict__ bp,
                                  const float* __restrict__ Wlin, const float* __restrict__ blin,
                                  float* __restrict__ foldR, float* __restrict__ foldV,
                                  float* __restrict__ wp2, float* __restrict__ cterm,
                                  float* __restrict__ fw) {
    int b = blockIdx.x;
    int t = threadIdx.x;  // 128
    if (b < 12) {
        int layer = b / 6, rel = (b % 6) / 2, side = b & 1;
        int K = (layer == 0) ? 16 : 128;
        const float* W = (layer == 0) ? (side ? Wdst1 : Wsrc1) : (side ? Wdst2 : Wsrc2);
        const float* a = (layer == 0) ? (side ? adst1 : asrc1) : (side ? adst2 : asrc2);
        W += (size_t)rel * K * 128;
        a += rel * 128;
        float* dst; int P; int colbase;
        if (rel == 0 && side == 0)      { dst = foldR; P = 8; colbase = 0; }
        else if (rel == 0)              { dst = foldR; P = 8; colbase = 2; }
        else if (rel == 1 && side == 0) { dst = foldV; P = 4; colbase = 0; }
        else if (rel == 1)              { dst = foldR; P = 8; colbase = 4; }
        else if (side == 0)             { dst = foldR; P = 8; colbase = 6; }
        else                            { dst = foldV; P = 4; colbase = 2; }
        dst += (size_t)layer * 128 * P;
        if (t < K) {
            for (int h = 0; h < 2; ++h) {
                float s = 0.f;
                for (int c = 0; c < 64; ++c) s += W[t * 128 + h * 64 + c] * a[h * 64 + c];
                dst[t * P + colbase + h] = s;
            }
        }
    } else if (b == 12) {
        if (t < 48) {
            int i = t / 16, k = (t / 2) % 8, o = t & 1;
            float s = 0.f;
            for (int c = 0; c < 64; ++c) s += Wp[(i * 8 + k) * 64 + c] * Wlin[(128 + c) * 2 + o];
            wp2[t] = s;
        } else if (t < 54) {
            int i = (t - 48) / 2, o = (t - 48) & 1;
            float s = blin[o];
            for (int c = 0; c < 64; ++c) s += bp[i * 64 + c] * Wlin[(128 + c) * 2 + o];
            cterm[i * 2 + o] = s;
        }
    } else {
        for (int idx = t; idx < 512; idx += 128) {
            int k = idx >> 2, c = idx & 3;
            fw[idx] = Wlin[(k + ((c >= 2) ? 192 : 0)) * 2 + (c & 1)];
        }
    }
}

__global__ void hist_all(const int* __restrict__ ei_rr, const int* __restrict__ ei_vr,
                         const int* __restrict__ ei_rv, int* __restrict__ cnt) {
    int j = blockIdx.x * blockDim.x + threadIdx.x;
    if (j < ERR_) atomicAdd(&cnt[ei_rr[ERR_ + j]], 1);
    else if (j < ERR_ + EVR_) atomicAdd(&cnt[NR_ + ei_vr[EVR_ + (j - ERR_)]], 1);
    else if (j < ETOT_) atomicAdd(&cnt[2 * NR_ + ei_rv[ERV_ + (j - ERR_ - EVR_)]], 1);
}

__global__ __launch_bounds__(256) void scan_reduce(const int* __restrict__ cnt, int* __restrict__ bsum) {
    __shared__ int buf[256];
    int t = threadIdx.x;
    int i0 = blockIdx.x * SCAN_ELEMS + t * 2;
    int s = 0;
    if (i0 + 1 < NTOT_) { int2 v = *(const int2*)&cnt[i0]; s = v.x + v.y; }
    else if (i0 < NTOT_) s = cnt[i0];
    buf[t] = s;
    __syncthreads();
    for (int off = 128; off; off >>= 1) {
        if (t < off) buf[t] += buf[t + off];
        __syncthreads();
    }
    if (t == 0) bsum[blockIdx.x] = buf[0];
}

__global__ __launch_bounds__(256) void scan_bsums(const int* __restrict__ bsum, int* __restrict__ boff,
                                                  int* __restrict__ row) {
    __shared__ int buf[256];
    int t = threadIdx.x;
    int s = (t < SCAN_NB) ? bsum[t] : 0;
    buf[t] = s;
    __syncthreads();
    for (int off = 1; off < 256; off <<= 1) {
        int v = (t >= off) ? buf[t - off] : 0;
        __syncthreads();
        buf[t] += v;
        __syncthreads();
    }
    if (t < SCAN_NB) boff[t] = buf[t] - s;
    if (t == 0) row[NTOT_] = ETOT_;
}

__global__ __launch_bounds__(256) void scan_write(const int* __restrict__ cnt, const int* __restrict__ boff,
                                                  int* __restrict__ row, int* __restrict__ cur) {
    __shared__ int buf[256];
    int t = threadIdx.x;
    int i0 = blockIdx.x * SCAN_ELEMS + t * 2;
    int vx = 0, vy = 0;
    if (i0 + 1 < NTOT_) { int2 v = *(const int2*)&cnt[i0]; vx = v.x; vy = v.y; }
    else if (i0 < NTOT_) vx = cnt[i0];
    int s = vx + vy;
    buf[t] = s;
    __syncthreads();
    for (int off = 1; off < 256; off <<= 1) {
        int v = (t >= off) ? buf[t - off] : 0;
        __syncthreads();
        buf[t] += v;
        __syncthreads();
    }
    int ex = buf[t] - s + boff[blockIdx.x];
    if (i0 + 1 < NTOT_) {
        *(int2*)&row[i0] = make_int2(ex, ex + vx);
        *(int2*)&cur[i0] = make_int2(ex, ex + vx);
    } else if (i0 < NTOT_) {
        row[i0] = ex;
        cur[i0] = ex;
    }
}

__global__ void scatter_all(const int* __restrict__ ei_rr, const int* __restrict__ ei_vr,
                            const int* __restrict__ ei_rv,
                            int* __restrict__ cur, int* __restrict__ cs) {
    int j = blockIdx.x * blockDim.x + threadIdx.x;
    int s, nidx;
    if (j < ERR_)             { s = ei_rr[j]; nidx = ei_rr[ERR_ + j]; }
    else if (j < ERR_ + EVR_) { int jj = j - ERR_; s = ei_vr[jj]; nidx = NR_ + ei_vr[EVR_ + jj]; }
    else if (j < ETOT_)       { int jj = j - ERR_ - EVR_; s = ei_rv[jj]; nidx = 2 * NR_ + ei_rv[ERV_ + jj]; }
    else return;
    int p = atomicAdd(&cur[nidx], 1);
    cs[p] = s;
}

// ===== projection GEMM, 32-row tiles, single W, optional fused scores =====
// xs padded by +4 floats/row: main-loop reads are broadcasts; score-tail banks
// become (srow*(KC+4)+k)%32 -> distinct across srow -> conflict-free.

template <int K, int P>
__global__ __launch_bounds__(256) void gemm32(const float* __restrict__ x,
                                              const float* __restrict__ W,
                                              const float* __restrict__ fold,
                                              float* __restrict__ hs,
                                              float* __restrict__ sc, int N) {
    constexpr int KC = (K < 32) ? K : 32;
    __shared__ float xs[32][KC + 4];
    __shared__ float ws[KC][128];
    __shared__ float fs[(P > 0) ? KC * P : 1];
    int t = threadIdx.x;
    int cg4 = (t & 31) * 4;
    int rg4 = (t >> 5) * 4;
    int row0 = blockIdx.x * 32;
    float acc[4][4] = {{0.f}};
    float sacc = 0.f;
    int srow = (P > 0) ? (t / P) : 0;
    int scol = (P > 0) ? (t % P) : 0;

    for (int k0 = 0; k0 < K; k0 += KC) {
        constexpr int KV = KC / 4;
        for (int v = t; v < 32 * KV; v += 256) {
            int r = v / KV, kk = (v % KV) * 4;
            int rr = row0 + r;
            float4 val = make_float4(0.f, 0.f, 0.f, 0.f);
            if (rr < N) val = *(const float4*)&x[(size_t)rr * K + k0 + kk];
            *(float4*)&xs[r][kk] = val;
        }
        constexpr int WV = KC * 128 / 4;
        const float4* Wv = (const float4*)&W[(size_t)k0 * 128];
        for (int v = t; v < WV; v += 256) ((float4*)&ws[0][0])[v] = Wv[v];
        if (P > 0)
            for (int v = t; v < KC * P; v += 256) fs[v] = fold[k0 * P + v];
        __syncthreads();

#pragma unroll
        for (int k = 0; k < KC; k += 4) {
            float4 xv[4];
#pragma unroll
            for (int i = 0; i < 4; ++i) xv[i] = *(const float4*)&xs[rg4 + i][k];
            float4 w0 = *(const float4*)&ws[k + 0][cg4];
            float4 w1 = *(const float4*)&ws[k + 1][cg4];
            float4 w2 = *(const float4*)&ws[k + 2][cg4];
            float4 w3 = *(const float4*)&ws[k + 3][cg4];
#pragma unroll
            for (int i = 0; i < 4; ++i) {
                acc[i][0] += xv[i].x * w0.x + xv[i].y * w1.x + xv[i].z * w2.x + xv[i].w * w3.x;
                acc[i][1] += xv[i].x * w0.y + xv[i].y * w1.y + xv[i].z * w2.y + xv[i].w * w3.y;
                acc[i][2] += xv[i].x * w0.z + xv[i].y * w1.z + xv[i].z * w2.z + xv[i].w * w3.z;
                acc[i][3] += xv[i].x * w0.w + xv[i].y * w1.w + xv[i].z * w2.w + xv[i].w * w3.w;
            }
        }
        if (P > 0 && t < 32 * P) {
            float s = 0.f;
            for (int k = 0; k < KC; ++k) s += xs[srow][k] * fs[k * P + scol];
            sacc += s;
        }
        __syncthreads();
    }
#pragma unroll
    for (int i = 0; i < 4; ++i) {
        int rr = row0 + rg4 + i;
        if (rr < N)
            *(float4*)&hs[(size_t)rr * 128 + cg4] =
                make_float4(acc[i][0], acc[i][1], acc[i][2], acc[i][3]);
    }
    if (P > 0 && t < 32 * P && row0 + srow < N)
        sc[(size_t)(row0 + srow) * P + scol] = sacc;
}

template <int K, int P>
__global__ void scores_multi(const float* __restrict__ x, const float* __restrict__ fold,
                             float* __restrict__ sc, int N) {
    __shared__ float sf[K * P];
    for (int i = threadIdx.x; i < K * P; i += 256) sf[i] = fold[i];
    __syncthreads();
    int n = blockIdx.x * 256 + threadIdx.x;
    if (n >= N) return;
    float a[P];
#pragma unroll
    for (int p = 0; p < P; ++p) a[p] = 0.f;
    const float* xp = x + (size_t)n * K;
    for (int k = 0; k < K; k += 4) {
        float4 xv = *(const float4*)&xp[k];
#pragma unroll
        for (int p = 0; p < P; ++p)
            a[p] += xv.x * sf[k * P + p] + xv.y * sf[(k + 1) * P + p] +
                    xv.z * sf[(k + 2) * P + p] + xv.w * sf[(k + 3) * P + p];
    }
    float* o = sc + (size_t)n * P;
    *(float4*)o = make_float4(a[0], a[1], a[2], a[3]);
    if (P == 8) *(float4*)(o + 4) = make_float4(a[4], a[5], a[6], a[7]);
}

__device__ __forceinline__ void agg_rel_f2(int node, int lane,
                                           const int* __restrict__ row, const int* __restrict__ cs,
                                           const float* __restrict__ hs,
                                           const float* __restrict__ Ss, int sst, int sc, float edv,
                                           float& ox, float& oy) {
    int r0 = row[node], r1 = row[node + 1];
    if (r1 <= r0) return;
    float ax = 0.f, ay = 0.f, den = 0.f;
    int j = r0;
    for (; j + 4 <= r1; j += 4) {
        int s0 = cs[j + 0], s1 = cs[j + 1], s2 = cs[j + 2], s3 = cs[j + 3];
        float p0 = Ss[s0 * sst + sc];
        float p1 = Ss[s1 * sst + sc];
        float p2 = Ss[s2 * sst + sc];
        float p3 = Ss[s3 * sst + sc];
        float2 v0 = *(const float2*)&hs[(size_t)s0 * 128 + lane * 2];
        float2 v1 = *(const float2*)&hs[(size_t)s1 * 128 + lane * 2];
        float2 v2 = *(const float2*)&hs[(size_t)s2 * 128 + lane * 2];
        float2 v3 = *(const float2*)&hs[(size_t)s3 * 128 + lane * 2];
        float e0 = p0 + edv; e0 = (e0 >= 0.f) ? e0 : NEG_ * e0;
        float e1 = p1 + edv; e1 = (e1 >= 0.f) ? e1 : NEG_ * e1;
        float e2 = p2 + edv; e2 = (e2 >= 0.f) ? e2 : NEG_ * e2;
        float e3 = p3 + edv; e3 = (e3 >= 0.f) ? e3 : NEG_ * e3;
        float w0 = __expf(e0), w1 = __expf(e1), w2 = __expf(e2), w3 = __expf(e3);
        ax += v0.x * w0 + v1.x * w1 + v2.x * w2 + v3.x * w3;
        ay += v0.y * w0 + v1.y * w1 + v2.y * w2 + v3.y * w3;
        den += w0 + w1 + w2 + w3;
    }
    for (; j < r1; ++j) {
        int s = cs[j];
        float p = Ss[s * sst + sc];
        float2 v = *(const float2*)&hs[(size_t)s * 128 + lane * 2];
        float e = p + edv; e = (e >= 0.f) ? e : NEG_ * e;
        float w = __expf(e);
        ax += v.x * w;
        ay += v.y * w;
        den += w;
    }
    float inv = 1.f / den;
    ox += ax * inv;
    oy += ay * inv;
}

__global__ __launch_bounds__(256) void agg_req(
        const int* __restrict__ row, const int* __restrict__ cs,
        const float* __restrict__ hs_rr, const float* __restrict__ hs_vr,
        const float* __restrict__ scR, const float* __restrict__ scV,
        float* __restrict__ o, int N) {
    int node = blockIdx.x * 4 + (threadIdx.x >> 6);
    if (node >= N) return;
    int lane = threadIdx.x & 63;
    int hoff = lane >> 5;
    float ed_rr = scR[node * 8 + 2 + hoff];
    float ed_vr = scR[node * 8 + 4 + hoff];
    float ox = 0.f, oy = 0.f;
    agg_rel_f2(node, lane, row, cs, hs_rr, scR, 8, 0 + hoff, ed_rr, ox, oy);
    agg_rel_f2(node, lane, row + NR_, cs, hs_vr, scV, 4, 0 + hoff, ed_vr, ox, oy);
    *(float2*)&o[(size_t)node * 128 + lane * 2] = make_float2(ox * 0.5f, oy * 0.5f);
}

__global__ __launch_bounds__(256) void agg_veh(
        const int* __restrict__ row, const int* __restrict__ cs,
        const float* __restrict__ hs,
        const float* __restrict__ scR, const float* __restrict__ scV,
        float* __restrict__ o, int N) {
    int node = blockIdx.x * 4 + (threadIdx.x >> 6);
    if (node >= N) return;
    int lane = threadIdx.x & 63;
    int hoff = lane >> 5;
    float ed_rv = scV[node * 4 + 2 + hoff];
    float ox = 0.f, oy = 0.f;
    agg_rel_f2(node, lane, row + 2 * NR_, cs, hs, scR, 8, 6 + hoff, ed_rv, ox, oy);
    *(float2*)&o[(size_t)node * 128 + lane * 2] = make_float2(ox, oy);
}

__global__ __launch_bounds__(256) void bn_stats_all(const float* __restrict__ o_r,
                                                    const float* __restrict__ o_v,
                                                    float* __restrict__ s4) {
    int b = blockIdx.x;
    const float* o; int N; int r0; int soff;
    if (b < BN_BLKS_R) { o = o_r; N = NR_; r0 = b * 64; soff = 0; }
    else               { o = o_v; N = NV_; r0 = (b - BN_BLKS_R) * 64; soff = 128; }
    int wave = threadIdx.x >> 6, lane = threadIdx.x & 63;
    int rend = r0 + 64; if (rend > N) rend = N;
    float sx = 0.f, sy = 0.f, qx = 0.f, qy = 0.f;
    for (int r = r0 + wave; r < rend; r += 4) {
        float2 v = *(const float2*)&o[(size_t)r * 128 + lane * 2];
        sx += v.x; sy += v.y;
        qx += v.x * v.x; qy += v.y * v.y;
    }
    __shared__ float bs[4][128];
    __shared__ float bq[4][128];
    bs[wave][lane * 2] = sx;  bs[wave][lane * 2 + 1] = sy;
    bq[wave][lane * 2] = qx;  bq[wave][lane * 2 + 1] = qy;
    __syncthreads();
    if (threadIdx.x < 128) {
        int c = threadIdx.x;
        float s = bs[0][c] + bs[1][c] + bs[2][c] + bs[3][c];
        float q = bq[0][c] + bq[1][c] + bq[2][c] + bq[3][c];
        atomicAdd(&s4[soff + c], s);
        atomicAdd(&s4[256 + soff + c], q);
    }
}

__global__ void bn_norm_all(const float* __restrict__ o_r, const float* __restrict__ o_v,
                            const float* __restrict__ s4,
                            const float* __restrict__ gammaL, const float* __restrict__ betaL,
                            float* __restrict__ xr, float* __restrict__ xv) {
    size_t idx = blockIdx.x * (size_t)256 + threadIdx.x;
    const size_t nr = (size_t)NR_ * 128;
    const float* o; float* x; int soff; float invN; size_t i;
    if (idx < nr) { o = o_r; x = xr; soff = 0;   invN = 1.f / NR_; i = idx; }
    else          { o = o_v; x = xv; soff = 128; invN = 1.f / NV_; i = idx - nr; }
    int c = (int)(i & 127);
    float mu = s4[soff + c] * invN;
    float var = s4[256 + soff + c] * invN - mu * mu;
    float v = (o[i] - mu) * rsqrtf(var + EPS_) * gammaL[soff + c] + betaL[soff + c];
    x[i] = (v >= 0.f) ? v : NEG_ * v;
}

__global__ void final_edge_all(const int* __restrict__ ei_rr, const int* __restrict__ ei_vr,
                               const int* __restrict__ ei_rv,
                               const float* __restrict__ ea_rr, const float* __restrict__ ea_vr,
                               const float* __restrict__ ea_rv,
                               const float* __restrict__ ssR, const float* __restrict__ ssV,
                               const float* __restrict__ wp2, const float* __restrict__ cterm,
                               float* __restrict__ out) {
    int j = blockIdx.x * blockDim.x + threadIdx.x;
    if (j >= ETOT_) return;
    int rel, jj;
    const int* src; const int* dst; const float* ea; const float* ss; const float* sd; float* o;
    if (j < ERR_) {
        rel = 0; jj = j; src = ei_rr; dst = ei_rr + ERR_; ea = ea_rr; ss = ssR; sd = ssR; o = out;
    } else if (j < ERR_ + EVR_) {
        rel = 1; jj = j - ERR_; src = ei_vr; dst = ei_vr + EVR_; ea = ea_vr; ss = ssV; sd = ssR;
        o = out + (size_t)ERR_ * 2;
    } else {
        rel = 2; jj = j - ERR_ - EVR_; src = ei_rv; dst = ei_rv + ERV_; ea = ea_rv; ss = ssR; sd = ssV;
        o = out + (size_t)(ERR_ + EVR_) * 2;
    }
    int s = src[jj], d = dst[jj];
    float l0 = ss[s * 4 + 0] + sd[d * 4 + 2] + cterm[rel * 2 + 0];
    float l1 = ss[s * 4 + 1] + sd[d * 4 + 3] + cterm[rel * 2 + 1];
    const float* w = wp2 + rel * 16;
#pragma unroll
    for (int k = 0; k < 8; ++k) {
        float v = ea[(size_t)jj * 8 + k];
        l0 += v * w[k * 2 + 0];
        l1 += v * w[k * 2 + 1];
    }
    float m = fmaxf(l0, l1);
    float p0 = __expf(l0 - m), p1 = __expf(l1 - m);
    float inv = 1.f / (p0 + p1);
    o[(size_t)jj * 2 + 0] = p0 * inv;
    o[(size_t)jj * 2 + 1] = p1 * inv;
}

extern "C" void kernel_launch(void* const* d_in, const int* in_sizes, int n_in,
                              void* d_out, int out_size, void* d_ws, size_t ws_size,
                              hipStream_t stream) {
    const float* x_req = (const float*)d_in[0];
    const float* x_veh = (const float*)d_in[1];
    const int* ei_rr = (const int*)d_in[2];
    const int* ei_vr = (const int*)d_in[3];
    const int* ei_rv = (const int*)d_in[4];
    const float* ea_rr = (const float*)d_in[5];
    const float* ea_vr = (const float*)d_in[6];
    const float* ea_rv = (const float*)d_in[7];
    const float* Wsrc1 = (const float*)d_in[8];
    const float* Wdst1 = (const float*)d_in[9];
    const float* asrc1 = (const float*)d_in[10];
    const float* adst1 = (const float*)d_in[11];
    const float* Wsrc2 = (const float*)d_in[13];
    const float* Wdst2 = (const float*)d_in[14];
    const float* asrc2 = (const float*)d_in[15];
    const float* adst2 = (const float*)d_in[16];
    const float* bn_gamma = (const float*)d_in[18];
    const float* bn_beta  = (const float*)d_in[19];
    const float* Wp   = (const float*)d_in[20];
    const float* bp   = (const float*)d_in[21];
    const float* Wlin = (const float*)d_in[22];
    const float* blin = (const float*)d_in[23];
    float* out = (float*)d_out;

    float* w = (float*)d_ws;
    size_t off = 0;
    float* xr    = w + off; off += (size_t)NR_ * 128;
    float* xv    = w + off; off += (size_t)NV_ * 128;
    float* hs_a  = w + off; off += (size_t)NR_ * 128;
    float* hs_b  = w + off; off += (size_t)NV_ * 128;
    float* hs_c  = w + off; off += (size_t)NR_ * 128;
    float* o_r   = w + off; off += (size_t)NR_ * 128;
    float* o_v   = w + off; off += (size_t)NV_ * 128;
    float* scR   = w + off; off += (size_t)NR_ * 8;
    float* scV   = w + off; off += (size_t)NV_ * 4;
    float* s4    = w + off; off += 512;
    float* foldR = w + off; off += 2 * 128 * 8;
    float* foldV = w + off; off += 2 * 128 * 4;
    float* wp2   = w + off; off += 48;
    float* cterm = w + off; off += 8;
    float* fw    = w + off; off += 512;
    float* ssR   = w + off; off += (size_t)NR_ * 4;
    float* ssV   = w + off; off += (size_t)NV_ * 4;
    int* iw = (int*)(w + off);
    size_t ioff = 0;
    int* row  = iw + ioff; ioff += NTOT_ + 1;
    int* cur  = iw + ioff; ioff += NTOT_;
    int* bsum = iw + ioff; ioff += SCAN_NB;
    int* boff = iw + ioff; ioff += SCAN_NB;
    int* cs   = iw + ioff; ioff += ETOT_;

    precompute_kernel<<<14, 128, 0, stream>>>(Wsrc1, Wdst1, asrc1, adst1, Wsrc2, Wdst2, asrc2, adst2,
                                              Wp, bp, Wlin, blin, foldR, foldV, wp2, cterm, fw);

    hipMemsetAsync(cur, 0, NTOT_ * sizeof(int), stream);
    hist_all<<<(ETOT_ + 255) / 256, 256, 0, stream>>>(ei_rr, ei_vr, ei_rv, cur);
    scan_reduce<<<SCAN_NB, 256, 0, stream>>>(cur, bsum);
    scan_bsums<<<1, 256, 0, stream>>>(bsum, boff, row);
    scan_write<<<SCAN_NB, 256, 0, stream>>>(cur, boff, row, cur);
    scatter_all<<<(ETOT_ + 255) / 256, 256, 0, stream>>>(ei_rr, ei_vr, ei_rv, cur, cs);

    for (int l = 0; l < 2; ++l) {
        const float* xri = (l == 0) ? x_req : xr;
        const float* xvi = (l == 0) ? x_veh : xv;
        const float* Ws = (l == 0) ? Wsrc1 : Wsrc2;
        const int KW = (l == 0) ? 16 : 128;
        const float* fR = foldR + (size_t)l * 128 * 8;
        const float* fV = foldV + (size_t)l * 128 * 4;

        if (l == 0) {
            gemm32<16, 8><<<(NR_ + 31) / 32, 256, 0, stream>>>(xri, Ws + 0 * KW * 128, fR, hs_a, scR, NR_);
            gemm32<16, 0><<<(NR_ + 31) / 32, 256, 0, stream>>>(xri, Ws + 2 * KW * 128, nullptr, hs_c, nullptr, NR_);
            gemm32<16, 4><<<(NV_ + 31) / 32, 256, 0, stream>>>(xvi, Ws + 1 * KW * 128, fV, hs_b, scV, NV_);
        } else {
            gemm32<128, 8><<<(NR_ + 31) / 32, 256, 0, stream>>>(xri, Ws + 0 * KW * 128, fR, hs_a, scR, NR_);
            gemm32<128, 0><<<(NR_ + 31) / 32, 256, 0, stream>>>(xri, Ws + 2 * KW * 128, nullptr, hs_c, nullptr, NR_);
            gemm32<128, 4><<<(NV_ + 31) / 32, 256, 0, stream>>>(xvi, Ws + 1 * KW * 128, fV, hs_b, scV, NV_);
        }
        agg_req<<<(NR_ + 3) / 4, 256, 0, stream>>>(row, cs, hs_a, hs_b, scR, scV, o_r, NR_);
        agg_veh<<<(NV_ + 3) / 4, 256, 0, stream>>>(row, cs, hs_c, scR, scV, o_v, NV_);

        hipMemsetAsync(s4, 0, 512 * sizeof(float), stream);
        bn_stats_all<<<BN_BLKS_R + BN_BLKS_V, 256, 0, stream>>>(o_r, o_v, s4);
        bn_norm_all<<<(int)(((size_t)(NR_ + NV_) * 128 + 255) / 256), 256, 0, stream>>>(
            o_r, o_v, s4, bn_gamma + l * 256, bn_beta + l * 256, xr, xv);
    }

    scores_multi<128, 4><<<(NR_ + 255) / 256, 256, 0, stream>>>(xr, fw, ssR, NR_);
    scores_multi<128, 4><<<(NV_ + 255) / 256, 256, 0, stream>>>(xv, fw, ssV, NV_);
    final_edge_all<<<(ETOT_ + 255) / 256, 256, 0, stream>>>(ei_rr, ei_vr, ei_rv, ea_rr, ea_vr, ea_rv,
                                                            ssR, ssV, wp2, cterm, out);
}

// Round 9
// 502.074 us; speedup vs baseline: 3.6533x; 1.0806x over previous
//
#include <hip/hip_runtime.h>
#include <hip/hip_bf16.h>

#define NR_ 40000
#define NV_ 4000
#define ERR_ 400000
#define EVR_ 150000
#define ERV_ 150000
#define ETOT_ (ERR_ + EVR_ + ERV_)
#define NTOT_ (NR_ + NR_ + NV_)
#define SCAN_ELEMS 512
#define SCAN_NB ((NTOT_ + SCAN_ELEMS - 1) / SCAN_ELEMS)
#define BN_BLKS_R ((NR_ + 63) / 64)
#define BN_BLKS_V ((NV_ + 63) / 64)
#define SCB_R ((NR_ + 255) / 256)   // 157
#define SCB_V ((NV_ + 255) / 256)   // 16
#define NEG_ 0.2f
#define EPS_ 1e-5f

typedef __attribute__((ext_vector_type(8))) __bf16 bfrag;
typedef __attribute__((ext_vector_type(4))) float ffrag;

// ================= precompute: folds + bf16-transposed layer-2 weights =================
// foldR[l][k][8]: es_rr(0,1) ed_rr(2,3) ed_vr(4,5) es_rv(6,7); foldV[l][k][4]: es_vr(0,1) ed_rv(2,3)
// Wt[rel][n][k] = (bf16) Wsrc2[rel][k][n]  -- B-operand layout for mfma (k contiguous)
__global__ void precompute_kernel(const float* __restrict__ Wsrc1, const float* __restrict__ Wdst1,
                                  const float* __restrict__ asrc1, const float* __restrict__ adst1,
                                  const float* __restrict__ Wsrc2, const float* __restrict__ Wdst2,
                                  const float* __restrict__ asrc2, const float* __restrict__ adst2,
                                  const float* __restrict__ Wp, const float* __restrict__ bp,
                                  const float* __restrict__ Wlin, const float* __restrict__ blin,
                                  float* __restrict__ foldR, float* __restrict__ foldV,
                                  float* __restrict__ wp2, float* __restrict__ cterm,
                                  float* __restrict__ fw, __bf16* __restrict__ Wt) {
    int b = blockIdx.x;
    int t = threadIdx.x;  // 128
    if (b < 12) {
        int layer = b / 6, rel = (b % 6) / 2, side = b & 1;
        int K = (layer == 0) ? 16 : 128;
        const float* W = (layer == 0) ? (side ? Wdst1 : Wsrc1) : (side ? Wdst2 : Wsrc2);
        const float* a = (layer == 0) ? (side ? adst1 : asrc1) : (side ? adst2 : asrc2);
        W += (size_t)rel * K * 128;
        a += rel * 128;
        float* dst; int P; int colbase;
        if (rel == 0 && side == 0)      { dst = foldR; P = 8; colbase = 0; }
        else if (rel == 0)              { dst = foldR; P = 8; colbase = 2; }
        else if (rel == 1 && side == 0) { dst = foldV; P = 4; colbase = 0; }
        else if (rel == 1)              { dst = foldR; P = 8; colbase = 4; }
        else if (side == 0)             { dst = foldR; P = 8; colbase = 6; }
        else                            { dst = foldV; P = 4; colbase = 2; }
        dst += (size_t)layer * 128 * P;
        if (t < K) {
            for (int h = 0; h < 2; ++h) {
                float s = 0.f;
                for (int c = 0; c < 64; ++c) s += W[t * 128 + h * 64 + c] * a[h * 64 + c];
                dst[t * P + colbase + h] = s;
            }
        }
    } else if (b == 12) {
        if (t < 48) {
            int i = t / 16, k = (t / 2) % 8, o = t & 1;
            float s = 0.f;
            for (int c = 0; c < 64; ++c) s += Wp[(i * 8 + k) * 64 + c] * Wlin[(128 + c) * 2 + o];
            wp2[t] = s;
        } else if (t < 54) {
            int i = (t - 48) / 2, o = (t - 48) & 1;
            float s = blin[o];
            for (int c = 0; c < 64; ++c) s += bp[i * 64 + c] * Wlin[(128 + c) * 2 + o];
            cterm[i * 2 + o] = s;
        }
    } else if (b == 13) {
        for (int idx = t; idx < 512; idx += 128) {
            int k = idx >> 2, c = idx & 3;
            fw[idx] = Wlin[(k + ((c >= 2) ? 192 : 0)) * 2 + (c & 1)];
        }
    } else {
        // transpose+bf16: blocks 14.. cover 3*128*128 elements, 128/block
        int i = (b - 14) * 128 + t;
        if (i < 3 * 128 * 128) {
            int rel = i >> 14, rem = i & 16383, n = rem >> 7, k = rem & 127;
            Wt[i] = (__bf16)Wsrc2[(size_t)rel * 16384 + k * 128 + n];
        }
    }
}

// ================= CSR build (concatenated slot space) =================

__global__ void hist_all(const int* __restrict__ ei_rr, const int* __restrict__ ei_vr,
                         const int* __restrict__ ei_rv, int* __restrict__ cnt) {
    int j = blockIdx.x * blockDim.x + threadIdx.x;
    if (j < ERR_) atomicAdd(&cnt[ei_rr[ERR_ + j]], 1);
    else if (j < ERR_ + EVR_) atomicAdd(&cnt[NR_ + ei_vr[EVR_ + (j - ERR_)]], 1);
    else if (j < ETOT_) atomicAdd(&cnt[2 * NR_ + ei_rv[ERV_ + (j - ERR_ - EVR_)]], 1);
}

__global__ __launch_bounds__(256) void scan_reduce(const int* __restrict__ cnt, int* __restrict__ bsum) {
    __shared__ int buf[256];
    int t = threadIdx.x;
    int i0 = blockIdx.x * SCAN_ELEMS + t * 2;
    int s = 0;
    if (i0 + 1 < NTOT_) { int2 v = *(const int2*)&cnt[i0]; s = v.x + v.y; }
    else if (i0 < NTOT_) s = cnt[i0];
    buf[t] = s;
    __syncthreads();
    for (int off = 128; off; off >>= 1) {
        if (t < off) buf[t] += buf[t + off];
        __syncthreads();
    }
    if (t == 0) bsum[blockIdx.x] = buf[0];
}

__global__ __launch_bounds__(256) void scan_bsums(const int* __restrict__ bsum, int* __restrict__ boff,
                                                  int* __restrict__ row) {
    __shared__ int buf[256];
    int t = threadIdx.x;
    int s = (t < SCAN_NB) ? bsum[t] : 0;
    buf[t] = s;
    __syncthreads();
    for (int off = 1; off < 256; off <<= 1) {
        int v = (t >= off) ? buf[t - off] : 0;
        __syncthreads();
        buf[t] += v;
        __syncthreads();
    }
    if (t < SCAN_NB) boff[t] = buf[t] - s;
    if (t == 0) row[NTOT_] = ETOT_;
}

__global__ __launch_bounds__(256) void scan_write(const int* __restrict__ cnt, const int* __restrict__ boff,
                                                  int* __restrict__ row, int* __restrict__ cur) {
    __shared__ int buf[256];
    int t = threadIdx.x;
    int i0 = blockIdx.x * SCAN_ELEMS + t * 2;
    int vx = 0, vy = 0;
    if (i0 + 1 < NTOT_) { int2 v = *(const int2*)&cnt[i0]; vx = v.x; vy = v.y; }
    else if (i0 < NTOT_) vx = cnt[i0];
    int s = vx + vy;
    buf[t] = s;
    __syncthreads();
    for (int off = 1; off < 256; off <<= 1) {
        int v = (t >= off) ? buf[t - off] : 0;
        __syncthreads();
        buf[t] += v;
        __syncthreads();
    }
    int ex = buf[t] - s + boff[blockIdx.x];
    if (i0 + 1 < NTOT_) {
        *(int2*)&row[i0] = make_int2(ex, ex + vx);
        *(int2*)&cur[i0] = make_int2(ex, ex + vx);
    } else if (i0 < NTOT_) {
        row[i0] = ex;
        cur[i0] = ex;
    }
}

__global__ void scatter_all(const int* __restrict__ ei_rr, const int* __restrict__ ei_vr,
                            const int* __restrict__ ei_rv,
                            int* __restrict__ cur, int* __restrict__ cs) {
    int j = blockIdx.x * blockDim.x + threadIdx.x;
    int s, nidx;
    if (j < ERR_)             { s = ei_rr[j]; nidx = ei_rr[ERR_ + j]; }
    else if (j < ERR_ + EVR_) { int jj = j - ERR_; s = ei_vr[jj]; nidx = NR_ + ei_vr[EVR_ + jj]; }
    else if (j < ETOT_)       { int jj = j - ERR_ - EVR_; s = ei_rv[jj]; nidx = 2 * NR_ + ei_rv[ERV_ + jj]; }
    else return;
    int p = atomicAdd(&cur[nidx], 1);
    cs[p] = s;
}

// ===== layer-1 projection GEMM (K=16), 32-row tiles, fused scores (f32) =====

template <int K, int P>
__global__ __launch_bounds__(256) void gemm32(const float* __restrict__ x,
                                              const float* __restrict__ W,
                                              const float* __restrict__ fold,
                                              float* __restrict__ hs,
                                              float* __restrict__ sc, int N) {
    constexpr int KC = (K < 32) ? K : 32;
    __shared__ float xs[32][KC + 4];
    __shared__ float ws[KC][128];
    __shared__ float fs[(P > 0) ? KC * P : 1];
    int t = threadIdx.x;
    int cg4 = (t & 31) * 4;
    int rg4 = (t >> 5) * 4;
    int row0 = blockIdx.x * 32;
    float acc[4][4] = {{0.f}};
    float sacc = 0.f;
    int srow = (P > 0) ? (t / P) : 0;
    int scol = (P > 0) ? (t % P) : 0;

    for (int k0 = 0; k0 < K; k0 += KC) {
        constexpr int KV = KC / 4;
        for (int v = t; v < 32 * KV; v += 256) {
            int r = v / KV, kk = (v % KV) * 4;
            int rr = row0 + r;
            float4 val = make_float4(0.f, 0.f, 0.f, 0.f);
            if (rr < N) val = *(const float4*)&x[(size_t)rr * K + k0 + kk];
            *(float4*)&xs[r][kk] = val;
        }
        constexpr int WV = KC * 128 / 4;
        const float4* Wv = (const float4*)&W[(size_t)k0 * 128];
        for (int v = t; v < WV; v += 256) ((float4*)&ws[0][0])[v] = Wv[v];
        if (P > 0)
            for (int v = t; v < KC * P; v += 256) fs[v] = fold[k0 * P + v];
        __syncthreads();

#pragma unroll
        for (int k = 0; k < KC; k += 4) {
            float4 xv[4];
#pragma unroll
            for (int i = 0; i < 4; ++i) xv[i] = *(const float4*)&xs[rg4 + i][k];
            float4 w0 = *(const float4*)&ws[k + 0][cg4];
            float4 w1 = *(const float4*)&ws[k + 1][cg4];
            float4 w2 = *(const float4*)&ws[k + 2][cg4];
            float4 w3 = *(const float4*)&ws[k + 3][cg4];
#pragma unroll
            for (int i = 0; i < 4; ++i) {
                acc[i][0] += xv[i].x * w0.x + xv[i].y * w1.x + xv[i].z * w2.x + xv[i].w * w3.x;
                acc[i][1] += xv[i].x * w0.y + xv[i].y * w1.y + xv[i].z * w2.y + xv[i].w * w3.y;
                acc[i][2] += xv[i].x * w0.z + xv[i].y * w1.z + xv[i].z * w2.z + xv[i].w * w3.z;
                acc[i][3] += xv[i].x * w0.w + xv[i].y * w1.w + xv[i].z * w2.w + xv[i].w * w3.w;
            }
        }
        if (P > 0 && t < 32 * P) {
            float s = 0.f;
            for (int k = 0; k < KC; ++k) s += xs[srow][k] * fs[k * P + scol];
            sacc += s;
        }
        __syncthreads();
    }
#pragma unroll
    for (int i = 0; i < 4; ++i) {
        int rr = row0 + rg4 + i;
        if (rr < N)
            *(float4*)&hs[(size_t)rr * 128 + cg4] =
                make_float4(acc[i][0], acc[i][1], acc[i][2], acc[i][3]);
    }
    if (P > 0 && t < 32 * P && row0 + srow < N)
        sc[(size_t)(row0 + srow) * P + scol] = sacc;
}

// ===== layer-2 projection: bf16 MFMA, no LDS =====
// A[m=lane&15][k=quad*8+j] from x_bf row-major; B[k=quad*8+j][n=lane&15] from Wt[n][k];
// D: col=lane&15, row=quad*4+reg (m89/m91-verified layout). Wave = 16 rows x 128 cols.

__global__ __launch_bounds__(256) void gemm_mfma(const __bf16* __restrict__ x,
                                                 const __bf16* __restrict__ Wt,
                                                 float* __restrict__ hs, int N) {
    int wave = threadIdx.x >> 6;
    int lane = threadIdx.x & 63;
    int m = lane & 15;
    int quad = lane >> 4;
    int row0 = blockIdx.x * 64 + wave * 16;
    int arow = row0 + m;
    int rs = (arow < N) ? arow : (N - 1);
    const __bf16* xp = x + (size_t)rs * 128 + quad * 8;
    bfrag A0 = *(const bfrag*)(xp);
    bfrag A1 = *(const bfrag*)(xp + 32);
    bfrag A2 = *(const bfrag*)(xp + 64);
    bfrag A3 = *(const bfrag*)(xp + 96);
#pragma unroll
    for (int nt = 0; nt < 8; ++nt) {
        const __bf16* wp = Wt + (size_t)(nt * 16 + m) * 128 + quad * 8;
        ffrag acc = {0.f, 0.f, 0.f, 0.f};
        acc = __builtin_amdgcn_mfma_f32_16x16x32_bf16(A0, *(const bfrag*)(wp), acc, 0, 0, 0);
        acc = __builtin_amdgcn_mfma_f32_16x16x32_bf16(A1, *(const bfrag*)(wp + 32), acc, 0, 0, 0);
        acc = __builtin_amdgcn_mfma_f32_16x16x32_bf16(A2, *(const bfrag*)(wp + 64), acc, 0, 0, 0);
        acc = __builtin_amdgcn_mfma_f32_16x16x32_bf16(A3, *(const bfrag*)(wp + 96), acc, 0, 0, 0);
        int dcol = nt * 16 + m;
#pragma unroll
        for (int r = 0; r < 4; ++r) {
            int drow = row0 + quad * 4 + r;
            if (drow < N) hs[(size_t)drow * 128 + dcol] = acc[r];
        }
    }
}

// ===== layer-2 attention scores (f32): scR[n][8] = xr@fR, scV[n][4] = xv@fV =====

__global__ __launch_bounds__(256) void scores_l2_all(const float* __restrict__ xr,
                                                     const float* __restrict__ xv,
                                                     const float* __restrict__ fR,
                                                     const float* __restrict__ fV,
                                                     float* __restrict__ scR, float* __restrict__ scV) {
    __shared__ float sf[1024];
    int b = blockIdx.x;
    const float* x; const float* fold; float* sc; int N, P, n0;
    if (b < SCB_R) { x = xr; fold = fR; sc = scR; N = NR_; P = 8; n0 = b * 256; }
    else           { x = xv; fold = fV; sc = scV; N = NV_; P = 4; n0 = (b - SCB_R) * 256; }
    for (int i = threadIdx.x; i < 128 * P; i += 256) sf[i] = fold[i];
    __syncthreads();
    int n = n0 + threadIdx.x;
    if (n >= N) return;
    float a[8] = {0.f, 0.f, 0.f, 0.f, 0.f, 0.f, 0.f, 0.f};
    const float* xp = x + (size_t)n * 128;
    for (int k = 0; k < 128; k += 4) {
        float4 xv4 = *(const float4*)&xp[k];
        for (int p = 0; p < P; ++p)
            a[p] += xv4.x * sf[k * P + p] + xv4.y * sf[(k + 1) * P + p] +
                    xv4.z * sf[(k + 2) * P + p] + xv4.w * sf[(k + 3) * P + p];
    }
    float* o = sc + (size_t)n * P;
    for (int p = 0; p < P; ++p) o[p] = a[p];
}

// ===== final head per-node scores (both node types, P=4, fold=fw) =====

__global__ __launch_bounds__(256) void final_scores_all(const float* __restrict__ xr,
                                                        const float* __restrict__ xv,
                                                        const float* __restrict__ fw,
                                                        float* __restrict__ ssR, float* __restrict__ ssV) {
    __shared__ float sf[512];
    int b = blockIdx.x;
    const float* x; float* sc; int N, n0;
    if (b < SCB_R) { x = xr; sc = ssR; N = NR_; n0 = b * 256; }
    else           { x = xv; sc = ssV; N = NV_; n0 = (b - SCB_R) * 256; }
    for (int i = threadIdx.x; i < 512; i += 256) sf[i] = fw[i];
    __syncthreads();
    int n = n0 + threadIdx.x;
    if (n >= N) return;
    float a0 = 0.f, a1 = 0.f, a2 = 0.f, a3 = 0.f;
    const float* xp = x + (size_t)n * 128;
    for (int k = 0; k < 128; k += 4) {
        float4 xv4 = *(const float4*)&xp[k];
        a0 += xv4.x * sf[k * 4 + 0] + xv4.y * sf[(k + 1) * 4 + 0] + xv4.z * sf[(k + 2) * 4 + 0] + xv4.w * sf[(k + 3) * 4 + 0];
        a1 += xv4.x * sf[k * 4 + 1] + xv4.y * sf[(k + 1) * 4 + 1] + xv4.z * sf[(k + 2) * 4 + 1] + xv4.w * sf[(k + 3) * 4 + 1];
        a2 += xv4.x * sf[k * 4 + 2] + xv4.y * sf[(k + 1) * 4 + 2] + xv4.z * sf[(k + 2) * 4 + 2] + xv4.w * sf[(k + 3) * 4 + 2];
        a3 += xv4.x * sf[k * 4 + 3] + xv4.y * sf[(k + 1) * 4 + 3] + xv4.z * sf[(k + 2) * 4 + 3] + xv4.w * sf[(k + 3) * 4 + 3];
    }
    *(float4*)&sc[(size_t)n * 4] = make_float4(a0, a1, a2, a3);
}

// ================= gather-aggregate with fused edge softmax =================

__device__ __forceinline__ void agg_rel_f2(int node, int lane,
                                           const int* __restrict__ row, const int* __restrict__ cs,
                                           const float* __restrict__ hs,
                                           const float* __restrict__ Ss, int sst, int sc, float edv,
                                           float& ox, float& oy) {
    int r0 = row[node], r1 = row[node + 1];
    if (r1 <= r0) return;
    float ax = 0.f, ay = 0.f, den = 0.f;
    int j = r0;
    for (; j + 4 <= r1; j += 4) {
        int s0 = cs[j + 0], s1 = cs[j + 1], s2 = cs[j + 2], s3 = cs[j + 3];
        float p0 = Ss[s0 * sst + sc];
        float p1 = Ss[s1 * sst + sc];
        float p2 = Ss[s2 * sst + sc];
        float p3 = Ss[s3 * sst + sc];
        float2 v0 = *(const float2*)&hs[(size_t)s0 * 128 + lane * 2];
        float2 v1 = *(const float2*)&hs[(size_t)s1 * 128 + lane * 2];
        float2 v2 = *(const float2*)&hs[(size_t)s2 * 128 + lane * 2];
        float2 v3 = *(const float2*)&hs[(size_t)s3 * 128 + lane * 2];
        float e0 = p0 + edv; e0 = (e0 >= 0.f) ? e0 : NEG_ * e0;
        float e1 = p1 + edv; e1 = (e1 >= 0.f) ? e1 : NEG_ * e1;
        float e2 = p2 + edv; e2 = (e2 >= 0.f) ? e2 : NEG_ * e2;
        float e3 = p3 + edv; e3 = (e3 >= 0.f) ? e3 : NEG_ * e3;
        float w0 = __expf(e0), w1 = __expf(e1), w2 = __expf(e2), w3 = __expf(e3);
        ax += v0.x * w0 + v1.x * w1 + v2.x * w2 + v3.x * w3;
        ay += v0.y * w0 + v1.y * w1 + v2.y * w2 + v3.y * w3;
        den += w0 + w1 + w2 + w3;
    }
    for (; j < r1; ++j) {
        int s = cs[j];
        float p = Ss[s * sst + sc];
        float2 v = *(const float2*)&hs[(size_t)s * 128 + lane * 2];
        float e = p + edv; e = (e >= 0.f) ? e : NEG_ * e;
        float w = __expf(e);
        ax += v.x * w;
        ay += v.y * w;
        den += w;
    }
    float inv = 1.f / den;
    ox += ax * inv;
    oy += ay * inv;
}

__global__ __launch_bounds__(256) void agg_req(
        const int* __restrict__ row, const int* __restrict__ cs,
        const float* __restrict__ hs_rr, const float* __restrict__ hs_vr,
        const float* __restrict__ scR, const float* __restrict__ scV,
        float* __restrict__ o, int N) {
    int node = blockIdx.x * 4 + (threadIdx.x >> 6);
    if (node >= N) return;
    int lane = threadIdx.x & 63;
    int hoff = lane >> 5;
    float ed_rr = scR[node * 8 + 2 + hoff];
    float ed_vr = scR[node * 8 + 4 + hoff];
    float ox = 0.f, oy = 0.f;
    agg_rel_f2(node, lane, row, cs, hs_rr, scR, 8, 0 + hoff, ed_rr, ox, oy);
    agg_rel_f2(node, lane, row + NR_, cs, hs_vr, scV, 4, 0 + hoff, ed_vr, ox, oy);
    *(float2*)&o[(size_t)node * 128 + lane * 2] = make_float2(ox * 0.5f, oy * 0.5f);
}

__global__ __launch_bounds__(256) void agg_veh(
        const int* __restrict__ row, const int* __restrict__ cs,
        const float* __restrict__ hs,
        const float* __restrict__ scR, const float* __restrict__ scV,
        float* __restrict__ o, int N) {
    int node = blockIdx.x * 4 + (threadIdx.x >> 6);
    if (node >= N) return;
    int lane = threadIdx.x & 63;
    int hoff = lane >> 5;
    float ed_rv = scV[node * 4 + 2 + hoff];
    float ox = 0.f, oy = 0.f;
    agg_rel_f2(node, lane, row + 2 * NR_, cs, hs, scR, 8, 6 + hoff, ed_rv, ox, oy);
    *(float2*)&o[(size_t)node * 128 + lane * 2] = make_float2(ox, oy);
}

// ================= BatchNorm (training stats) + leaky-relu =================

__global__ __launch_bounds__(256) void bn_stats_all(const float* __restrict__ o_r,
                                                    const float* __restrict__ o_v,
                                                    float* __restrict__ s4) {
    int b = blockIdx.x;
    const float* o; int N; int r0; int soff;
    if (b < BN_BLKS_R) { o = o_r; N = NR_; r0 = b * 64; soff = 0; }
    else               { o = o_v; N = NV_; r0 = (b - BN_BLKS_R) * 64; soff = 128; }
    int wave = threadIdx.x >> 6, lane = threadIdx.x & 63;
    int rend = r0 + 64; if (rend > N) rend = N;
    float sx = 0.f, sy = 0.f, qx = 0.f, qy = 0.f;
    for (int r = r0 + wave; r < rend; r += 4) {
        float2 v = *(const float2*)&o[(size_t)r * 128 + lane * 2];
        sx += v.x; sy += v.y;
        qx += v.x * v.x; qy += v.y * v.y;
    }
    __shared__ float bs[4][128];
    __shared__ float bq[4][128];
    bs[wave][lane * 2] = sx;  bs[wave][lane * 2 + 1] = sy;
    bq[wave][lane * 2] = qx;  bq[wave][lane * 2 + 1] = qy;
    __syncthreads();
    if (threadIdx.x < 128) {
        int c = threadIdx.x;
        float s = bs[0][c] + bs[1][c] + bs[2][c] + bs[3][c];
        float q = bq[0][c] + bq[1][c] + bq[2][c] + bq[3][c];
        atomicAdd(&s4[soff + c], s);
        atomicAdd(&s4[256 + soff + c], q);
    }
}

// writes f32 x (for scores) AND bf16 copy (for MFMA projections)
__global__ void bn_norm_all(const float* __restrict__ o_r, const float* __restrict__ o_v,
                            const float* __restrict__ s4,
                            const float* __restrict__ gammaL, const float* __restrict__ betaL,
                            float* __restrict__ xr, float* __restrict__ xv,
                            __bf16* __restrict__ xrb, __bf16* __restrict__ xvb) {
    size_t idx = blockIdx.x * (size_t)256 + threadIdx.x;
    const size_t nr = (size_t)NR_ * 128;
    const float* o; float* x; __bf16* xb; int soff; float invN; size_t i;
    if (idx < nr) { o = o_r; x = xr; xb = xrb; soff = 0;   invN = 1.f / NR_; i = idx; }
    else          { o = o_v; x = xv; xb = xvb; soff = 128; invN = 1.f / NV_; i = idx - nr; }
    int c = (int)(i & 127);
    float mu = s4[soff + c] * invN;
    float var = s4[256 + soff + c] * invN - mu * mu;
    float v = (o[i] - mu) * rsqrtf(var + EPS_) * gammaL[soff + c] + betaL[soff + c];
    v = (v >= 0.f) ? v : NEG_ * v;
    x[i] = v;
    xb[i] = (__bf16)v;
}

// ================= final head =================

__global__ void final_edge_all(const int* __restrict__ ei_rr, const int* __restrict__ ei_vr,
                               const int* __restrict__ ei_rv,
                               const float* __restrict__ ea_rr, const float* __restrict__ ea_vr,
                               const float* __restrict__ ea_rv,
                               const float* __restrict__ ssR, const float* __restrict__ ssV,
                               const float* __restrict__ wp2, const float* __restrict__ cterm,
                               float* __restrict__ out) {
    int j = blockIdx.x * blockDim.x + threadIdx.x;
    if (j >= ETOT_) return;
    int rel, jj;
    const int* src; const int* dst; const float* ea; const float* ss; const float* sd; float* o;
    if (j < ERR_) {
        rel = 0; jj = j; src = ei_rr; dst = ei_rr + ERR_; ea = ea_rr; ss = ssR; sd = ssR; o = out;
    } else if (j < ERR_ + EVR_) {
        rel = 1; jj = j - ERR_; src = ei_vr; dst = ei_vr + EVR_; ea = ea_vr; ss = ssV; sd = ssR;
        o = out + (size_t)ERR_ * 2;
    } else {
        rel = 2; jj = j - ERR_ - EVR_; src = ei_rv; dst = ei_rv + ERV_; ea = ea_rv; ss = ssR; sd = ssV;
        o = out + (size_t)(ERR_ + EVR_) * 2;
    }
    int s = src[jj], d = dst[jj];
    float l0 = ss[s * 4 + 0] + sd[d * 4 + 2] + cterm[rel * 2 + 0];
    float l1 = ss[s * 4 + 1] + sd[d * 4 + 3] + cterm[rel * 2 + 1];
    const float* w = wp2 + rel * 16;
#pragma unroll
    for (int k = 0; k < 8; ++k) {
        float v = ea[(size_t)jj * 8 + k];
        l0 += v * w[k * 2 + 0];
        l1 += v * w[k * 2 + 1];
    }
    float m = fmaxf(l0, l1);
    float p0 = __expf(l0 - m), p1 = __expf(l1 - m);
    float inv = 1.f / (p0 + p1);
    o[(size_t)jj * 2 + 0] = p0 * inv;
    o[(size_t)jj * 2 + 1] = p1 * inv;
}

// ================= host orchestration =================

extern "C" void kernel_launch(void* const* d_in, const int* in_sizes, int n_in,
                              void* d_out, int out_size, void* d_ws, size_t ws_size,
                              hipStream_t stream) {
    const float* x_req = (const float*)d_in[0];
    const float* x_veh = (const float*)d_in[1];
    const int* ei_rr = (const int*)d_in[2];
    const int* ei_vr = (const int*)d_in[3];
    const int* ei_rv = (const int*)d_in[4];
    const float* ea_rr = (const float*)d_in[5];
    const float* ea_vr = (const float*)d_in[6];
    const float* ea_rv = (const float*)d_in[7];
    const float* Wsrc1 = (const float*)d_in[8];
    const float* Wdst1 = (const float*)d_in[9];
    const float* asrc1 = (const float*)d_in[10];
    const float* adst1 = (const float*)d_in[11];
    const float* Wsrc2 = (const float*)d_in[13];
    const float* Wdst2 = (const float*)d_in[14];
    const float* asrc2 = (const float*)d_in[15];
    const float* adst2 = (const float*)d_in[16];
    const float* bn_gamma = (const float*)d_in[18];
    const float* bn_beta  = (const float*)d_in[19];
    const float* Wp   = (const float*)d_in[20];
    const float* bp   = (const float*)d_in[21];
    const float* Wlin = (const float*)d_in[22];
    const float* blin = (const float*)d_in[23];
    float* out = (float*)d_out;

    float* w = (float*)d_ws;
    size_t off = 0;
    float* xr    = w + off; off += (size_t)NR_ * 128;
    float* xv    = w + off; off += (size_t)NV_ * 128;
    float* hs_a  = w + off; off += (size_t)NR_ * 128;
    float* hs_b  = w + off; off += (size_t)NV_ * 128;
    float* hs_c  = w + off; off += (size_t)NR_ * 128;
    float* o_r   = w + off; off += (size_t)NR_ * 128;
    float* o_v   = w + off; off += (size_t)NV_ * 128;
    float* scR   = w + off; off += (size_t)NR_ * 8;
    float* scV   = w + off; off += (size_t)NV_ * 4;
    float* s4    = w + off; off += 512;
    float* foldR = w + off; off += 2 * 128 * 8;
    float* foldV = w + off; off += 2 * 128 * 4;
    float* wp2   = w + off; off += 48;
    float* cterm = w + off; off += 8;
    float* fw    = w + off; off += 512;
    float* ssR   = w + off; off += (size_t)NR_ * 4;
    float* ssV   = w + off; off += (size_t)NV_ * 4;
    // bf16 region (16B-aligned: all prior sizes are multiples of 4 floats)
    __bf16* xrb = (__bf16*)(w + off); off += (size_t)NR_ * 128 / 2;
    __bf16* xvb = (__bf16*)(w + off); off += (size_t)NV_ * 128 / 2;
    __bf16* Wt  = (__bf16*)(w + off); off += 3 * 128 * 128 / 2;
    int* iw = (int*)(w + off);
    size_t ioff = 0;
    int* row  = iw + ioff; ioff += NTOT_ + 1;
    int* cur  = iw + ioff; ioff += NTOT_;
    int* bsum = iw + ioff; ioff += SCAN_NB;
    int* boff = iw + ioff; ioff += SCAN_NB;
    int* cs   = iw + ioff; ioff += ETOT_;

    // precompute folds + bf16-transposed layer-2 weights (blocks 14.. : 3*16384/128 = 384)
    precompute_kernel<<<14 + 384, 128, 0, stream>>>(Wsrc1, Wdst1, asrc1, adst1,
                                                    Wsrc2, Wdst2, asrc2, adst2,
                                                    Wp, bp, Wlin, blin,
                                                    foldR, foldV, wp2, cterm, fw, Wt);

    hipMemsetAsync(cur, 0, NTOT_ * sizeof(int), stream);
    hist_all<<<(ETOT_ + 255) / 256, 256, 0, stream>>>(ei_rr, ei_vr, ei_rv, cur);
    scan_reduce<<<SCAN_NB, 256, 0, stream>>>(cur, bsum);
    scan_bsums<<<1, 256, 0, stream>>>(bsum, boff, row);
    scan_write<<<SCAN_NB, 256, 0, stream>>>(cur, boff, row, cur);
    scatter_all<<<(ETOT_ + 255) / 256, 256, 0, stream>>>(ei_rr, ei_vr, ei_rv, cur, cs);

    for (int l = 0; l < 2; ++l) {
        const float* fR = foldR + (size_t)l * 128 * 8;
        const float* fV = foldV + (size_t)l * 128 * 4;

        if (l == 0) {
            gemm32<16, 8><<<(NR_ + 31) / 32, 256, 0, stream>>>(x_req, Wsrc1 + 0 * 16 * 128, fR, hs_a, scR, NR_);
            gemm32<16, 0><<<(NR_ + 31) / 32, 256, 0, stream>>>(x_req, Wsrc1 + 2 * 16 * 128, nullptr, hs_c, nullptr, NR_);
            gemm32<16, 4><<<(NV_ + 31) / 32, 256, 0, stream>>>(x_veh, Wsrc1 + 1 * 16 * 128, fV, hs_b, scV, NV_);
        } else {
            gemm_mfma<<<(NR_ + 63) / 64, 256, 0, stream>>>(xrb, Wt + 0 * 16384, hs_a, NR_);
            gemm_mfma<<<(NR_ + 63) / 64, 256, 0, stream>>>(xrb, Wt + 2 * 16384, hs_c, NR_);
            gemm_mfma<<<(NV_ + 63) / 64, 256, 0, stream>>>(xvb, Wt + 1 * 16384, hs_b, NV_);
            scores_l2_all<<<SCB_R + SCB_V, 256, 0, stream>>>(xr, xv, fR, fV, scR, scV);
        }
        agg_req<<<(NR_ + 3) / 4, 256, 0, stream>>>(row, cs, hs_a, hs_b, scR, scV, o_r, NR_);
        agg_veh<<<(NV_ + 3) / 4, 256, 0, stream>>>(row, cs, hs_c, scR, scV, o_v, NV_);

        hipMemsetAsync(s4, 0, 512 * sizeof(float), stream);
        bn_stats_all<<<BN_BLKS_R + BN_BLKS_V, 256, 0, stream>>>(o_r, o_v, s4);
        bn_norm_all<<<(int)(((size_t)(NR_ + NV_) * 128 + 255) / 256), 256, 0, stream>>>(
            o_r, o_v, s4, bn_gamma + l * 256, bn_beta + l * 256, xr, xv, xrb, xvb);
    }

    final_scores_all<<<SCB_R + SCB_V, 256, 0, stream>>>(xr, xv, fw, ssR, ssV);
    final_edge_all<<<(ETOT_ + 255) / 256, 256, 0, stream>>>(ei_rr, ei_vr, ei_rv, ea_rr, ea_vr, ea_rv,
                                                            ssR, ssV, wp2, cterm, out);
}

// Round 10
// 453.780 us; speedup vs baseline: 4.0421x; 1.1064x over previous
//
#include <hip/hip_runtime.h>
#include <hip/hip_bf16.h>

#define NR_ 40000
#define NV_ 4000
#define ERR_ 400000
#define EVR_ 150000
#define ERV_ 150000
#define ETOT_ (ERR_ + EVR_ + ERV_)
#define NTOT_ (NR_ + NR_ + NV_)
#define SCAN_ELEMS 512
#define SCAN_NB ((NTOT_ + SCAN_ELEMS - 1) / SCAN_ELEMS)
#define BN_BLKS_R ((NR_ + 63) / 64)
#define BN_BLKS_V ((NV_ + 63) / 64)
#define SCB_R ((NR_ + 255) / 256)   // 157
#define SCB_V ((NV_ + 255) / 256)   // 16
#define L1B_R ((NR_ + 31) / 32)     // 1250
#define L1B_V ((NV_ + 31) / 32)     // 125
#define MFB_R ((NR_ + 63) / 64)     // 625
#define MFB_V ((NV_ + 63) / 64)     // 63
#define AGB_R ((NR_ + 3) / 4)       // 10000
#define AGB_V ((NV_ + 3) / 4)       // 1000
#define NEG_ 0.2f
#define EPS_ 1e-5f

typedef __attribute__((ext_vector_type(8))) __bf16 bfrag;
typedef __attribute__((ext_vector_type(4))) float ffrag;
typedef __attribute__((ext_vector_type(4))) __bf16 bf4;
typedef __attribute__((ext_vector_type(2))) __bf16 bf2;

// ================= precompute: folds + bf16-transposed layer-2 weights =================

__global__ void precompute_kernel(const float* __restrict__ Wsrc1, const float* __restrict__ Wdst1,
                                  const float* __restrict__ asrc1, const float* __restrict__ adst1,
                                  const float* __restrict__ Wsrc2, const float* __restrict__ Wdst2,
                                  const float* __restrict__ asrc2, const float* __restrict__ adst2,
                                  const float* __restrict__ Wp, const float* __restrict__ bp,
                                  const float* __restrict__ Wlin, const float* __restrict__ blin,
                                  float* __restrict__ foldR, float* __restrict__ foldV,
                                  float* __restrict__ wp2, float* __restrict__ cterm,
                                  float* __restrict__ fw, __bf16* __restrict__ Wt) {
    int b = blockIdx.x;
    int t = threadIdx.x;  // 128
    if (b < 12) {
        int layer = b / 6, rel = (b % 6) / 2, side = b & 1;
        int K = (layer == 0) ? 16 : 128;
        const float* W = (layer == 0) ? (side ? Wdst1 : Wsrc1) : (side ? Wdst2 : Wsrc2);
        const float* a = (layer == 0) ? (side ? adst1 : asrc1) : (side ? adst2 : asrc2);
        W += (size_t)rel * K * 128;
        a += rel * 128;
        float* dst; int P; int colbase;
        if (rel == 0 && side == 0)      { dst = foldR; P = 8; colbase = 0; }
        else if (rel == 0)              { dst = foldR; P = 8; colbase = 2; }
        else if (rel == 1 && side == 0) { dst = foldV; P = 4; colbase = 0; }
        else if (rel == 1)              { dst = foldR; P = 8; colbase = 4; }
        else if (side == 0)             { dst = foldR; P = 8; colbase = 6; }
        else                            { dst = foldV; P = 4; colbase = 2; }
        dst += (size_t)layer * 128 * P;
        if (t < K) {
            for (int h = 0; h < 2; ++h) {
                float s = 0.f;
                for (int c = 0; c < 64; ++c) s += W[t * 128 + h * 64 + c] * a[h * 64 + c];
                dst[t * P + colbase + h] = s;
            }
        }
    } else if (b == 12) {
        if (t < 48) {
            int i = t / 16, k = (t / 2) % 8, o = t & 1;
            float s = 0.f;
            for (int c = 0; c < 64; ++c) s += Wp[(i * 8 + k) * 64 + c] * Wlin[(128 + c) * 2 + o];
            wp2[t] = s;
        } else if (t < 54) {
            int i = (t - 48) / 2, o = (t - 48) & 1;
            float s = blin[o];
            for (int c = 0; c < 64; ++c) s += bp[i * 64 + c] * Wlin[(128 + c) * 2 + o];
            cterm[i * 2 + o] = s;
        }
    } else if (b == 13) {
        for (int idx = t; idx < 512; idx += 128) {
            int k = idx >> 2, c = idx & 3;
            fw[idx] = Wlin[(k + ((c >= 2) ? 192 : 0)) * 2 + (c & 1)];
        }
    } else {
        int i = (b - 14) * 128 + t;
        if (i < 3 * 128 * 128) {
            int rel = i >> 14, rem = i & 16383, n = rem >> 7, k = rem & 127;
            Wt[i] = (__bf16)Wsrc2[(size_t)rel * 16384 + k * 128 + n];
        }
    }
}

// ================= CSR build (concatenated slot space) =================

__global__ void hist_all(const int* __restrict__ ei_rr, const int* __restrict__ ei_vr,
                         const int* __restrict__ ei_rv, int* __restrict__ cnt) {
    int j = blockIdx.x * blockDim.x + threadIdx.x;
    if (j < ERR_) atomicAdd(&cnt[ei_rr[ERR_ + j]], 1);
    else if (j < ERR_ + EVR_) atomicAdd(&cnt[NR_ + ei_vr[EVR_ + (j - ERR_)]], 1);
    else if (j < ETOT_) atomicAdd(&cnt[2 * NR_ + ei_rv[ERV_ + (j - ERR_ - EVR_)]], 1);
}

__global__ __launch_bounds__(256) void scan_reduce(const int* __restrict__ cnt, int* __restrict__ bsum) {
    __shared__ int buf[256];
    int t = threadIdx.x;
    int i0 = blockIdx.x * SCAN_ELEMS + t * 2;
    int s = 0;
    if (i0 + 1 < NTOT_) { int2 v = *(const int2*)&cnt[i0]; s = v.x + v.y; }
    else if (i0 < NTOT_) s = cnt[i0];
    buf[t] = s;
    __syncthreads();
    for (int off = 128; off; off >>= 1) {
        if (t < off) buf[t] += buf[t + off];
        __syncthreads();
    }
    if (t == 0) bsum[blockIdx.x] = buf[0];
}

__global__ __launch_bounds__(256) void scan_bsums(const int* __restrict__ bsum, int* __restrict__ boff,
                                                  int* __restrict__ row) {
    __shared__ int buf[256];
    int t = threadIdx.x;
    int s = (t < SCAN_NB) ? bsum[t] : 0;
    buf[t] = s;
    __syncthreads();
    for (int off = 1; off < 256; off <<= 1) {
        int v = (t >= off) ? buf[t - off] : 0;
        __syncthreads();
        buf[t] += v;
        __syncthreads();
    }
    if (t < SCAN_NB) boff[t] = buf[t] - s;
    if (t == 0) row[NTOT_] = ETOT_;
}

__global__ __launch_bounds__(256) void scan_write(const int* __restrict__ cnt, const int* __restrict__ boff,
                                                  int* __restrict__ row, int* __restrict__ cur) {
    __shared__ int buf[256];
    int t = threadIdx.x;
    int i0 = blockIdx.x * SCAN_ELEMS + t * 2;
    int vx = 0, vy = 0;
    if (i0 + 1 < NTOT_) { int2 v = *(const int2*)&cnt[i0]; vx = v.x; vy = v.y; }
    else if (i0 < NTOT_) vx = cnt[i0];
    int s = vx + vy;
    buf[t] = s;
    __syncthreads();
    for (int off = 1; off < 256; off <<= 1) {
        int v = (t >= off) ? buf[t - off] : 0;
        __syncthreads();
        buf[t] += v;
        __syncthreads();
    }
    int ex = buf[t] - s + boff[blockIdx.x];
    if (i0 + 1 < NTOT_) {
        *(int2*)&row[i0] = make_int2(ex, ex + vx);
        *(int2*)&cur[i0] = make_int2(ex, ex + vx);
    } else if (i0 < NTOT_) {
        row[i0] = ex;
        cur[i0] = ex;
    }
}

__global__ void scatter_all(const int* __restrict__ ei_rr, const int* __restrict__ ei_vr,
                            const int* __restrict__ ei_rv,
                            int* __restrict__ cur, int* __restrict__ cs) {
    int j = blockIdx.x * blockDim.x + threadIdx.x;
    int s, nidx;
    if (j < ERR_)             { s = ei_rr[j]; nidx = ei_rr[ERR_ + j]; }
    else if (j < ERR_ + EVR_) { int jj = j - ERR_; s = ei_vr[jj]; nidx = NR_ + ei_vr[EVR_ + jj]; }
    else if (j < ETOT_)       { int jj = j - ERR_ - EVR_; s = ei_rv[jj]; nidx = 2 * NR_ + ei_rv[ERV_ + jj]; }
    else return;
    int p = atomicAdd(&cur[nidx], 1);
    cs[p] = s;
}

// ===== layer-1: all 3 projections (K=16) + fused scores, one launch, bf16 hs out =====

__global__ __launch_bounds__(256) void gemm_l1_all(const float* __restrict__ x_req,
                                                   const float* __restrict__ x_veh,
                                                   const float* __restrict__ W /*Wsrc1[3][16][128]*/,
                                                   const float* __restrict__ fR, const float* __restrict__ fV,
                                                   __bf16* __restrict__ hs_a, __bf16* __restrict__ hs_b,
                                                   __bf16* __restrict__ hs_c,
                                                   float* __restrict__ scR, float* __restrict__ scV) {
    __shared__ float xs[32][20];
    __shared__ float ws[16][128];
    __shared__ float fs[128];
    int b = blockIdx.x;
    int t = threadIdx.x;
    const float* x; const float* Wr; const float* fold; __bf16* hs; float* sc; int N, P, row0;
    if (b < L1B_R)          { x = x_req; Wr = W + 0 * 2048; fold = fR; hs = hs_a; sc = scR; N = NR_; P = 8; row0 = b * 32; }
    else if (b < 2 * L1B_R) { x = x_req; Wr = W + 2 * 2048; fold = nullptr; hs = hs_c; sc = nullptr; N = NR_; P = 0; row0 = (b - L1B_R) * 32; }
    else                    { x = x_veh; Wr = W + 1 * 2048; fold = fV; hs = hs_b; sc = scV; N = NV_; P = 4; row0 = (b - 2 * L1B_R) * 32; }

    // stage x (32x16), W (16x128), fold (16xP)
    for (int v = t; v < 32 * 4; v += 256) {
        int r = v >> 2, kk = (v & 3) * 4;
        int rr = row0 + r;
        float4 val = make_float4(0.f, 0.f, 0.f, 0.f);
        if (rr < N) val = *(const float4*)&x[(size_t)rr * 16 + kk];
        *(float4*)&xs[r][kk] = val;
    }
    for (int v = t; v < 512; v += 256) ((float4*)&ws[0][0])[v] = ((const float4*)Wr)[v];
    if (P > 0)
        for (int v = t; v < 16 * P; v += 256) fs[v] = fold[v];
    __syncthreads();

    int cg4 = (t & 31) * 4;
    int rg4 = (t >> 5) * 4;
    float acc[4][4] = {{0.f}};
#pragma unroll
    for (int k = 0; k < 16; k += 4) {
        float4 xv[4];
#pragma unroll
        for (int i = 0; i < 4; ++i) xv[i] = *(const float4*)&xs[rg4 + i][k];
        float4 w0 = *(const float4*)&ws[k + 0][cg4];
        float4 w1 = *(const float4*)&ws[k + 1][cg4];
        float4 w2 = *(const float4*)&ws[k + 2][cg4];
        float4 w3 = *(const float4*)&ws[k + 3][cg4];
#pragma unroll
        for (int i = 0; i < 4; ++i) {
            acc[i][0] += xv[i].x * w0.x + xv[i].y * w1.x + xv[i].z * w2.x + xv[i].w * w3.x;
            acc[i][1] += xv[i].x * w0.y + xv[i].y * w1.y + xv[i].z * w2.y + xv[i].w * w3.y;
            acc[i][2] += xv[i].x * w0.z + xv[i].y * w1.z + xv[i].z * w2.z + xv[i].w * w3.z;
            acc[i][3] += xv[i].x * w0.w + xv[i].y * w1.w + xv[i].z * w2.w + xv[i].w * w3.w;
        }
    }
#pragma unroll
    for (int i = 0; i < 4; ++i) {
        int rr = row0 + rg4 + i;
        if (rr < N) {
            bf4 o;
            o[0] = (__bf16)acc[i][0]; o[1] = (__bf16)acc[i][1];
            o[2] = (__bf16)acc[i][2]; o[3] = (__bf16)acc[i][3];
            *(bf4*)&hs[(size_t)rr * 128 + cg4] = o;
        }
    }
    if (P > 0 && t < 32 * P) {
        int srow = t / P, scol = t % P;
        if (row0 + srow < N) {
            float s = 0.f;
            for (int k = 0; k < 16; ++k) s += xs[srow][k] * fs[k * P + scol];
            sc[(size_t)(row0 + srow) * P + scol] = s;
        }
    }
}

// ===== layer-2: all 3 projections via bf16 MFMA, one launch, bf16 hs out =====

__global__ __launch_bounds__(256) void gemm_mfma_all(const __bf16* __restrict__ xrb,
                                                     const __bf16* __restrict__ xvb,
                                                     const __bf16* __restrict__ Wt,
                                                     __bf16* __restrict__ hs_a, __bf16* __restrict__ hs_b,
                                                     __bf16* __restrict__ hs_c) {
    int b = blockIdx.x;
    const __bf16* x; const __bf16* W; __bf16* hs; int N, blk;
    if (b < MFB_R)          { x = xrb; W = Wt + 0 * 16384; hs = hs_a; N = NR_; blk = b; }
    else if (b < 2 * MFB_R) { x = xrb; W = Wt + 2 * 16384; hs = hs_c; N = NR_; blk = b - MFB_R; }
    else                    { x = xvb; W = Wt + 1 * 16384; hs = hs_b; N = NV_; blk = b - 2 * MFB_R; }
    int wave = threadIdx.x >> 6;
    int lane = threadIdx.x & 63;
    int m = lane & 15;
    int quad = lane >> 4;
    int row0 = blk * 64 + wave * 16;
    int arow = row0 + m;
    int rs = (arow < N) ? arow : (N - 1);
    const __bf16* xp = x + (size_t)rs * 128 + quad * 8;
    bfrag A0 = *(const bfrag*)(xp);
    bfrag A1 = *(const bfrag*)(xp + 32);
    bfrag A2 = *(const bfrag*)(xp + 64);
    bfrag A3 = *(const bfrag*)(xp + 96);
#pragma unroll
    for (int nt = 0; nt < 8; ++nt) {
        const __bf16* wp = W + (size_t)(nt * 16 + m) * 128 + quad * 8;
        ffrag acc = {0.f, 0.f, 0.f, 0.f};
        acc = __builtin_amdgcn_mfma_f32_16x16x32_bf16(A0, *(const bfrag*)(wp), acc, 0, 0, 0);
        acc = __builtin_amdgcn_mfma_f32_16x16x32_bf16(A1, *(const bfrag*)(wp + 32), acc, 0, 0, 0);
        acc = __builtin_amdgcn_mfma_f32_16x16x32_bf16(A2, *(const bfrag*)(wp + 64), acc, 0, 0, 0);
        acc = __builtin_amdgcn_mfma_f32_16x16x32_bf16(A3, *(const bfrag*)(wp + 96), acc, 0, 0, 0);
        int dcol = nt * 16 + m;
#pragma unroll
        for (int r = 0; r < 4; ++r) {
            int drow = row0 + quad * 4 + r;
            if (drow < N) hs[(size_t)drow * 128 + dcol] = (__bf16)acc[r];
        }
    }
}

// ===== layer-2 attention scores (f32) =====

__global__ __launch_bounds__(256) void scores_l2_all(const float* __restrict__ xr,
                                                     const float* __restrict__ xv,
                                                     const float* __restrict__ fR,
                                                     const float* __restrict__ fV,
                                                     float* __restrict__ scR, float* __restrict__ scV) {
    __shared__ float sf[1024];
    int b = blockIdx.x;
    const float* x; const float* fold; float* sc; int N, P, n0;
    if (b < SCB_R) { x = xr; fold = fR; sc = scR; N = NR_; P = 8; n0 = b * 256; }
    else           { x = xv; fold = fV; sc = scV; N = NV_; P = 4; n0 = (b - SCB_R) * 256; }
    for (int i = threadIdx.x; i < 128 * P; i += 256) sf[i] = fold[i];
    __syncthreads();
    int n = n0 + threadIdx.x;
    if (n >= N) return;
    float a[8] = {0.f, 0.f, 0.f, 0.f, 0.f, 0.f, 0.f, 0.f};
    const float* xp = x + (size_t)n * 128;
    for (int k = 0; k < 128; k += 4) {
        float4 xv4 = *(const float4*)&xp[k];
        for (int p = 0; p < P; ++p)
            a[p] += xv4.x * sf[k * P + p] + xv4.y * sf[(k + 1) * P + p] +
                    xv4.z * sf[(k + 2) * P + p] + xv4.w * sf[(k + 3) * P + p];
    }
    float* o = sc + (size_t)n * P;
    for (int p = 0; p < P; ++p) o[p] = a[p];
}

// ===== final head per-node scores =====

__global__ __launch_bounds__(256) void final_scores_all(const float* __restrict__ xr,
                                                        const float* __restrict__ xv,
                                                        const float* __restrict__ fw,
                                                        float* __restrict__ ssR, float* __restrict__ ssV) {
    __shared__ float sf[512];
    int b = blockIdx.x;
    const float* x; float* sc; int N, n0;
    if (b < SCB_R) { x = xr; sc = ssR; N = NR_; n0 = b * 256; }
    else           { x = xv; sc = ssV; N = NV_; n0 = (b - SCB_R) * 256; }
    for (int i = threadIdx.x; i < 512; i += 256) sf[i] = fw[i];
    __syncthreads();
    int n = n0 + threadIdx.x;
    if (n >= N) return;
    float a0 = 0.f, a1 = 0.f, a2 = 0.f, a3 = 0.f;
    const float* xp = x + (size_t)n * 128;
    for (int k = 0; k < 128; k += 4) {
        float4 xv4 = *(const float4*)&xp[k];
        a0 += xv4.x * sf[k * 4 + 0] + xv4.y * sf[(k + 1) * 4 + 0] + xv4.z * sf[(k + 2) * 4 + 0] + xv4.w * sf[(k + 3) * 4 + 0];
        a1 += xv4.x * sf[k * 4 + 1] + xv4.y * sf[(k + 1) * 4 + 1] + xv4.z * sf[(k + 2) * 4 + 1] + xv4.w * sf[(k + 3) * 4 + 1];
        a2 += xv4.x * sf[k * 4 + 2] + xv4.y * sf[(k + 1) * 4 + 2] + xv4.z * sf[(k + 2) * 4 + 2] + xv4.w * sf[(k + 3) * 4 + 2];
        a3 += xv4.x * sf[k * 4 + 3] + xv4.y * sf[(k + 1) * 4 + 3] + xv4.z * sf[(k + 2) * 4 + 3] + xv4.w * sf[(k + 3) * 4 + 3];
    }
    *(float4*)&sc[(size_t)n * 4] = make_float4(a0, a1, a2, a3);
}

// ================= gather-aggregate (bf16 hs) with fused edge softmax =================
// 1 wave per node, bf16x2 per lane (features 2*lane, 2*lane+1), head = lane>>5.

__device__ __forceinline__ void agg_rel_bf(int node, int lane,
                                           const int* __restrict__ row, const int* __restrict__ cs,
                                           const __bf16* __restrict__ hs,
                                           const float* __restrict__ Ss, int sst, int sc, float edv,
                                           float& ox, float& oy) {
    int r0 = row[node], r1 = row[node + 1];
    if (r1 <= r0) return;
    float ax = 0.f, ay = 0.f, den = 0.f;
    int j = r0;
    for (; j + 4 <= r1; j += 4) {
        int s0 = cs[j + 0], s1 = cs[j + 1], s2 = cs[j + 2], s3 = cs[j + 3];
        float p0 = Ss[s0 * sst + sc];
        float p1 = Ss[s1 * sst + sc];
        float p2 = Ss[s2 * sst + sc];
        float p3 = Ss[s3 * sst + sc];
        bf2 v0 = *(const bf2*)&hs[(size_t)s0 * 128 + lane * 2];
        bf2 v1 = *(const bf2*)&hs[(size_t)s1 * 128 + lane * 2];
        bf2 v2 = *(const bf2*)&hs[(size_t)s2 * 128 + lane * 2];
        bf2 v3 = *(const bf2*)&hs[(size_t)s3 * 128 + lane * 2];
        float e0 = p0 + edv; e0 = (e0 >= 0.f) ? e0 : NEG_ * e0;
        float e1 = p1 + edv; e1 = (e1 >= 0.f) ? e1 : NEG_ * e1;
        float e2 = p2 + edv; e2 = (e2 >= 0.f) ? e2 : NEG_ * e2;
        float e3 = p3 + edv; e3 = (e3 >= 0.f) ? e3 : NEG_ * e3;
        float w0 = __expf(e0), w1 = __expf(e1), w2 = __expf(e2), w3 = __expf(e3);
        ax += (float)v0[0] * w0 + (float)v1[0] * w1 + (float)v2[0] * w2 + (float)v3[0] * w3;
        ay += (float)v0[1] * w0 + (float)v1[1] * w1 + (float)v2[1] * w2 + (float)v3[1] * w3;
        den += w0 + w1 + w2 + w3;
    }
    for (; j < r1; ++j) {
        int s = cs[j];
        float p = Ss[s * sst + sc];
        bf2 v = *(const bf2*)&hs[(size_t)s * 128 + lane * 2];
        float e = p + edv; e = (e >= 0.f) ? e : NEG_ * e;
        float w = __expf(e);
        ax += (float)v[0] * w;
        ay += (float)v[1] * w;
        den += w;
    }
    float inv = 1.f / den;
    ox += ax * inv;
    oy += ay * inv;
}

__global__ __launch_bounds__(256) void agg_all(
        const int* __restrict__ row, const int* __restrict__ cs,
        const __bf16* __restrict__ hs_a, const __bf16* __restrict__ hs_b,
        const __bf16* __restrict__ hs_c,
        const float* __restrict__ scR, const float* __restrict__ scV,
        float* __restrict__ o_r, float* __restrict__ o_v) {
    int b = blockIdx.x;
    int lane = threadIdx.x & 63;
    int hoff = lane >> 5;
    if (b < AGB_R) {
        int node = b * 4 + (threadIdx.x >> 6);
        if (node >= NR_) return;
        float ed_rr = scR[node * 8 + 2 + hoff];
        float ed_vr = scR[node * 8 + 4 + hoff];
        float ox = 0.f, oy = 0.f;
        agg_rel_bf(node, lane, row, cs, hs_a, scR, 8, 0 + hoff, ed_rr, ox, oy);
        agg_rel_bf(node, lane, row + NR_, cs, hs_b, scV, 4, 0 + hoff, ed_vr, ox, oy);
        *(float2*)&o_r[(size_t)node * 128 + lane * 2] = make_float2(ox * 0.5f, oy * 0.5f);
    } else {
        int node = (b - AGB_R) * 4 + (threadIdx.x >> 6);
        if (node >= NV_) return;
        float ed_rv = scV[node * 4 + 2 + hoff];
        float ox = 0.f, oy = 0.f;
        agg_rel_bf(node, lane, row + 2 * NR_, cs, hs_c, scR, 8, 6 + hoff, ed_rv, ox, oy);
        *(float2*)&o_v[(size_t)node * 128 + lane * 2] = make_float2(ox, oy);
    }
}

// ================= BatchNorm (training stats) + leaky-relu =================

__global__ __launch_bounds__(256) void bn_stats_all(const float* __restrict__ o_r,
                                                    const float* __restrict__ o_v,
                                                    float* __restrict__ s4) {
    int b = blockIdx.x;
    const float* o; int N; int r0; int soff;
    if (b < BN_BLKS_R) { o = o_r; N = NR_; r0 = b * 64; soff = 0; }
    else               { o = o_v; N = NV_; r0 = (b - BN_BLKS_R) * 64; soff = 128; }
    int wave = threadIdx.x >> 6, lane = threadIdx.x & 63;
    int rend = r0 + 64; if (rend > N) rend = N;
    float sx = 0.f, sy = 0.f, qx = 0.f, qy = 0.f;
    for (int r = r0 + wave; r < rend; r += 4) {
        float2 v = *(const float2*)&o[(size_t)r * 128 + lane * 2];
        sx += v.x; sy += v.y;
        qx += v.x * v.x; qy += v.y * v.y;
    }
    __shared__ float bs[4][128];
    __shared__ float bq[4][128];
    bs[wave][lane * 2] = sx;  bs[wave][lane * 2 + 1] = sy;
    bq[wave][lane * 2] = qx;  bq[wave][lane * 2 + 1] = qy;
    __syncthreads();
    if (threadIdx.x < 128) {
        int c = threadIdx.x;
        float s = bs[0][c] + bs[1][c] + bs[2][c] + bs[3][c];
        float q = bq[0][c] + bq[1][c] + bq[2][c] + bq[3][c];
        atomicAdd(&s4[soff + c], s);
        atomicAdd(&s4[256 + soff + c], q);
    }
}

__global__ void bn_norm_all(const float* __restrict__ o_r, const float* __restrict__ o_v,
                            const float* __restrict__ s4,
                            const float* __restrict__ gammaL, const float* __restrict__ betaL,
                            float* __restrict__ xr, float* __restrict__ xv,
                            __bf16* __restrict__ xrb, __bf16* __restrict__ xvb) {
    size_t idx = blockIdx.x * (size_t)256 + threadIdx.x;
    const size_t nr = (size_t)NR_ * 128;
    const float* o; float* x; __bf16* xb; int soff; float invN; size_t i;
    if (idx < nr) { o = o_r; x = xr; xb = xrb; soff = 0;   invN = 1.f / NR_; i = idx; }
    else          { o = o_v; x = xv; xb = xvb; soff = 128; invN = 1.f / NV_; i = idx - nr; }
    int c = (int)(i & 127);
    float mu = s4[soff + c] * invN;
    float var = s4[256 + soff + c] * invN - mu * mu;
    float v = (o[i] - mu) * rsqrtf(var + EPS_) * gammaL[soff + c] + betaL[soff + c];
    v = (v >= 0.f) ? v : NEG_ * v;
    x[i] = v;
    xb[i] = (__bf16)v;
}

// ================= final head =================

__global__ void final_edge_all(const int* __restrict__ ei_rr, const int* __restrict__ ei_vr,
                               const int* __restrict__ ei_rv,
                               const float* __restrict__ ea_rr, const float* __restrict__ ea_vr,
                               const float* __restrict__ ea_rv,
                               const float* __restrict__ ssR, const float* __restrict__ ssV,
                               const float* __restrict__ wp2, const float* __restrict__ cterm,
                               float* __restrict__ out) {
    int j = blockIdx.x * blockDim.x + threadIdx.x;
    if (j >= ETOT_) return;
    int rel, jj;
    const int* src; const int* dst; const float* ea; const float* ss; const float* sd; float* o;
    if (j < ERR_) {
        rel = 0; jj = j; src = ei_rr; dst = ei_rr + ERR_; ea = ea_rr; ss = ssR; sd = ssR; o = out;
    } else if (j < ERR_ + EVR_) {
        rel = 1; jj = j - ERR_; src = ei_vr; dst = ei_vr + EVR_; ea = ea_vr; ss = ssV; sd = ssR;
        o = out + (size_t)ERR_ * 2;
    } else {
        rel = 2; jj = j - ERR_ - EVR_; src = ei_rv; dst = ei_rv + ERV_; ea = ea_rv; ss = ssR; sd = ssV;
        o = out + (size_t)(ERR_ + EVR_) * 2;
    }
    int s = src[jj], d = dst[jj];
    float l0 = ss[s * 4 + 0] + sd[d * 4 + 2] + cterm[rel * 2 + 0];
    float l1 = ss[s * 4 + 1] + sd[d * 4 + 3] + cterm[rel * 2 + 1];
    const float* w = wp2 + rel * 16;
#pragma unroll
    for (int k = 0; k < 8; ++k) {
        float v = ea[(size_t)jj * 8 + k];
        l0 += v * w[k * 2 + 0];
        l1 += v * w[k * 2 + 1];
    }
    float m = fmaxf(l0, l1);
    float p0 = __expf(l0 - m), p1 = __expf(l1 - m);
    float inv = 1.f / (p0 + p1);
    o[(size_t)jj * 2 + 0] = p0 * inv;
    o[(size_t)jj * 2 + 1] = p1 * inv;
}

// ================= host orchestration =================

extern "C" void kernel_launch(void* const* d_in, const int* in_sizes, int n_in,
                              void* d_out, int out_size, void* d_ws, size_t ws_size,
                              hipStream_t stream) {
    const float* x_req = (const float*)d_in[0];
    const float* x_veh = (const float*)d_in[1];
    const int* ei_rr = (const int*)d_in[2];
    const int* ei_vr = (const int*)d_in[3];
    const int* ei_rv = (const int*)d_in[4];
    const float* ea_rr = (const float*)d_in[5];
    const float* ea_vr = (const float*)d_in[6];
    const float* ea_rv = (const float*)d_in[7];
    const float* Wsrc1 = (const float*)d_in[8];
    const float* Wdst1 = (const float*)d_in[9];
    const float* asrc1 = (const float*)d_in[10];
    const float* adst1 = (const float*)d_in[11];
    const float* Wsrc2 = (const float*)d_in[13];
    const float* Wdst2 = (const float*)d_in[14];
    const float* asrc2 = (const float*)d_in[15];
    const float* adst2 = (const float*)d_in[16];
    const float* bn_gamma = (const float*)d_in[18];
    const float* bn_beta  = (const float*)d_in[19];
    const float* Wp   = (const float*)d_in[20];
    const float* bp   = (const float*)d_in[21];
    const float* Wlin = (const float*)d_in[22];
    const float* blin = (const float*)d_in[23];
    float* out = (float*)d_out;

    float* w = (float*)d_ws;
    size_t off = 0;
    float* xr    = w + off; off += (size_t)NR_ * 128;
    float* xv    = w + off; off += (size_t)NV_ * 128;
    float* o_r   = w + off; off += (size_t)NR_ * 128;
    float* o_v   = w + off; off += (size_t)NV_ * 128;
    float* scR   = w + off; off += (size_t)NR_ * 8;
    float* scV   = w + off; off += (size_t)NV_ * 4;
    float* s4    = w + off; off += 512;
    float* foldR = w + off; off += 2 * 128 * 8;
    float* foldV = w + off; off += 2 * 128 * 4;
    float* wp2   = w + off; off += 48;
    float* cterm = w + off; off += 8;
    float* fw    = w + off; off += 512;
    float* ssR   = w + off; off += (size_t)NR_ * 4;
    float* ssV   = w + off; off += (size_t)NV_ * 4;
    // bf16 region (element counts are multiples of 2 -> float-offset aligned)
    __bf16* hs_a = (__bf16*)(w + off); off += (size_t)NR_ * 128 / 2;
    __bf16* hs_b = (__bf16*)(w + off); off += (size_t)NV_ * 128 / 2;
    __bf16* hs_c = (__bf16*)(w + off); off += (size_t)NR_ * 128 / 2;
    __bf16* xrb  = (__bf16*)(w + off); off += (size_t)NR_ * 128 / 2;
    __bf16* xvb  = (__bf16*)(w + off); off += (size_t)NV_ * 128 / 2;
    __bf16* Wt   = (__bf16*)(w + off); off += 3 * 128 * 128 / 2;
    int* iw = (int*)(w + off);
    size_t ioff = 0;
    int* row  = iw + ioff; ioff += NTOT_ + 1;
    int* cur  = iw + ioff; ioff += NTOT_;
    int* bsum = iw + ioff; ioff += SCAN_NB;
    int* boff = iw + ioff; ioff += SCAN_NB;
    int* cs   = iw + ioff; ioff += ETOT_;

    precompute_kernel<<<14 + 384, 128, 0, stream>>>(Wsrc1, Wdst1, asrc1, adst1,
                                                    Wsrc2, Wdst2, asrc2, adst2,
                                                    Wp, bp, Wlin, blin,
                                                    foldR, foldV, wp2, cterm, fw, Wt);

    hipMemsetAsync(cur, 0, NTOT_ * sizeof(int), stream);
    hist_all<<<(ETOT_ + 255) / 256, 256, 0, stream>>>(ei_rr, ei_vr, ei_rv, cur);
    scan_reduce<<<SCAN_NB, 256, 0, stream>>>(cur, bsum);
    scan_bsums<<<1, 256, 0, stream>>>(bsum, boff, row);
    scan_write<<<SCAN_NB, 256, 0, stream>>>(cur, boff, row, cur);
    scatter_all<<<(ETOT_ + 255) / 256, 256, 0, stream>>>(ei_rr, ei_vr, ei_rv, cur, cs);

    for (int l = 0; l < 2; ++l) {
        const float* fR = foldR + (size_t)l * 128 * 8;
        const float* fV = foldV + (size_t)l * 128 * 4;

        if (l == 0) {
            gemm_l1_all<<<2 * L1B_R + L1B_V, 256, 0, stream>>>(
                x_req, x_veh, Wsrc1, fR, fV, hs_a, hs_b, hs_c, scR, scV);
        } else {
            gemm_mfma_all<<<2 * MFB_R + MFB_V, 256, 0, stream>>>(xrb, xvb, Wt, hs_a, hs_b, hs_c);
            scores_l2_all<<<SCB_R + SCB_V, 256, 0, stream>>>(xr, xv, fR, fV, scR, scV);
        }
        agg_all<<<AGB_R + AGB_V, 256, 0, stream>>>(row, cs, hs_a, hs_b, hs_c, scR, scV, o_r, o_v);

        hipMemsetAsync(s4, 0, 512 * sizeof(float), stream);
        bn_stats_all<<<BN_BLKS_R + BN_BLKS_V, 256, 0, stream>>>(o_r, o_v, s4);
        bn_norm_all<<<(int)(((size_t)(NR_ + NV_) * 128 + 255) / 256), 256, 0, stream>>>(
            o_r, o_v, s4, bn_gamma + l * 256, bn_beta + l * 256, xr, xv, xrb, xvb);
    }

    final_scores_all<<<SCB_R + SCB_V, 256, 0, stream>>>(xr, xv, fw, ssR, ssV);
    final_edge_all<<<(ETOT_ + 255) / 256, 256, 0, stream>>>(ei_rr, ei_vr, ei_rv, ea_rr, ea_vr, ea_rv,
                                                            ssR, ssV, wp2, cterm, out);
}